// Round 3
// baseline (668.531 us; speedup 1.0000x reference)
//
#include <hip/hip_runtime.h>
#include <math.h>

// Problem constants
#define BB 2
#define DD 128
#define LL 2048
#define HH 8
#define OC 1024     // H*D
#define RR_ 128
#define BL (BB*LL)          // 4096
#define NROW (BL*HH)        // 32768

// ---------------------------------------------------------------------------
// Kernel 1: causal conv1d K=3 + bias + gamma/beta affine. fp64 accumulation:
// phi feeds the catastrophically-cancelling denominator, needs ~1e-7 accuracy.
// ---------------------------------------------------------------------------
__global__ __launch_bounds__(256) void conv3_k(
    const float* __restrict__ x, const float* __restrict__ w,
    const float* __restrict__ bias, const float* __restrict__ gamma,
    const float* __restrict__ beta, float* __restrict__ out)
{
    __shared__ float xs[32][66];
    __shared__ float wsm[64][97];
    const int tid = threadIdx.x;
    const int tile = blockIdx.x;
    const int b  = tile >> 5;
    const int l0 = (tile & 31) << 6;
    const int o0 = blockIdx.y << 6;
    const double g  = (double)gamma[0];
    const double be = (double)beta[0];
    const int ty = tid >> 4;
    const int tx = tid & 15;
    double acc[4][4] = {};

    for (int c0 = 0; c0 < DD; c0 += 32) {
        for (int e = tid; e < 32*66; e += 256) {
            int c = e / 66, j = e % 66;
            int gl = l0 - 2 + j;
            xs[c][j] = (gl >= 0) ? x[(b*DD + c0 + c)*LL + gl] : 0.f;
        }
        for (int e = tid; e < 64*96; e += 256) {
            int o = e / 96, ct = e % 96;
            wsm[o][ct] = w[(o0 + o)*384 + c0*3 + ct];
        }
        __syncthreads();
        for (int cc = 0; cc < 32; ++cc) {
            float xv[6];
            #pragma unroll
            for (int jj = 0; jj < 6; ++jj) xv[jj] = xs[cc][ty*4 + jj];
            #pragma unroll
            for (int i = 0; i < 4; ++i) {
                const double w0 = (double)wsm[tx*4+i][cc*3+0];
                const double w1 = (double)wsm[tx*4+i][cc*3+1];
                const double w2 = (double)wsm[tx*4+i][cc*3+2];
                #pragma unroll
                for (int j = 0; j < 4; ++j) {
                    acc[i][j] += w0*(double)xv[j];
                    acc[i][j] += w1*(double)xv[j+1];
                    acc[i][j] += w2*(double)xv[j+2];
                }
            }
        }
        __syncthreads();
    }
    #pragma unroll
    for (int j = 0; j < 4; ++j) {
        const int l = l0 + ty*4 + j;
        float4 r;
        r.x = (float)(g*(acc[0][j] + (double)bias[o0 + tx*4 + 0]) + be);
        r.y = (float)(g*(acc[1][j] + (double)bias[o0 + tx*4 + 1]) + be);
        r.z = (float)(g*(acc[2][j] + (double)bias[o0 + tx*4 + 2]) + be);
        r.w = (float)(g*(acc[3][j] + (double)bias[o0 + tx*4 + 3]) + be);
        *(float4*)&out[(size_t)(b*LL + l)*OC + o0 + tx*4] = r;
    }
}

// ---------------------------------------------------------------------------
// Kernel 2: V projection (conv K=1, no bias). fp32 (numerator-only path).
// ---------------------------------------------------------------------------
__global__ __launch_bounds__(256) void vproj_k(
    const float* __restrict__ x, const float* __restrict__ vw,
    float* __restrict__ v_out)
{
    __shared__ float xsv[32][65];
    __shared__ float wsv[64][33];
    const int tid = threadIdx.x;
    const int tile = blockIdx.x;
    const int b  = tile >> 5;
    const int l0 = (tile & 31) << 6;
    const int o0 = blockIdx.y << 6;
    const int ty = tid >> 4;
    const int tx = tid & 15;
    float acc[4][4] = {};

    for (int c0 = 0; c0 < DD; c0 += 32) {
        for (int e = tid; e < 32*64; e += 256) {
            int c = e >> 6, j = e & 63;
            xsv[c][j] = x[(b*DD + c0 + c)*LL + l0 + j];
        }
        for (int e = tid; e < 64*32; e += 256) {
            int o = e >> 5, c = e & 31;
            wsv[o][c] = vw[(o0 + o)*DD + c0 + c];
        }
        __syncthreads();
        for (int cc = 0; cc < 32; ++cc) {
            float xv[4], wv[4];
            #pragma unroll
            for (int j = 0; j < 4; ++j) xv[j] = xsv[cc][ty*4 + j];
            #pragma unroll
            for (int i = 0; i < 4; ++i) wv[i] = wsv[tx*4+i][cc];
            #pragma unroll
            for (int i = 0; i < 4; ++i)
                #pragma unroll
                for (int j = 0; j < 4; ++j)
                    acc[i][j] += wv[i]*xv[j];
        }
        __syncthreads();
    }
    #pragma unroll
    for (int j = 0; j < 4; ++j) {
        const int l = l0 + ty*4 + j;
        float4 r = make_float4(acc[0][j], acc[1][j], acc[2][j], acc[3][j]);
        *(float4*)&v_out[(size_t)(b*LL + l)*OC + o0 + tx*4] = r;
    }
}

// ---------------------------------------------------------------------------
// Kernel 3: sketch, in-place, fp64 u1/u2 accumulation + fp64 tanh.
// ---------------------------------------------------------------------------
__global__ __launch_bounds__(256) void sketch_k(
    float* __restrict__ buf, const float* __restrict__ g1,
    const float* __restrict__ g2)
{
    __shared__ float Qs[64][33];
    __shared__ float G1s[32][132];
    __shared__ float G2s[32][132];
    const int tid = threadIdx.x;
    const size_t i0 = (size_t)blockIdx.x * 64;
    const int ty = tid >> 4;
    const int tx = tid & 15;
    double u1[4][8] = {}, u2[4][8] = {};

    for (int k0 = 0; k0 < DD; k0 += 32) {
        __syncthreads();
        for (int e = tid; e < 64*32; e += 256) {
            int row = e >> 5, kk = e & 31;
            Qs[row][kk] = buf[(i0 + row)*RR_ + k0 + kk];
        }
        for (int e = tid; e < 32*128; e += 256) {
            int kk = e >> 7, r = e & 127;
            G1s[kk][r] = g1[(k0 + kk)*RR_ + r];
            G2s[kk][r] = g2[(k0 + kk)*RR_ + r];
        }
        __syncthreads();
        for (int kk = 0; kk < 32; ++kk) {
            double a[4];
            #pragma unroll
            for (int i = 0; i < 4; ++i) a[i] = (double)Qs[ty*4+i][kk];
            float4 c0 = *(const float4*)&G1s[kk][tx*8];
            float4 c1 = *(const float4*)&G1s[kk][tx*8+4];
            float4 d0 = *(const float4*)&G2s[kk][tx*8];
            float4 d1 = *(const float4*)&G2s[kk][tx*8+4];
            float b1[8] = {c0.x,c0.y,c0.z,c0.w,c1.x,c1.y,c1.z,c1.w};
            float b2[8] = {d0.x,d0.y,d0.z,d0.w,d1.x,d1.y,d1.z,d1.w};
            #pragma unroll
            for (int i = 0; i < 4; ++i)
                #pragma unroll
                for (int j = 0; j < 8; ++j) {
                    u1[i][j] += a[i]*(double)b1[j];
                    u2[i][j] += a[i]*(double)b2[j];
                }
        }
    }
    const double SR  = 11.313708498984760390;   // sqrt(128)
    const double ISR = 0.088388347648318440550; // 1/sqrt(128)
    #pragma unroll
    for (int i = 0; i < 4; ++i) {
        float out[8];
        #pragma unroll
        for (int j = 0; j < 8; ++j)
            out[j] = (float)(SR * tanh(u1[i][j]*u2[i][j]*ISR));
        size_t base = (i0 + ty*4 + i)*RR_ + tx*8;
        *(float4*)&buf[base]   = make_float4(out[0],out[1],out[2],out[3]);
        *(float4*)&buf[base+4] = make_float4(out[4],out[5],out[6],out[7]);
    }
}

// ---------------------------------------------------------------------------
// Kernel 4: partial KV (fp32) + Ksum (fp64) per (b,h,l-chunk of 128).
// ---------------------------------------------------------------------------
__global__ __launch_bounds__(256) void kv_part_k(
    const float* __restrict__ phi_k, const float* __restrict__ v,
    float* __restrict__ part_kv, double* __restrict__ part_ks)
{
    __shared__ float Ps[32][132];
    __shared__ float Vs[32][132];
    const int tid = threadIdx.x;
    const int chunk = blockIdx.x;   // 16
    const int bh = blockIdx.y;      // 16
    const int b = bh >> 3, h = bh & 7;
    const int lbase = chunk * 128;
    const int ty = tid >> 4;
    const int tx = tid & 15;
    float acc[8][8] = {};
    double ks = 0.0;

    for (int ls = 0; ls < 128; ls += 32) {
        for (int e = tid; e < 32*128; e += 256) {
            int ll = e >> 7, r = e & 127;
            size_t base = ((size_t)(b*LL + lbase + ls + ll)*HH + h)*RR_;
            Ps[ll][r] = phi_k[base + r];
            Vs[ll][r] = v[base + r];
        }
        __syncthreads();
        for (int ll = 0; ll < 32; ++ll) {
            float4 a0 = *(const float4*)&Ps[ll][ty*8];
            float4 a1 = *(const float4*)&Ps[ll][ty*8+4];
            float4 b0 = *(const float4*)&Vs[ll][tx*8];
            float4 b1 = *(const float4*)&Vs[ll][tx*8+4];
            float av[8] = {a0.x,a0.y,a0.z,a0.w,a1.x,a1.y,a1.z,a1.w};
            float bv[8] = {b0.x,b0.y,b0.z,b0.w,b1.x,b1.y,b1.z,b1.w};
            #pragma unroll
            for (int i = 0; i < 8; ++i)
                #pragma unroll
                for (int j = 0; j < 8; ++j)
                    acc[i][j] += av[i]*bv[j];
        }
        if (tid < 128) {
            #pragma unroll 8
            for (int ll = 0; ll < 32; ++ll) ks += (double)Ps[ll][tid];
        }
        __syncthreads();
    }
    float* outp = part_kv + ((size_t)(bh*16 + chunk))*RR_*DD;
    #pragma unroll
    for (int i = 0; i < 8; ++i) {
        int r = ty*8 + i;
        *(float4*)&outp[r*DD + tx*8]   = make_float4(acc[i][0],acc[i][1],acc[i][2],acc[i][3]);
        *(float4*)&outp[r*DD + tx*8+4] = make_float4(acc[i][4],acc[i][5],acc[i][6],acc[i][7]);
    }
    if (tid < 128) part_ks[(bh*16 + chunk)*RR_ + tid] = ks;
}

// ---------------------------------------------------------------------------
// Kernel 5: reduce partial KV over 16 chunks.
// ---------------------------------------------------------------------------
__global__ __launch_bounds__(256) void kvreduce_k(
    const float* __restrict__ part_kv, float* __restrict__ KV)
{
    const int gid = blockIdx.x*256 + threadIdx.x;
    if (gid >= 16*RR_*DD) return;
    const int bh = gid >> 14;
    const int rd = gid & 16383;
    float s = 0.f;
    #pragma unroll
    for (int c = 0; c < 16; ++c)
        s += part_kv[(((size_t)(bh*16 + c)) << 14) + rd];
    KV[gid] = s;
}

// ---------------------------------------------------------------------------
// Kernel 6: o = (phi_q @ KV) / (phi_q . Ksum + 1e-6). Den path in fp64.
// ---------------------------------------------------------------------------
__global__ __launch_bounds__(256) void numden_k(
    const float* __restrict__ phi_q, const float* __restrict__ KV,
    const double* __restrict__ part_ks, float* __restrict__ o_out)
{
    __shared__ float Pq[64][33];
    __shared__ float KVs[32][132];
    __shared__ double Ks_s[128];
    __shared__ double den_s[64];
    const int tid = threadIdx.x;
    const int lt = blockIdx.x;
    const int bh = blockIdx.y;
    const int b = bh >> 3, h = bh & 7;
    const int l0 = lt * 64;
    if (tid < 128) {
        double s = 0.0;
        #pragma unroll
        for (int c = 0; c < 16; ++c) s += part_ks[(bh*16 + c)*RR_ + tid];
        Ks_s[tid] = s;
    }
    const int ty = tid >> 4;
    const int tx = tid & 15;
    float acc[4][8] = {};
    double den = 0.0;

    for (int r0 = 0; r0 < RR_; r0 += 32) {
        __syncthreads();
        for (int e = tid; e < 64*32; e += 256) {
            int row = e >> 5, rr = e & 31;
            Pq[row][rr] = phi_q[((size_t)(b*LL + l0 + row)*HH + h)*RR_ + r0 + rr];
        }
        for (int e = tid; e < 32*128; e += 256) {
            int rr = e >> 7, d = e & 127;
            KVs[rr][d] = KV[((size_t)bh*RR_ + r0 + rr)*DD + d];
        }
        __syncthreads();
        for (int rr = 0; rr < 32; ++rr) {
            float a[4];
            #pragma unroll
            for (int i = 0; i < 4; ++i) a[i] = Pq[ty*4+i][rr];
            float4 b0 = *(const float4*)&KVs[rr][tx*8];
            float4 b1 = *(const float4*)&KVs[rr][tx*8+4];
            float bv[8] = {b0.x,b0.y,b0.z,b0.w,b1.x,b1.y,b1.z,b1.w};
            #pragma unroll
            for (int i = 0; i < 4; ++i)
                #pragma unroll
                for (int j = 0; j < 8; ++j)
                    acc[i][j] += a[i]*bv[j];
        }
        if (tid < 64) {
            #pragma unroll
            for (int rr = 0; rr < 32; ++rr)
                den += (double)Pq[tid][rr]*Ks_s[r0 + rr];
        }
    }
    __syncthreads();
    if (tid < 64) den_s[tid] = den;
    __syncthreads();
    #pragma unroll
    for (int i = 0; i < 4; ++i) {
        const int l = l0 + ty*4 + i;
        const float inv = (float)(1.0 / (den_s[ty*4+i] + 1e-6));
        size_t base = ((size_t)(b*LL + l))*OC + h*DD + tx*8;
        *(float4*)&o_out[base]   = make_float4(acc[i][0]*inv, acc[i][1]*inv,
                                               acc[i][2]*inv, acc[i][3]*inv);
        *(float4*)&o_out[base+4] = make_float4(acc[i][4]*inv, acc[i][5]*inv,
                                               acc[i][6]*inv, acc[i][7]*inv);
    }
}

// ---------------------------------------------------------------------------
// Kernel 7: output projection
// ---------------------------------------------------------------------------
__global__ __launch_bounds__(256) void proj_k(
    const float* __restrict__ o_s, const float* __restrict__ pw,
    const float* __restrict__ pb, float* __restrict__ out)
{
    __shared__ float As[32][33];
    __shared__ float Bs[32][132];
    const int tid = threadIdx.x;
    const int row0 = blockIdx.x * 32;
    const int ty = tid >> 5;
    const int tx = tid & 31;
    float acc[4][4] = {};

    for (int k0 = 0; k0 < OC; k0 += 32) {
        __syncthreads();
        for (int e = tid; e < 32*32; e += 256) {
            int r = e >> 5, kk = e & 31;
            As[r][kk] = o_s[(size_t)(row0 + r)*OC + k0 + kk];
        }
        for (int e = tid; e < 32*128; e += 256) {
            int j = e >> 5, kk = e & 31;
            Bs[kk][j] = pw[(size_t)j*OC + k0 + kk];
        }
        __syncthreads();
        for (int kk = 0; kk < 32; ++kk) {
            float a[4];
            #pragma unroll
            for (int i = 0; i < 4; ++i) a[i] = As[ty*4+i][kk];
            float4 bq = *(const float4*)&Bs[kk][tx*4];
            float bv[4] = {bq.x,bq.y,bq.z,bq.w};
            #pragma unroll
            for (int i = 0; i < 4; ++i)
                #pragma unroll
                for (int j = 0; j < 4; ++j)
                    acc[i][j] += a[i]*bv[j];
        }
    }
    #pragma unroll
    for (int i = 0; i < 4; ++i) {
        float4 r;
        r.x = acc[i][0] + pb[tx*4+0];
        r.y = acc[i][1] + pb[tx*4+1];
        r.z = acc[i][2] + pb[tx*4+2];
        r.w = acc[i][3] + pb[tx*4+3];
        *(float4*)&out[(size_t)(row0 + ty*4 + i)*DD + tx*4] = r;
    }
}

// ---------------------------------------------------------------------------
extern "C" void kernel_launch(void* const* d_in, const int* in_sizes, int n_in,
                              void* d_out, int out_size, void* d_ws, size_t ws_size,
                              hipStream_t stream) {
    const float* x       = (const float*)d_in[0];
    const float* q_w     = (const float*)d_in[1];
    const float* q_b     = (const float*)d_in[2];
    const float* k_w     = (const float*)d_in[3];
    const float* k_b     = (const float*)d_in[4];
    const float* v_w     = (const float*)d_in[5];
    const float* g1_q    = (const float*)d_in[6];
    const float* g2_q    = (const float*)d_in[7];
    const float* g1_k    = (const float*)d_in[8];
    const float* g2_k    = (const float*)d_in[9];
    const float* gamma_q = (const float*)d_in[10];
    const float* beta_q  = (const float*)d_in[11];
    const float* gamma_k = (const float*)d_in[12];
    const float* beta_k  = (const float*)d_in[13];
    const float* proj_w  = (const float*)d_in[14];
    const float* proj_b  = (const float*)d_in[15];

    float* f = (float*)d_ws;
    float* q_s     = f;                        // 4,194,304 floats
    float* k_s     = f + 4194304;              // 4,194,304
    float* v_s     = f + 8388608;              // 4,194,304
    float* part_kv = f + 12582912;             // 4,194,304
    double* part_ks = (double*)(f + 16777216); // 32,768 doubles, 8B-aligned (64MB offset)
    float* KVb     = f + 16842752;             // 262,144
    float* o_s     = k_s;                      // reuse (phi_k dead after kv_part_k)

    dim3 blk(256);
    conv3_k  <<<dim3(64,16), blk, 0, stream>>>(x, q_w, q_b, gamma_q, beta_q, q_s);
    conv3_k  <<<dim3(64,16), blk, 0, stream>>>(x, k_w, k_b, gamma_k, beta_k, k_s);
    vproj_k  <<<dim3(64,16), blk, 0, stream>>>(x, v_w, v_s);
    sketch_k <<<512, blk, 0, stream>>>(q_s, g1_q, g2_q);
    sketch_k <<<512, blk, 0, stream>>>(k_s, g1_k, g2_k);
    kv_part_k<<<dim3(16,16), blk, 0, stream>>>(k_s, v_s, part_kv, part_ks);
    kvreduce_k<<<1024, blk, 0, stream>>>(part_kv, KVb);
    numden_k <<<dim3(32,16), blk, 0, stream>>>(q_s, KVb, part_ks, o_s);
    proj_k   <<<128, blk, 0, stream>>>(o_s, proj_w, proj_b, (float*)d_out);
}

// Round 6
// 556.975 us; speedup vs baseline: 1.2003x; 1.2003x over previous
//
#include <hip/hip_runtime.h>
#include <math.h>

// Problem constants
#define BB 2
#define DD 128
#define LL 2048
#define HH 8
#define OC 1024     // H*D
#define RR_ 128
#define BL (BB*LL)          // 4096
#define NROW (BL*HH)        // 32768

// Numerics ledger (absmax is bf16-quantized, ulp=32 at |o|~9e3; threshold 180.48):
//   full fp64 conv+sketch           -> 128  PASS (r3, = comparison floor)
//   seq fp32 (eps_phi ~7e-7)        -> 192  FAIL (r2)
//   chunk-32 fp32 + tanhf (~5e-7)   -> 192  FAIL (r5)
// => need eps_phi <= ~2e-7: conv chunk=4ch (12 taps, ~7e-8), sketch chunk=8k
//    (~1.2e-7), fp64 z+tanh (tanhf ulp was ~1e-7 on phi). Total ~1.9e-7.

// ---------------------------------------------------------------------------
// Kernel 1: causal conv1d K=3 + bias + gamma/beta affine.
// fp32 FMAs within 4-channel (12-tap) sub-chunks; fp64 inter-chunk.
// ---------------------------------------------------------------------------
__global__ __launch_bounds__(256) void conv3_k(
    const float* __restrict__ x, const float* __restrict__ w,
    const float* __restrict__ bias, const float* __restrict__ gamma,
    const float* __restrict__ beta, float* __restrict__ out)
{
    __shared__ float xs[32][66];
    __shared__ float wsm[64][97];
    const int tid = threadIdx.x;
    const int tile = blockIdx.x;
    const int b  = tile >> 5;
    const int l0 = (tile & 31) << 6;
    const int o0 = blockIdx.y << 6;
    const double g  = (double)gamma[0];
    const double be = (double)beta[0];
    const int ty = tid >> 4;
    const int tx = tid & 15;
    double accd[4][4] = {};

    for (int c0 = 0; c0 < DD; c0 += 32) {
        for (int e = tid; e < 32*66; e += 256) {
            int c = e / 66, j = e % 66;
            int gl = l0 - 2 + j;
            xs[c][j] = (gl >= 0) ? x[(b*DD + c0 + c)*LL + gl] : 0.f;
        }
        for (int e = tid; e < 64*96; e += 256) {
            int o = e / 96, ct = e % 96;
            wsm[o][ct] = w[(o0 + o)*384 + c0*3 + ct];
        }
        __syncthreads();
        for (int cc0 = 0; cc0 < 32; cc0 += 4) {
            float accf[4][4] = {};
            #pragma unroll
            for (int u = 0; u < 4; ++u) {
                const int cc = cc0 + u;
                float xv[6];
                #pragma unroll
                for (int jj = 0; jj < 6; ++jj) xv[jj] = xs[cc][ty*4 + jj];
                #pragma unroll
                for (int i = 0; i < 4; ++i) {
                    const float w0 = wsm[tx*4+i][cc*3+0];
                    const float w1 = wsm[tx*4+i][cc*3+1];
                    const float w2 = wsm[tx*4+i][cc*3+2];
                    #pragma unroll
                    for (int j = 0; j < 4; ++j)
                        accf[i][j] += w0*xv[j] + w1*xv[j+1] + w2*xv[j+2];
                }
            }
            #pragma unroll
            for (int i = 0; i < 4; ++i)
                #pragma unroll
                for (int j = 0; j < 4; ++j)
                    accd[i][j] += (double)accf[i][j];
        }
        __syncthreads();
    }
    #pragma unroll
    for (int j = 0; j < 4; ++j) {
        const int l = l0 + ty*4 + j;
        float4 r;
        r.x = (float)(g*(accd[0][j] + (double)bias[o0 + tx*4 + 0]) + be);
        r.y = (float)(g*(accd[1][j] + (double)bias[o0 + tx*4 + 1]) + be);
        r.z = (float)(g*(accd[2][j] + (double)bias[o0 + tx*4 + 2]) + be);
        r.w = (float)(g*(accd[3][j] + (double)bias[o0 + tx*4 + 3]) + be);
        *(float4*)&out[(size_t)(b*LL + l)*OC + o0 + tx*4] = r;
    }
}

// ---------------------------------------------------------------------------
// Kernel 2: V projection (conv K=1, no bias). fp32 (numerator-only path).
// ---------------------------------------------------------------------------
__global__ __launch_bounds__(256) void vproj_k(
    const float* __restrict__ x, const float* __restrict__ vw,
    float* __restrict__ v_out)
{
    __shared__ float xsv[32][65];
    __shared__ float wsv[64][33];
    const int tid = threadIdx.x;
    const int tile = blockIdx.x;
    const int b  = tile >> 5;
    const int l0 = (tile & 31) << 6;
    const int o0 = blockIdx.y << 6;
    const int ty = tid >> 4;
    const int tx = tid & 15;
    float acc[4][4] = {};

    for (int c0 = 0; c0 < DD; c0 += 32) {
        for (int e = tid; e < 32*64; e += 256) {
            int c = e >> 6, j = e & 63;
            xsv[c][j] = x[(b*DD + c0 + c)*LL + l0 + j];
        }
        for (int e = tid; e < 64*32; e += 256) {
            int o = e >> 5, c = e & 31;
            wsv[o][c] = vw[(o0 + o)*DD + c0 + c];
        }
        __syncthreads();
        for (int cc = 0; cc < 32; ++cc) {
            float xv[4], wv[4];
            #pragma unroll
            for (int j = 0; j < 4; ++j) xv[j] = xsv[cc][ty*4 + j];
            #pragma unroll
            for (int i = 0; i < 4; ++i) wv[i] = wsv[tx*4+i][cc];
            #pragma unroll
            for (int i = 0; i < 4; ++i)
                #pragma unroll
                for (int j = 0; j < 4; ++j)
                    acc[i][j] += wv[i]*xv[j];
        }
        __syncthreads();
    }
    #pragma unroll
    for (int j = 0; j < 4; ++j) {
        const int l = l0 + ty*4 + j;
        float4 r = make_float4(acc[0][j], acc[1][j], acc[2][j], acc[3][j]);
        *(float4*)&v_out[(size_t)(b*LL + l)*OC + o0 + tx*4] = r;
    }
}

// ---------------------------------------------------------------------------
// Kernel 3: sketch, in-place. fp32 FMAs within 8-k sub-chunks, fp64
// inter-chunk; fp64 z and tanh (tanhf ulp alone is ~1e-7 on phi — too big).
// ---------------------------------------------------------------------------
__global__ __launch_bounds__(256) void sketch_k(
    float* __restrict__ buf, const float* __restrict__ g1,
    const float* __restrict__ g2)
{
    __shared__ float Qs[64][33];
    __shared__ float G1s[32][132];
    __shared__ float G2s[32][132];
    const int tid = threadIdx.x;
    const size_t i0 = (size_t)blockIdx.x * 64;
    const int ty = tid >> 4;
    const int tx = tid & 15;
    double u1d[4][8] = {}, u2d[4][8] = {};

    for (int k0 = 0; k0 < DD; k0 += 32) {
        __syncthreads();
        for (int e = tid; e < 64*32; e += 256) {
            int row = e >> 5, kk = e & 31;
            Qs[row][kk] = buf[(i0 + row)*RR_ + k0 + kk];
        }
        for (int e = tid; e < 32*128; e += 256) {
            int kk = e >> 7, r = e & 127;
            G1s[kk][r] = g1[(k0 + kk)*RR_ + r];
            G2s[kk][r] = g2[(k0 + kk)*RR_ + r];
        }
        __syncthreads();
        for (int kk0 = 0; kk0 < 32; kk0 += 8) {
            float u1[4][8] = {}, u2[4][8] = {};
            #pragma unroll
            for (int u = 0; u < 8; ++u) {
                const int kk = kk0 + u;
                float a[4];
                #pragma unroll
                for (int i = 0; i < 4; ++i) a[i] = Qs[ty*4+i][kk];
                float4 c0 = *(const float4*)&G1s[kk][tx*8];
                float4 c1 = *(const float4*)&G1s[kk][tx*8+4];
                float4 d0 = *(const float4*)&G2s[kk][tx*8];
                float4 d1 = *(const float4*)&G2s[kk][tx*8+4];
                float b1[8] = {c0.x,c0.y,c0.z,c0.w,c1.x,c1.y,c1.z,c1.w};
                float b2[8] = {d0.x,d0.y,d0.z,d0.w,d1.x,d1.y,d1.z,d1.w};
                #pragma unroll
                for (int i = 0; i < 4; ++i)
                    #pragma unroll
                    for (int j = 0; j < 8; ++j) {
                        u1[i][j] += a[i]*b1[j];
                        u2[i][j] += a[i]*b2[j];
                    }
            }
            #pragma unroll
            for (int i = 0; i < 4; ++i)
                #pragma unroll
                for (int j = 0; j < 8; ++j) {
                    u1d[i][j] += (double)u1[i][j];
                    u2d[i][j] += (double)u2[i][j];
                }
        }
    }
    const double SR  = 11.313708498984760390;   // sqrt(128)
    const double ISR = 0.088388347648318440550; // 1/sqrt(128)
    #pragma unroll
    for (int i = 0; i < 4; ++i) {
        float out[8];
        #pragma unroll
        for (int j = 0; j < 8; ++j)
            out[j] = (float)(SR * tanh(u1d[i][j]*u2d[i][j]*ISR));
        size_t base = (i0 + ty*4 + i)*RR_ + tx*8;
        *(float4*)&buf[base]   = make_float4(out[0],out[1],out[2],out[3]);
        *(float4*)&buf[base+4] = make_float4(out[4],out[5],out[6],out[7]);
    }
}

// ---------------------------------------------------------------------------
// Kernel 4: partial KV (fp32) + Ksum (fp64) per (b,h,l-chunk of 128).
// ---------------------------------------------------------------------------
__global__ __launch_bounds__(256) void kv_part_k(
    const float* __restrict__ phi_k, const float* __restrict__ v,
    float* __restrict__ part_kv, double* __restrict__ part_ks)
{
    __shared__ float Ps[32][132];
    __shared__ float Vs[32][132];
    const int tid = threadIdx.x;
    const int chunk = blockIdx.x;   // 16
    const int bh = blockIdx.y;      // 16
    const int b = bh >> 3, h = bh & 7;
    const int lbase = chunk * 128;
    const int ty = tid >> 4;
    const int tx = tid & 15;
    float acc[8][8] = {};
    double ks = 0.0;

    for (int ls = 0; ls < 128; ls += 32) {
        for (int e = tid; e < 32*128; e += 256) {
            int ll = e >> 7, r = e & 127;
            size_t base = ((size_t)(b*LL + lbase + ls + ll)*HH + h)*RR_;
            Ps[ll][r] = phi_k[base + r];
            Vs[ll][r] = v[base + r];
        }
        __syncthreads();
        for (int ll = 0; ll < 32; ++ll) {
            float4 a0 = *(const float4*)&Ps[ll][ty*8];
            float4 a1 = *(const float4*)&Ps[ll][ty*8+4];
            float4 b0 = *(const float4*)&Vs[ll][tx*8];
            float4 b1 = *(const float4*)&Vs[ll][tx*8+4];
            float av[8] = {a0.x,a0.y,a0.z,a0.w,a1.x,a1.y,a1.z,a1.w};
            float bv[8] = {b0.x,b0.y,b0.z,b0.w,b1.x,b1.y,b1.z,b1.w};
            #pragma unroll
            for (int i = 0; i < 8; ++i)
                #pragma unroll
                for (int j = 0; j < 8; ++j)
                    acc[i][j] += av[i]*bv[j];
        }
        if (tid < 128) {
            #pragma unroll 8
            for (int ll = 0; ll < 32; ++ll) ks += (double)Ps[ll][tid];
        }
        __syncthreads();
    }
    float* outp = part_kv + ((size_t)(bh*16 + chunk))*RR_*DD;
    #pragma unroll
    for (int i = 0; i < 8; ++i) {
        int r = ty*8 + i;
        *(float4*)&outp[r*DD + tx*8]   = make_float4(acc[i][0],acc[i][1],acc[i][2],acc[i][3]);
        *(float4*)&outp[r*DD + tx*8+4] = make_float4(acc[i][4],acc[i][5],acc[i][6],acc[i][7]);
    }
    if (tid < 128) part_ks[(bh*16 + chunk)*RR_ + tid] = ks;
}

// ---------------------------------------------------------------------------
// Kernel 5: reduce partial KV over 16 chunks.
// ---------------------------------------------------------------------------
__global__ __launch_bounds__(256) void kvreduce_k(
    const float* __restrict__ part_kv, float* __restrict__ KV)
{
    const int gid = blockIdx.x*256 + threadIdx.x;
    if (gid >= 16*RR_*DD) return;
    const int bh = gid >> 14;
    const int rd = gid & 16383;
    float s = 0.f;
    #pragma unroll
    for (int c = 0; c < 16; ++c)
        s += part_kv[(((size_t)(bh*16 + c)) << 14) + rd];
    KV[gid] = s;
}

// ---------------------------------------------------------------------------
// Kernel 6: o = (phi_q @ KV) / (phi_q . Ksum + 1e-6). Den path in fp64.
// ---------------------------------------------------------------------------
__global__ __launch_bounds__(256) void numden_k(
    const float* __restrict__ phi_q, const float* __restrict__ KV,
    const double* __restrict__ part_ks, float* __restrict__ o_out)
{
    __shared__ float Pq[64][33];
    __shared__ float KVs[32][132];
    __shared__ double Ks_s[128];
    __shared__ double den_s[64];
    const int tid = threadIdx.x;
    const int lt = blockIdx.x;
    const int bh = blockIdx.y;
    const int b = bh >> 3, h = bh & 7;
    const int l0 = lt * 64;
    if (tid < 128) {
        double s = 0.0;
        #pragma unroll
        for (int c = 0; c < 16; ++c) s += part_ks[(bh*16 + c)*RR_ + tid];
        Ks_s[tid] = s;
    }
    const int ty = tid >> 4;
    const int tx = tid & 15;
    float acc[4][8] = {};
    double den = 0.0;

    for (int r0 = 0; r0 < RR_; r0 += 32) {
        __syncthreads();
        for (int e = tid; e < 64*32; e += 256) {
            int row = e >> 5, rr = e & 31;
            Pq[row][rr] = phi_q[((size_t)(b*LL + l0 + row)*HH + h)*RR_ + r0 + rr];
        }
        for (int e = tid; e < 32*128; e += 256) {
            int rr = e >> 7, d = e & 127;
            KVs[rr][d] = KV[((size_t)bh*RR_ + r0 + rr)*DD + d];
        }
        __syncthreads();
        for (int rr = 0; rr < 32; ++rr) {
            float a[4];
            #pragma unroll
            for (int i = 0; i < 4; ++i) a[i] = Pq[ty*4+i][rr];
            float4 b0 = *(const float4*)&KVs[rr][tx*8];
            float4 b1 = *(const float4*)&KVs[rr][tx*8+4];
            float bv[8] = {b0.x,b0.y,b0.z,b0.w,b1.x,b1.y,b1.z,b1.w};
            #pragma unroll
            for (int i = 0; i < 4; ++i)
                #pragma unroll
                for (int j = 0; j < 8; ++j)
                    acc[i][j] += a[i]*bv[j];
        }
        if (tid < 64) {
            #pragma unroll
            for (int rr = 0; rr < 32; ++rr)
                den += (double)Pq[tid][rr]*Ks_s[r0 + rr];
        }
    }
    __syncthreads();
    if (tid < 64) den_s[tid] = den;
    __syncthreads();
    #pragma unroll
    for (int i = 0; i < 4; ++i) {
        const int l = l0 + ty*4 + i;
        const float inv = (float)(1.0 / (den_s[ty*4+i] + 1e-6));
        size_t base = ((size_t)(b*LL + l))*OC + h*DD + tx*8;
        *(float4*)&o_out[base]   = make_float4(acc[i][0]*inv, acc[i][1]*inv,
                                               acc[i][2]*inv, acc[i][3]*inv);
        *(float4*)&o_out[base+4] = make_float4(acc[i][4]*inv, acc[i][5]*inv,
                                               acc[i][6]*inv, acc[i][7]*inv);
    }
}

// ---------------------------------------------------------------------------
// Kernel 7a: output projection, split-K x4.
// ---------------------------------------------------------------------------
__global__ __launch_bounds__(256) void proj_part_k(
    const float* __restrict__ o_s, const float* __restrict__ pw,
    float* __restrict__ part)
{
    __shared__ float As[32][33];
    __shared__ float Bs[32][132];
    const int tid = threadIdx.x;
    const int row0 = blockIdx.x * 32;
    const int kbase = blockIdx.y * 256;
    const int ty = tid >> 5;
    const int tx = tid & 31;
    float acc[4][4] = {};

    for (int k0 = kbase; k0 < kbase + 256; k0 += 32) {
        __syncthreads();
        for (int e = tid; e < 32*32; e += 256) {
            int r = e >> 5, kk = e & 31;
            As[r][kk] = o_s[(size_t)(row0 + r)*OC + k0 + kk];
        }
        for (int e = tid; e < 32*128; e += 256) {
            int j = e >> 5, kk = e & 31;
            Bs[kk][j] = pw[(size_t)j*OC + k0 + kk];
        }
        __syncthreads();
        for (int kk = 0; kk < 32; ++kk) {
            float a[4];
            #pragma unroll
            for (int i = 0; i < 4; ++i) a[i] = As[ty*4+i][kk];
            float4 bq = *(const float4*)&Bs[kk][tx*4];
            float bv[4] = {bq.x,bq.y,bq.z,bq.w};
            #pragma unroll
            for (int i = 0; i < 4; ++i)
                #pragma unroll
                for (int j = 0; j < 4; ++j)
                    acc[i][j] += a[i]*bv[j];
        }
    }
    float* outp = part + (size_t)blockIdx.y*BL*DD;
    #pragma unroll
    for (int i = 0; i < 4; ++i)
        *(float4*)&outp[(size_t)(row0 + ty*4 + i)*DD + tx*4] =
            make_float4(acc[i][0],acc[i][1],acc[i][2],acc[i][3]);
}

// ---------------------------------------------------------------------------
// Kernel 7b: reduce the 4 K-split partials + bias.
// ---------------------------------------------------------------------------
__global__ __launch_bounds__(256) void proj_reduce_k(
    const float* __restrict__ part, const float* __restrict__ pb,
    float* __restrict__ out)
{
    const int gid = blockIdx.x*256 + threadIdx.x;   // 0 .. BL*DD/4-1
    if (gid >= BL*DD/4) return;
    const float4* p4 = (const float4*)part;
    float4 s = p4[gid];
    #pragma unroll
    for (int c = 1; c < 4; ++c) {
        float4 t = p4[gid + (size_t)c*(BL*DD/4)];
        s.x += t.x; s.y += t.y; s.z += t.z; s.w += t.w;
    }
    const int col = (gid << 2) & (DD-1);
    s.x += pb[col]; s.y += pb[col+1]; s.z += pb[col+2]; s.w += pb[col+3];
    ((float4*)out)[gid] = s;
}

// ---------------------------------------------------------------------------
extern "C" void kernel_launch(void* const* d_in, const int* in_sizes, int n_in,
                              void* d_out, int out_size, void* d_ws, size_t ws_size,
                              hipStream_t stream) {
    const float* x       = (const float*)d_in[0];
    const float* q_w     = (const float*)d_in[1];
    const float* q_b     = (const float*)d_in[2];
    const float* k_w     = (const float*)d_in[3];
    const float* k_b     = (const float*)d_in[4];
    const float* v_w     = (const float*)d_in[5];
    const float* g1_q    = (const float*)d_in[6];
    const float* g2_q    = (const float*)d_in[7];
    const float* g1_k    = (const float*)d_in[8];
    const float* g2_k    = (const float*)d_in[9];
    const float* gamma_q = (const float*)d_in[10];
    const float* beta_q  = (const float*)d_in[11];
    const float* gamma_k = (const float*)d_in[12];
    const float* beta_k  = (const float*)d_in[13];
    const float* proj_w  = (const float*)d_in[14];
    const float* proj_b  = (const float*)d_in[15];

    float* f = (float*)d_ws;
    float* q_s     = f;                        // 4,194,304 floats
    float* k_s     = f + 4194304;              // 4,194,304
    float* v_s     = f + 8388608;              // 4,194,304
    float* part_kv = f + 12582912;             // 4,194,304 (reused as proj partials)
    double* part_ks = (double*)(f + 16777216); // 32,768 doubles, 8B-aligned
    float* KVb     = f + 16842752;             // 262,144
    float* o_s     = k_s;                      // reuse (phi_k dead after kv_part_k)
    float* proj_part = part_kv;                // reuse (part_kv dead after kvreduce)

    dim3 blk(256);
    conv3_k  <<<dim3(64,16), blk, 0, stream>>>(x, q_w, q_b, gamma_q, beta_q, q_s);
    conv3_k  <<<dim3(64,16), blk, 0, stream>>>(x, k_w, k_b, gamma_k, beta_k, k_s);
    vproj_k  <<<dim3(64,16), blk, 0, stream>>>(x, v_w, v_s);
    sketch_k <<<512, blk, 0, stream>>>(q_s, g1_q, g2_q);
    sketch_k <<<512, blk, 0, stream>>>(k_s, g1_k, g2_k);
    kv_part_k<<<dim3(16,16), blk, 0, stream>>>(k_s, v_s, part_kv, part_ks);
    kvreduce_k<<<1024, blk, 0, stream>>>(part_kv, KVb);
    numden_k <<<dim3(32,16), blk, 0, stream>>>(q_s, KVb, part_ks, o_s);
    proj_part_k<<<dim3(128,4), blk, 0, stream>>>(o_s, proj_w, proj_part);
    proj_reduce_k<<<512, blk, 0, stream>>>(proj_part, proj_b, (float*)d_out);
}

// Round 7
// 467.178 us; speedup vs baseline: 1.4310x; 1.1922x over previous
//
#include <hip/hip_runtime.h>
#include <math.h>

// Problem constants
#define BB 2
#define DD 128
#define LL 2048
#define HH 8
#define OC 1024     // H*D
#define RR_ 128
#define BL (BB*LL)          // 4096
#define NROW (BL*HH)        // 32768

// Numerics ledger (absmax is bf16-quantized, ulp=32 at |o|~9e3; threshold 180.48):
//   full fp64 conv+sketch              -> 128  PASS (r3, comparison floor)
//   seq fp32 (eps_phi ~7e-7)           -> 192  FAIL (r2)
//   chunk-32 fp32 + tanhf (~5e-7)      -> 192  FAIL (r5)
//   conv chunk-4 + sketch chunk-8 fp64 -> 128  PASS (r6, eps_phi ~1.9e-7)
// r7: conv -> split-bf16 (3-plane) MFMA, 6 cross passes, per-chunk main acc
//     (chain 3, ~1e-7) + corr acc, fp64 epilogue combine. eps ~1.2e-7. Sketch
//     unchanged -> total ~1.6e-7, inside the proven-pass envelope.

typedef __bf16  bf16x8  __attribute__((ext_vector_type(8)));
typedef float   float4v __attribute__((ext_vector_type(4)));

// ---------------------------------------------------------------------------
// Kernel 0: encode conv weights (q and k) into 3 bf16 planes,
// layout wenc[plane][t][o(2048: q then k)][c(128)] for contiguous B-frags.
// ---------------------------------------------------------------------------
__global__ __launch_bounds__(256) void enc_w_k(
    const float* __restrict__ q_w, const float* __restrict__ k_w,
    __bf16* __restrict__ wenc)
{
    const int gid = blockIdx.x*256 + threadIdx.x;   // 0 .. 2048*128-1
    if (gid >= 2048*128) return;
    const int o = gid >> 7, c = gid & 127;
    #pragma unroll
    for (int t = 0; t < 3; ++t) {
        float v = (o < 1024) ? q_w[(o*128 + c)*3 + t]
                             : k_w[((o-1024)*128 + c)*3 + t];
        __bf16 h1 = (__bf16)v;  float r1 = v - (float)h1;
        __bf16 h2 = (__bf16)r1; float r2 = r1 - (float)h2;
        __bf16 h3 = (__bf16)r2;
        wenc[((size_t)(0*3 + t)*2048 + o)*128 + c] = h1;
        wenc[((size_t)(1*3 + t)*2048 + o)*128 + c] = h2;
        wenc[((size_t)(2*3 + t)*2048 + o)*128 + c] = h3;
    }
}

// ---------------------------------------------------------------------------
// Kernel 1: fused q+k causal conv1d K=3 as split-bf16 MFMA GEMM.
// M = 4096 rows (b,l), N = 2048 (q 0..1023 | k 1024..2047), K = 128c x 3t.
// Block: 32 l x 64 o, 4 waves (wave w: o-sub w*16, 2 l-tiles of 16).
// Per 32-c chunk: stage x tile (34 l x 32 c) encoded to 3 bf16 planes in LDS.
// Passes kept: 11(main, per-chunk acc) + 12,21,13,31,22 (corr acc).
// Epilogue: fp64 combine + bias + gamma/beta, store fp32.
// ---------------------------------------------------------------------------
__global__ __launch_bounds__(256) void conv_mfma_k(
    const float* __restrict__ x, const __bf16* __restrict__ wenc,
    const float* __restrict__ q_b, const float* __restrict__ k_b,
    const float* __restrict__ gamma_q, const float* __restrict__ beta_q,
    const float* __restrict__ gamma_k, const float* __restrict__ beta_k,
    float* __restrict__ q_s, float* __restrict__ k_s)
{
    __shared__ __bf16 xs[3][34][40];   // [plane][l row: l0-2..l0+31][c pad 40]
    const int tid  = threadIdx.x;
    const int wave = tid >> 6;
    const int lane = tid & 63;
    const int m    = lane & 15;        // A/D row index within tile
    const int quad = lane >> 4;        // 0..3
    const int bx = blockIdx.x;         // 128 l-blocks of 32 rows
    const int b  = bx >> 6;
    const int lb0 = (bx & 63) << 5;    // l within batch
    const int o0 = blockIdx.y << 6;    // 64-wide o tile
    const int osub = o0 + wave*16;

    float4v accm[2][4];   // [l-tile][c-chunk] main-pass accumulators
    float4v corr[2];      // correction-pass accumulators
    #pragma unroll
    for (int lt = 0; lt < 2; ++lt) {
        corr[lt] = (float4v){0.f,0.f,0.f,0.f};
        #pragma unroll
        for (int c = 0; c < 4; ++c) accm[lt][c] = (float4v){0.f,0.f,0.f,0.f};
    }

    for (int cidx = 0; cidx < 4; ++cidx) {
        const int c0 = cidx << 5;
        // ---- stage + 3-plane encode x tile ----
        __syncthreads();
        for (int e = tid; e < 34*32; e += 256) {
            int c = e / 34, row = e % 34;
            int gl = lb0 - 2 + row;
            float v = (gl >= 0) ? x[((size_t)(b*DD + c0 + c))*LL + gl] : 0.f;
            __bf16 h1 = (__bf16)v;  float r1 = v - (float)h1;
            __bf16 h2 = (__bf16)r1; float r2 = r1 - (float)h2;
            __bf16 h3 = (__bf16)r2;
            xs[0][row][c] = h1; xs[1][row][c] = h2; xs[2][row][c] = h3;
        }
        __syncthreads();
        // ---- MFMA passes ----
        #pragma unroll
        for (int t = 0; t < 3; ++t) {
            // B-frags: 3 planes, direct global->reg (L2-cached)
            bf16x8 B1, B2, B3;
            {
                size_t base = ((size_t)t*2048 + osub + m)*128 + c0 + quad*8;
                B1 = *(const bf16x8*)&wenc[base];
                B2 = *(const bf16x8*)&wenc[base + (size_t)3*2048*128];
                B3 = *(const bf16x8*)&wenc[base + (size_t)6*2048*128];
            }
            #pragma unroll
            for (int lt = 0; lt < 2; ++lt) {
                const int row = lt*16 + m + t;       // staged row (l + t - 2)
                bf16x8 A1 = *(const bf16x8*)&xs[0][row][quad*8];
                bf16x8 A2 = *(const bf16x8*)&xs[1][row][quad*8];
                bf16x8 A3 = *(const bf16x8*)&xs[2][row][quad*8];
                accm[lt][cidx] = __builtin_amdgcn_mfma_f32_16x16x32_bf16(A1, B1, accm[lt][cidx], 0, 0, 0);
                corr[lt] = __builtin_amdgcn_mfma_f32_16x16x32_bf16(A1, B2, corr[lt], 0, 0, 0);
                corr[lt] = __builtin_amdgcn_mfma_f32_16x16x32_bf16(A2, B1, corr[lt], 0, 0, 0);
                corr[lt] = __builtin_amdgcn_mfma_f32_16x16x32_bf16(A1, B3, corr[lt], 0, 0, 0);
                corr[lt] = __builtin_amdgcn_mfma_f32_16x16x32_bf16(A3, B1, corr[lt], 0, 0, 0);
                corr[lt] = __builtin_amdgcn_mfma_f32_16x16x32_bf16(A2, B2, corr[lt], 0, 0, 0);
            }
        }
    }

    // ---- epilogue: fp64 combine, affine, store ----
    const int is_k = (o0 >= 1024);
    const double g  = (double)(is_k ? gamma_k[0] : gamma_q[0]);
    const double be = (double)(is_k ? beta_k[0]  : beta_q[0]);
    const int o_global = osub + m;     // D col = n = lane&15
    const int o_local  = o_global - (is_k ? 1024 : 0);
    const double bias  = (double)(is_k ? k_b[o_local] : q_b[o_local]);
    float* dest = is_k ? k_s : q_s;
    #pragma unroll
    for (int lt = 0; lt < 2; ++lt) {
        #pragma unroll
        for (int reg = 0; reg < 4; ++reg) {
            double s = (double)corr[lt][reg];
            #pragma unroll
            for (int c = 0; c < 4; ++c) s += (double)accm[lt][c][reg];
            const int rowm = quad*4 + reg;           // D row = m
            const int l = lb0 + lt*16 + rowm;
            dest[((size_t)(b*LL + l))*OC + o_local] = (float)(g*(s + bias) + be);
        }
    }
}

// ---------------------------------------------------------------------------
// Kernel 2: V projection (conv K=1, no bias). fp32 (numerator-only path).
// ---------------------------------------------------------------------------
__global__ __launch_bounds__(256) void vproj_k(
    const float* __restrict__ x, const float* __restrict__ vw,
    float* __restrict__ v_out)
{
    __shared__ float xsv[32][65];
    __shared__ float wsv[64][33];
    const int tid = threadIdx.x;
    const int tile = blockIdx.x;
    const int b  = tile >> 5;
    const int l0 = (tile & 31) << 6;
    const int o0 = blockIdx.y << 6;
    const int ty = tid >> 4;
    const int tx = tid & 15;
    float acc[4][4] = {};

    for (int c0 = 0; c0 < DD; c0 += 32) {
        for (int e = tid; e < 32*64; e += 256) {
            int c = e >> 6, j = e & 63;
            xsv[c][j] = x[(b*DD + c0 + c)*LL + l0 + j];
        }
        for (int e = tid; e < 64*32; e += 256) {
            int o = e >> 5, c = e & 31;
            wsv[o][c] = vw[(o0 + o)*DD + c0 + c];
        }
        __syncthreads();
        for (int cc = 0; cc < 32; ++cc) {
            float xv[4], wv[4];
            #pragma unroll
            for (int j = 0; j < 4; ++j) xv[j] = xsv[cc][ty*4 + j];
            #pragma unroll
            for (int i = 0; i < 4; ++i) wv[i] = wsv[tx*4+i][cc];
            #pragma unroll
            for (int i = 0; i < 4; ++i)
                #pragma unroll
                for (int j = 0; j < 4; ++j)
                    acc[i][j] += wv[i]*xv[j];
        }
        __syncthreads();
    }
    #pragma unroll
    for (int j = 0; j < 4; ++j) {
        const int l = l0 + ty*4 + j;
        float4 r = make_float4(acc[0][j], acc[1][j], acc[2][j], acc[3][j]);
        *(float4*)&v_out[(size_t)(b*LL + l)*OC + o0 + tx*4] = r;
    }
}

// ---------------------------------------------------------------------------
// Kernel 3: sketch, in-place. fp32 FMAs within 8-k sub-chunks, fp64
// inter-chunk; fp64 z and tanh. (r6-proven numerics, unchanged)
// ---------------------------------------------------------------------------
__global__ __launch_bounds__(256) void sketch_k(
    float* __restrict__ buf, const float* __restrict__ g1,
    const float* __restrict__ g2)
{
    __shared__ float Qs[64][33];
    __shared__ float G1s[32][132];
    __shared__ float G2s[32][132];
    const int tid = threadIdx.x;
    const size_t i0 = (size_t)blockIdx.x * 64;
    const int ty = tid >> 4;
    const int tx = tid & 15;
    double u1d[4][8] = {}, u2d[4][8] = {};

    for (int k0 = 0; k0 < DD; k0 += 32) {
        __syncthreads();
        for (int e = tid; e < 64*32; e += 256) {
            int row = e >> 5, kk = e & 31;
            Qs[row][kk] = buf[(i0 + row)*RR_ + k0 + kk];
        }
        for (int e = tid; e < 32*128; e += 256) {
            int kk = e >> 7, r = e & 127;
            G1s[kk][r] = g1[(k0 + kk)*RR_ + r];
            G2s[kk][r] = g2[(k0 + kk)*RR_ + r];
        }
        __syncthreads();
        for (int kk0 = 0; kk0 < 32; kk0 += 8) {
            float u1[4][8] = {}, u2[4][8] = {};
            #pragma unroll
            for (int u = 0; u < 8; ++u) {
                const int kk = kk0 + u;
                float a[4];
                #pragma unroll
                for (int i = 0; i < 4; ++i) a[i] = Qs[ty*4+i][kk];
                float4 c0 = *(const float4*)&G1s[kk][tx*8];
                float4 c1 = *(const float4*)&G1s[kk][tx*8+4];
                float4 d0 = *(const float4*)&G2s[kk][tx*8];
                float4 d1 = *(const float4*)&G2s[kk][tx*8+4];
                float b1[8] = {c0.x,c0.y,c0.z,c0.w,c1.x,c1.y,c1.z,c1.w};
                float b2[8] = {d0.x,d0.y,d0.z,d0.w,d1.x,d1.y,d1.z,d1.w};
                #pragma unroll
                for (int i = 0; i < 4; ++i)
                    #pragma unroll
                    for (int j = 0; j < 8; ++j) {
                        u1[i][j] += a[i]*b1[j];
                        u2[i][j] += a[i]*b2[j];
                    }
            }
            #pragma unroll
            for (int i = 0; i < 4; ++i)
                #pragma unroll
                for (int j = 0; j < 8; ++j) {
                    u1d[i][j] += (double)u1[i][j];
                    u2d[i][j] += (double)u2[i][j];
                }
        }
    }
    const double SR  = 11.313708498984760390;   // sqrt(128)
    const double ISR = 0.088388347648318440550; // 1/sqrt(128)
    #pragma unroll
    for (int i = 0; i < 4; ++i) {
        float out[8];
        #pragma unroll
        for (int j = 0; j < 8; ++j)
            out[j] = (float)(SR * tanh(u1d[i][j]*u2d[i][j]*ISR));
        size_t base = (i0 + ty*4 + i)*RR_ + tx*8;
        *(float4*)&buf[base]   = make_float4(out[0],out[1],out[2],out[3]);
        *(float4*)&buf[base+4] = make_float4(out[4],out[5],out[6],out[7]);
    }
}

// ---------------------------------------------------------------------------
// Kernel 4: partial KV (fp32) + Ksum (fp64) per (b,h,l-chunk of 128).
// ---------------------------------------------------------------------------
__global__ __launch_bounds__(256) void kv_part_k(
    const float* __restrict__ phi_k, const float* __restrict__ v,
    float* __restrict__ part_kv, double* __restrict__ part_ks)
{
    __shared__ float Ps[32][132];
    __shared__ float Vs[32][132];
    const int tid = threadIdx.x;
    const int chunk = blockIdx.x;   // 16
    const int bh = blockIdx.y;      // 16
    const int b = bh >> 3, h = bh & 7;
    const int lbase = chunk * 128;
    const int ty = tid >> 4;
    const int tx = tid & 15;
    float acc[8][8] = {};
    double ks = 0.0;

    for (int ls = 0; ls < 128; ls += 32) {
        for (int e = tid; e < 32*128; e += 256) {
            int ll = e >> 7, r = e & 127;
            size_t base = ((size_t)(b*LL + lbase + ls + ll)*HH + h)*RR_;
            Ps[ll][r] = phi_k[base + r];
            Vs[ll][r] = v[base + r];
        }
        __syncthreads();
        for (int ll = 0; ll < 32; ++ll) {
            float4 a0 = *(const float4*)&Ps[ll][ty*8];
            float4 a1 = *(const float4*)&Ps[ll][ty*8+4];
            float4 b0 = *(const float4*)&Vs[ll][tx*8];
            float4 b1 = *(const float4*)&Vs[ll][tx*8+4];
            float av[8] = {a0.x,a0.y,a0.z,a0.w,a1.x,a1.y,a1.z,a1.w};
            float bv[8] = {b0.x,b0.y,b0.z,b0.w,b1.x,b1.y,b1.z,b1.w};
            #pragma unroll
            for (int i = 0; i < 8; ++i)
                #pragma unroll
                for (int j = 0; j < 8; ++j)
                    acc[i][j] += av[i]*bv[j];
        }
        if (tid < 128) {
            #pragma unroll 8
            for (int ll = 0; ll < 32; ++ll) ks += (double)Ps[ll][tid];
        }
        __syncthreads();
    }
    float* outp = part_kv + ((size_t)(bh*16 + chunk))*RR_*DD;
    #pragma unroll
    for (int i = 0; i < 8; ++i) {
        int r = ty*8 + i;
        *(float4*)&outp[r*DD + tx*8]   = make_float4(acc[i][0],acc[i][1],acc[i][2],acc[i][3]);
        *(float4*)&outp[r*DD + tx*8+4] = make_float4(acc[i][4],acc[i][5],acc[i][6],acc[i][7]);
    }
    if (tid < 128) part_ks[(bh*16 + chunk)*RR_ + tid] = ks;
}

// ---------------------------------------------------------------------------
// Kernel 5: reduce partial KV over 16 chunks.
// ---------------------------------------------------------------------------
__global__ __launch_bounds__(256) void kvreduce_k(
    const float* __restrict__ part_kv, float* __restrict__ KV)
{
    const int gid = blockIdx.x*256 + threadIdx.x;
    if (gid >= 16*RR_*DD) return;
    const int bh = gid >> 14;
    const int rd = gid & 16383;
    float s = 0.f;
    #pragma unroll
    for (int c = 0; c < 16; ++c)
        s += part_kv[(((size_t)(bh*16 + c)) << 14) + rd];
    KV[gid] = s;
}

// ---------------------------------------------------------------------------
// Kernel 6: o = (phi_q @ KV) / (phi_q . Ksum + 1e-6). Den path in fp64.
// ---------------------------------------------------------------------------
__global__ __launch_bounds__(256) void numden_k(
    const float* __restrict__ phi_q, const float* __restrict__ KV,
    const double* __restrict__ part_ks, float* __restrict__ o_out)
{
    __shared__ float Pq[64][33];
    __shared__ float KVs[32][132];
    __shared__ double Ks_s[128];
    __shared__ double den_s[64];
    const int tid = threadIdx.x;
    const int lt = blockIdx.x;
    const int bh = blockIdx.y;
    const int b = bh >> 3, h = bh & 7;
    const int l0 = lt * 64;
    if (tid < 128) {
        double s = 0.0;
        #pragma unroll
        for (int c = 0; c < 16; ++c) s += part_ks[(bh*16 + c)*RR_ + tid];
        Ks_s[tid] = s;
    }
    const int ty = tid >> 4;
    const int tx = tid & 15;
    float acc[4][8] = {};
    double den = 0.0;

    for (int r0 = 0; r0 < RR_; r0 += 32) {
        __syncthreads();
        for (int e = tid; e < 64*32; e += 256) {
            int row = e >> 5, rr = e & 31;
            Pq[row][rr] = phi_q[((size_t)(b*LL + l0 + row)*HH + h)*RR_ + r0 + rr];
        }
        for (int e = tid; e < 32*128; e += 256) {
            int rr = e >> 7, d = e & 127;
            KVs[rr][d] = KV[((size_t)bh*RR_ + r0 + rr)*DD + d];
        }
        __syncthreads();
        for (int rr = 0; rr < 32; ++rr) {
            float a[4];
            #pragma unroll
            for (int i = 0; i < 4; ++i) a[i] = Pq[ty*4+i][rr];
            float4 b0 = *(const float4*)&KVs[rr][tx*8];
            float4 b1 = *(const float4*)&KVs[rr][tx*8+4];
            float bv[8] = {b0.x,b0.y,b0.z,b0.w,b1.x,b1.y,b1.z,b1.w};
            #pragma unroll
            for (int i = 0; i < 4; ++i)
                #pragma unroll
                for (int j = 0; j < 8; ++j)
                    acc[i][j] += a[i]*bv[j];
        }
        if (tid < 64) {
            #pragma unroll
            for (int rr = 0; rr < 32; ++rr)
                den += (double)Pq[tid][rr]*Ks_s[r0 + rr];
        }
    }
    __syncthreads();
    if (tid < 64) den_s[tid] = den;
    __syncthreads();
    #pragma unroll
    for (int i = 0; i < 4; ++i) {
        const int l = l0 + ty*4 + i;
        const float inv = (float)(1.0 / (den_s[ty*4+i] + 1e-6));
        size_t base = ((size_t)(b*LL + l))*OC + h*DD + tx*8;
        *(float4*)&o_out[base]   = make_float4(acc[i][0]*inv, acc[i][1]*inv,
                                               acc[i][2]*inv, acc[i][3]*inv);
        *(float4*)&o_out[base+4] = make_float4(acc[i][4]*inv, acc[i][5]*inv,
                                               acc[i][6]*inv, acc[i][7]*inv);
    }
}

// ---------------------------------------------------------------------------
// Kernel 7a: output projection, split-K x4.
// ---------------------------------------------------------------------------
__global__ __launch_bounds__(256) void proj_part_k(
    const float* __restrict__ o_s, const float* __restrict__ pw,
    float* __restrict__ part)
{
    __shared__ float As[32][33];
    __shared__ float Bs[32][132];
    const int tid = threadIdx.x;
    const int row0 = blockIdx.x * 32;
    const int kbase = blockIdx.y * 256;
    const int ty = tid >> 5;
    const int tx = tid & 31;
    float acc[4][4] = {};

    for (int k0 = kbase; k0 < kbase + 256; k0 += 32) {
        __syncthreads();
        for (int e = tid; e < 32*32; e += 256) {
            int r = e >> 5, kk = e & 31;
            As[r][kk] = o_s[(size_t)(row0 + r)*OC + k0 + kk];
        }
        for (int e = tid; e < 32*128; e += 256) {
            int j = e >> 5, kk = e & 31;
            Bs[kk][j] = pw[(size_t)j*OC + k0 + kk];
        }
        __syncthreads();
        for (int kk = 0; kk < 32; ++kk) {
            float a[4];
            #pragma unroll
            for (int i = 0; i < 4; ++i) a[i] = As[ty*4+i][kk];
            float4 bq = *(const float4*)&Bs[kk][tx*4];
            float bv[4] = {bq.x,bq.y,bq.z,bq.w};
            #pragma unroll
            for (int i = 0; i < 4; ++i)
                #pragma unroll
                for (int j = 0; j < 4; ++j)
                    acc[i][j] += a[i]*bv[j];
        }
    }
    float* outp = part + (size_t)blockIdx.y*BL*DD;
    #pragma unroll
    for (int i = 0; i < 4; ++i)
        *(float4*)&outp[(size_t)(row0 + ty*4 + i)*DD + tx*4] =
            make_float4(acc[i][0],acc[i][1],acc[i][2],acc[i][3]);
}

// ---------------------------------------------------------------------------
// Kernel 7b: reduce the 4 K-split partials + bias.
// ---------------------------------------------------------------------------
__global__ __launch_bounds__(256) void proj_reduce_k(
    const float* __restrict__ part, const float* __restrict__ pb,
    float* __restrict__ out)
{
    const int gid = blockIdx.x*256 + threadIdx.x;   // 0 .. BL*DD/4-1
    if (gid >= BL*DD/4) return;
    const float4* p4 = (const float4*)part;
    float4 s = p4[gid];
    #pragma unroll
    for (int c = 1; c < 4; ++c) {
        float4 t = p4[gid + (size_t)c*(BL*DD/4)];
        s.x += t.x; s.y += t.y; s.z += t.z; s.w += t.w;
    }
    const int col = (gid << 2) & (DD-1);
    s.x += pb[col]; s.y += pb[col+1]; s.z += pb[col+2]; s.w += pb[col+3];
    ((float4*)out)[gid] = s;
}

// ---------------------------------------------------------------------------
extern "C" void kernel_launch(void* const* d_in, const int* in_sizes, int n_in,
                              void* d_out, int out_size, void* d_ws, size_t ws_size,
                              hipStream_t stream) {
    const float* x       = (const float*)d_in[0];
    const float* q_w     = (const float*)d_in[1];
    const float* q_b     = (const float*)d_in[2];
    const float* k_w     = (const float*)d_in[3];
    const float* k_b     = (const float*)d_in[4];
    const float* v_w     = (const float*)d_in[5];
    const float* g1_q    = (const float*)d_in[6];
    const float* g2_q    = (const float*)d_in[7];
    const float* g1_k    = (const float*)d_in[8];
    const float* g2_k    = (const float*)d_in[9];
    const float* gamma_q = (const float*)d_in[10];
    const float* beta_q  = (const float*)d_in[11];
    const float* gamma_k = (const float*)d_in[12];
    const float* beta_k  = (const float*)d_in[13];
    const float* proj_w  = (const float*)d_in[14];
    const float* proj_b  = (const float*)d_in[15];

    float* f = (float*)d_ws;
    float* q_s     = f;                        // 4,194,304 floats
    float* k_s     = f + 4194304;              // 4,194,304
    float* v_s     = f + 8388608;              // 4,194,304
    float* part_kv = f + 12582912;             // 4,194,304 (wenc / proj partials share)
    double* part_ks = (double*)(f + 16777216); // 32,768 doubles, 8B-aligned
    float* KVb     = f + 16842752;             // 262,144
    float* o_s     = k_s;                      // reuse (phi_k dead after kv_part_k)
    float* proj_part = part_kv;                // reuse (part_kv dead after kvreduce)
    __bf16* wenc   = (__bf16*)part_kv;         // 2.36M bf16 (4.7 MB), dead before kv_part_k

    dim3 blk(256);
    enc_w_k  <<<1024, blk, 0, stream>>>(q_w, k_w, wenc);
    conv_mfma_k<<<dim3(128,32), blk, 0, stream>>>(x, wenc, q_b, k_b,
                                                  gamma_q, beta_q, gamma_k, beta_k,
                                                  q_s, k_s);
    vproj_k  <<<dim3(64,16), blk, 0, stream>>>(x, v_w, v_s);
    sketch_k <<<512, blk, 0, stream>>>(q_s, g1_q, g2_q);
    sketch_k <<<512, blk, 0, stream>>>(k_s, g1_k, g2_k);
    kv_part_k<<<dim3(16,16), blk, 0, stream>>>(k_s, v_s, part_kv, part_ks);
    kvreduce_k<<<1024, blk, 0, stream>>>(part_kv, KVb);
    numden_k <<<dim3(32,16), blk, 0, stream>>>(q_s, KVb, part_ks, o_s);
    proj_part_k<<<dim3(128,4), blk, 0, stream>>>(o_s, proj_w, proj_part);
    proj_reduce_k<<<512, blk, 0, stream>>>(proj_part, proj_b, (float*)d_out);
}

// Round 8
// 395.239 us; speedup vs baseline: 1.6915x; 1.1820x over previous
//
#include <hip/hip_runtime.h>
#include <math.h>

// Problem constants
#define BB 2
#define DD 128
#define LL 2048
#define HH 8
#define OC 1024     // H*D
#define RR_ 128
#define BL (BB*LL)          // 4096
#define NROW (BL*HH)        // 32768

// Numerics ledger (absmax bf16-quantized; threshold 180.48):
//   r3  full fp64 conv+sketch             -> 128 PASS
//   r2  seq fp32 (eps~7e-7)               -> 192 FAIL
//   r5  chunk-32 fp32 + tanhf (~5e-7)     -> 192 FAIL
//   r6  conv chunk-4 + sketch chunk-8     -> 128 PASS (eps ~1.9e-7)
//   r7  conv = split-bf16 MFMA 3-plane/6-pass -> 64 PASS (conv eps ~6e-8)
// r8: sketch -> same 3-plane/6-pass MFMA (single fp32 main acc over K=128,
//     chain of 4 MFMAs ~ conv's proven chunks; corr acc separate; fp64
//     z+tanh epilogue). vproj -> 2-plane/4-pass MFMA (numerator path,
//     rel ~6e-8, budget ~1e-5).

typedef __bf16  bf16x8  __attribute__((ext_vector_type(8)));
typedef float   float4v __attribute__((ext_vector_type(4)));

// ---------------------------------------------------------------------------
// Kernel 0: encode all weights to bf16 planes.
//  wenc[plane(3)][t(3)][o(2048: q|k)][c(128)]            (conv q+k)
//  genc[mat(4: g1q,g2q,g1k,g2k)][plane(3)][r(128)][d(128)] (transposed!)
//  venc[plane(2)][o(1024)][c(128)]                        (v_w)
// ---------------------------------------------------------------------------
__global__ __launch_bounds__(256) void enc_all_k(
    const float* __restrict__ q_w, const float* __restrict__ k_w,
    const float* __restrict__ v_w,
    const float* __restrict__ g1_q, const float* __restrict__ g2_q,
    const float* __restrict__ g1_k, const float* __restrict__ g2_k,
    __bf16* __restrict__ wenc, __bf16* __restrict__ genc,
    __bf16* __restrict__ venc)
{
    const int gid = blockIdx.x*256 + threadIdx.x;
    if (gid < 262144) {                       // conv weights
        const int o = gid >> 7, c = gid & 127;
        #pragma unroll
        for (int t = 0; t < 3; ++t) {
            float v = (o < 1024) ? q_w[(o*128 + c)*3 + t]
                                 : k_w[((o-1024)*128 + c)*3 + t];
            __bf16 h1 = (__bf16)v;  float r1 = v - (float)h1;
            __bf16 h2 = (__bf16)r1; float r2 = r1 - (float)h2;
            __bf16 h3 = (__bf16)r2;
            wenc[((size_t)(0*3 + t)*2048 + o)*128 + c] = h1;
            wenc[((size_t)(1*3 + t)*2048 + o)*128 + c] = h2;
            wenc[((size_t)(2*3 + t)*2048 + o)*128 + c] = h3;
        }
    } else if (gid < 262144 + 65536) {        // sketch G matrices (transposed)
        const int g = gid - 262144;
        const int mat = g >> 14, rem = g & 16383;
        const int r = rem >> 7, d = rem & 127;
        const float* src = (mat == 0) ? g1_q : (mat == 1) ? g2_q
                         : (mat == 2) ? g1_k : g2_k;
        float v = src[d*RR_ + r];             // transpose: B[n=r][k=d]
        __bf16 h1 = (__bf16)v;  float r1 = v - (float)h1;
        __bf16 h2 = (__bf16)r1; float r2 = r1 - (float)h2;
        __bf16 h3 = (__bf16)r2;
        genc[((size_t)(mat*3 + 0)*128 + r)*128 + d] = h1;
        genc[((size_t)(mat*3 + 1)*128 + r)*128 + d] = h2;
        genc[((size_t)(mat*3 + 2)*128 + r)*128 + d] = h3;
    } else if (gid < 262144 + 65536 + 131072) { // v weights (2 planes)
        const int g = gid - 262144 - 65536;
        const int o = g >> 7, c = g & 127;
        float v = v_w[o*128 + c];
        __bf16 h1 = (__bf16)v;  float r1 = v - (float)h1;
        __bf16 h2 = (__bf16)r1;
        venc[((size_t)0*1024 + o)*128 + c] = h1;
        venc[((size_t)1*1024 + o)*128 + c] = h2;
    }
}

// ---------------------------------------------------------------------------
// Kernel 1: fused q+k causal conv1d K=3 as split-bf16 MFMA GEMM (r7-proven).
// ---------------------------------------------------------------------------
__global__ __launch_bounds__(256) void conv_mfma_k(
    const float* __restrict__ x, const __bf16* __restrict__ wenc,
    const float* __restrict__ q_b, const float* __restrict__ k_b,
    const float* __restrict__ gamma_q, const float* __restrict__ beta_q,
    const float* __restrict__ gamma_k, const float* __restrict__ beta_k,
    float* __restrict__ q_s, float* __restrict__ k_s)
{
    __shared__ __bf16 xs[3][34][40];
    const int tid  = threadIdx.x;
    const int wave = tid >> 6;
    const int lane = tid & 63;
    const int m    = lane & 15;
    const int quad = lane >> 4;
    const int bx = blockIdx.x;
    const int b  = bx >> 6;
    const int lb0 = (bx & 63) << 5;
    const int o0 = blockIdx.y << 6;
    const int osub = o0 + wave*16;

    float4v accm[2][4];
    float4v corr[2];
    #pragma unroll
    for (int lt = 0; lt < 2; ++lt) {
        corr[lt] = (float4v){0.f,0.f,0.f,0.f};
        #pragma unroll
        for (int c = 0; c < 4; ++c) accm[lt][c] = (float4v){0.f,0.f,0.f,0.f};
    }

    for (int cidx = 0; cidx < 4; ++cidx) {
        const int c0 = cidx << 5;
        __syncthreads();
        for (int e = tid; e < 34*32; e += 256) {
            int c = e / 34, row = e % 34;
            int gl = lb0 - 2 + row;
            float v = (gl >= 0) ? x[((size_t)(b*DD + c0 + c))*LL + gl] : 0.f;
            __bf16 h1 = (__bf16)v;  float r1 = v - (float)h1;
            __bf16 h2 = (__bf16)r1; float r2 = r1 - (float)h2;
            __bf16 h3 = (__bf16)r2;
            xs[0][row][c] = h1; xs[1][row][c] = h2; xs[2][row][c] = h3;
        }
        __syncthreads();
        #pragma unroll
        for (int t = 0; t < 3; ++t) {
            bf16x8 B1, B2, B3;
            {
                size_t base = ((size_t)t*2048 + osub + m)*128 + c0 + quad*8;
                B1 = *(const bf16x8*)&wenc[base];
                B2 = *(const bf16x8*)&wenc[base + (size_t)3*2048*128];
                B3 = *(const bf16x8*)&wenc[base + (size_t)6*2048*128];
            }
            #pragma unroll
            for (int lt = 0; lt < 2; ++lt) {
                const int row = lt*16 + m + t;
                bf16x8 A1 = *(const bf16x8*)&xs[0][row][quad*8];
                bf16x8 A2 = *(const bf16x8*)&xs[1][row][quad*8];
                bf16x8 A3 = *(const bf16x8*)&xs[2][row][quad*8];
                accm[lt][cidx] = __builtin_amdgcn_mfma_f32_16x16x32_bf16(A1, B1, accm[lt][cidx], 0, 0, 0);
                corr[lt] = __builtin_amdgcn_mfma_f32_16x16x32_bf16(A1, B2, corr[lt], 0, 0, 0);
                corr[lt] = __builtin_amdgcn_mfma_f32_16x16x32_bf16(A2, B1, corr[lt], 0, 0, 0);
                corr[lt] = __builtin_amdgcn_mfma_f32_16x16x32_bf16(A1, B3, corr[lt], 0, 0, 0);
                corr[lt] = __builtin_amdgcn_mfma_f32_16x16x32_bf16(A3, B1, corr[lt], 0, 0, 0);
                corr[lt] = __builtin_amdgcn_mfma_f32_16x16x32_bf16(A2, B2, corr[lt], 0, 0, 0);
            }
        }
    }

    const int is_k = (o0 >= 1024);
    const double g  = (double)(is_k ? gamma_k[0] : gamma_q[0]);
    const double be = (double)(is_k ? beta_k[0]  : beta_q[0]);
    const int o_global = osub + m;
    const int o_local  = o_global - (is_k ? 1024 : 0);
    const double bias  = (double)(is_k ? k_b[o_local] : q_b[o_local]);
    float* dest = is_k ? k_s : q_s;
    #pragma unroll
    for (int lt = 0; lt < 2; ++lt) {
        #pragma unroll
        for (int reg = 0; reg < 4; ++reg) {
            double s = (double)corr[lt][reg];
            #pragma unroll
            for (int c = 0; c < 4; ++c) s += (double)accm[lt][c][reg];
            const int rowm = quad*4 + reg;
            const int l = lb0 + lt*16 + rowm;
            dest[((size_t)(b*LL + l))*OC + o_local] = (float)(g*(s + bias) + be);
        }
    }
}

// ---------------------------------------------------------------------------
// Kernel 2: V projection as 2-plane split-bf16 MFMA (numerator path).
// M=4096(b,l), N=1024(o), K=128(c). Block: 32 l x 128 o, 4 waves.
// ---------------------------------------------------------------------------
__global__ __launch_bounds__(256) void vproj_mfma_k(
    const float* __restrict__ x, const __bf16* __restrict__ venc,
    float* __restrict__ v_out)
{
    __shared__ __bf16 As[2][32][136];
    const int tid  = threadIdx.x;
    const int wave = tid >> 6;
    const int lane = tid & 63;
    const int m    = lane & 15;
    const int quad = lane >> 4;
    const int bx = blockIdx.x;
    const int b  = bx >> 6;
    const int l0 = (bx & 63) << 5;
    const int o0 = blockIdx.y << 7;       // 128-wide o tile

    // stage + encode x tile (transpose [c][l] -> [l][c])
    for (int e = tid; e < 32*128; e += 256) {
        int c = e >> 5, lofs = e & 31;
        float v = x[((size_t)(b*DD + c))*LL + l0 + lofs];
        __bf16 h1 = (__bf16)v;  float r1 = v - (float)h1;
        __bf16 h2 = (__bf16)r1;
        As[0][lofs][c] = h1; As[1][lofs][c] = h2;
    }
    __syncthreads();

    float4v accm[2][2], corr[2][2];   // [mt][nt]
    #pragma unroll
    for (int mt = 0; mt < 2; ++mt)
        #pragma unroll
        for (int nt = 0; nt < 2; ++nt) {
            accm[mt][nt] = (float4v){0.f,0.f,0.f,0.f};
            corr[mt][nt] = (float4v){0.f,0.f,0.f,0.f};
        }

    #pragma unroll
    for (int ck = 0; ck < 4; ++ck) {
        const int k0 = ck << 5;
        bf16x8 A1[2], A2[2];
        #pragma unroll
        for (int mt = 0; mt < 2; ++mt) {
            A1[mt] = *(const bf16x8*)&As[0][mt*16 + m][k0 + quad*8];
            A2[mt] = *(const bf16x8*)&As[1][mt*16 + m][k0 + quad*8];
        }
        #pragma unroll
        for (int nt = 0; nt < 2; ++nt) {
            const int o = o0 + wave*32 + nt*16 + m;
            size_t base = ((size_t)o)*128 + k0 + quad*8;
            bf16x8 B1 = *(const bf16x8*)&venc[base];
            bf16x8 B2 = *(const bf16x8*)&venc[base + (size_t)1024*128];
            #pragma unroll
            for (int mt = 0; mt < 2; ++mt) {
                accm[mt][nt] = __builtin_amdgcn_mfma_f32_16x16x32_bf16(A1[mt], B1, accm[mt][nt], 0, 0, 0);
                corr[mt][nt] = __builtin_amdgcn_mfma_f32_16x16x32_bf16(A1[mt], B2, corr[mt][nt], 0, 0, 0);
                corr[mt][nt] = __builtin_amdgcn_mfma_f32_16x16x32_bf16(A2[mt], B1, corr[mt][nt], 0, 0, 0);
                corr[mt][nt] = __builtin_amdgcn_mfma_f32_16x16x32_bf16(A2[mt], B2, corr[mt][nt], 0, 0, 0);
            }
        }
    }

    #pragma unroll
    for (int mt = 0; mt < 2; ++mt)
        #pragma unroll
        for (int nt = 0; nt < 2; ++nt)
            #pragma unroll
            for (int reg = 0; reg < 4; ++reg) {
                const int l = l0 + mt*16 + quad*4 + reg;
                const int o = o0 + wave*32 + nt*16 + m;
                v_out[((size_t)(b*LL + l))*OC + o] = accm[mt][nt][reg] + corr[mt][nt][reg];
            }
}

// ---------------------------------------------------------------------------
// Kernel 3: sketch as 3-plane/6-pass split-bf16 MFMA, in-place.
// M=32768 rows, N=128(u1)+128(u2) fused via shared A, K=128.
// Block: 32 rows; wave w covers cols [w*32, w*32+16*2) of BOTH mats.
// Epilogue: fp64 z + tanh (r6-proven).
// ---------------------------------------------------------------------------
__global__ __launch_bounds__(256) void sketch_mfma_k(
    float* __restrict__ buf, const __bf16* __restrict__ genc)
{
    __shared__ __bf16 As[3][32][136];
    const int tid  = threadIdx.x;
    const int wave = tid >> 6;
    const int lane = tid & 63;
    const int m    = lane & 15;
    const int quad = lane >> 4;
    const size_t i0 = (size_t)blockIdx.x * 32;

    // stage + 3-plane encode 32 rows x 128 d
    for (int e = tid; e < 32*128; e += 256) {
        int row = e >> 7, d = e & 127;
        float v = buf[(i0 + row)*RR_ + d];
        __bf16 h1 = (__bf16)v;  float r1 = v - (float)h1;
        __bf16 h2 = (__bf16)r1; float r2 = r1 - (float)h2;
        __bf16 h3 = (__bf16)r2;
        As[0][row][d] = h1; As[1][row][d] = h2; As[2][row][d] = h3;
    }
    __syncthreads();

    float4v accm[2][2][2], corr[2][2][2];   // [mt][nt][mat]
    #pragma unroll
    for (int mt = 0; mt < 2; ++mt)
        #pragma unroll
        for (int nt = 0; nt < 2; ++nt)
            #pragma unroll
            for (int mat = 0; mat < 2; ++mat) {
                accm[mt][nt][mat] = (float4v){0.f,0.f,0.f,0.f};
                corr[mt][nt][mat] = (float4v){0.f,0.f,0.f,0.f};
            }

    #pragma unroll
    for (int ck = 0; ck < 4; ++ck) {
        const int k0 = ck << 5;
        bf16x8 A1[2], A2[2], A3[2];
        #pragma unroll
        for (int mt = 0; mt < 2; ++mt) {
            A1[mt] = *(const bf16x8*)&As[0][mt*16 + m][k0 + quad*8];
            A2[mt] = *(const bf16x8*)&As[1][mt*16 + m][k0 + quad*8];
            A3[mt] = *(const bf16x8*)&As[2][mt*16 + m][k0 + quad*8];
        }
        #pragma unroll
        for (int nt = 0; nt < 2; ++nt) {
            const int r = wave*32 + nt*16 + m;
            #pragma unroll
            for (int mat = 0; mat < 2; ++mat) {
                size_t base = ((size_t)(mat*3)*128 + r)*128 + k0 + quad*8;
                bf16x8 B1 = *(const bf16x8*)&genc[base];
                bf16x8 B2 = *(const bf16x8*)&genc[base + (size_t)128*128];
                bf16x8 B3 = *(const bf16x8*)&genc[base + (size_t)2*128*128];
                #pragma unroll
                for (int mt = 0; mt < 2; ++mt) {
                    accm[mt][nt][mat] = __builtin_amdgcn_mfma_f32_16x16x32_bf16(A1[mt], B1, accm[mt][nt][mat], 0, 0, 0);
                    corr[mt][nt][mat] = __builtin_amdgcn_mfma_f32_16x16x32_bf16(A1[mt], B2, corr[mt][nt][mat], 0, 0, 0);
                    corr[mt][nt][mat] = __builtin_amdgcn_mfma_f32_16x16x32_bf16(A2[mt], B1, corr[mt][nt][mat], 0, 0, 0);
                    corr[mt][nt][mat] = __builtin_amdgcn_mfma_f32_16x16x32_bf16(A1[mt], B3, corr[mt][nt][mat], 0, 0, 0);
                    corr[mt][nt][mat] = __builtin_amdgcn_mfma_f32_16x16x32_bf16(A3[mt], B1, corr[mt][nt][mat], 0, 0, 0);
                    corr[mt][nt][mat] = __builtin_amdgcn_mfma_f32_16x16x32_bf16(A2[mt], B2, corr[mt][nt][mat], 0, 0, 0);
                }
            }
        }
    }
    __syncthreads();   // all reads of buf rows done before in-place writes

    const double SR  = 11.313708498984760390;
    const double ISR = 0.088388347648318440550;
    #pragma unroll
    for (int mt = 0; mt < 2; ++mt)
        #pragma unroll
        for (int nt = 0; nt < 2; ++nt)
            #pragma unroll
            for (int reg = 0; reg < 4; ++reg) {
                double u1 = (double)accm[mt][nt][0][reg] + (double)corr[mt][nt][0][reg];
                double u2 = (double)accm[mt][nt][1][reg] + (double)corr[mt][nt][1][reg];
                double phi = SR * tanh(u1*u2*ISR);
                const size_t row = i0 + mt*16 + quad*4 + reg;
                const int col = wave*32 + nt*16 + m;
                buf[row*RR_ + col] = (float)phi;
            }
}

// ---------------------------------------------------------------------------
// Kernel 4: partial KV (fp32) + Ksum (fp64) per (b,h,l-chunk of 128).
// ---------------------------------------------------------------------------
__global__ __launch_bounds__(256) void kv_part_k(
    const float* __restrict__ phi_k, const float* __restrict__ v,
    float* __restrict__ part_kv, double* __restrict__ part_ks)
{
    __shared__ float Ps[32][132];
    __shared__ float Vs[32][132];
    const int tid = threadIdx.x;
    const int chunk = blockIdx.x;
    const int bh = blockIdx.y;
    const int b = bh >> 3, h = bh & 7;
    const int lbase = chunk * 128;
    const int ty = tid >> 4;
    const int tx = tid & 15;
    float acc[8][8] = {};
    double ks = 0.0;

    for (int ls = 0; ls < 128; ls += 32) {
        for (int e = tid; e < 32*128; e += 256) {
            int ll = e >> 7, r = e & 127;
            size_t base = ((size_t)(b*LL + lbase + ls + ll)*HH + h)*RR_;
            Ps[ll][r] = phi_k[base + r];
            Vs[ll][r] = v[base + r];
        }
        __syncthreads();
        for (int ll = 0; ll < 32; ++ll) {
            float4 a0 = *(const float4*)&Ps[ll][ty*8];
            float4 a1 = *(const float4*)&Ps[ll][ty*8+4];
            float4 b0 = *(const float4*)&Vs[ll][tx*8];
            float4 b1 = *(const float4*)&Vs[ll][tx*8+4];
            float av[8] = {a0.x,a0.y,a0.z,a0.w,a1.x,a1.y,a1.z,a1.w};
            float bv[8] = {b0.x,b0.y,b0.z,b0.w,b1.x,b1.y,b1.z,b1.w};
            #pragma unroll
            for (int i = 0; i < 8; ++i)
                #pragma unroll
                for (int j = 0; j < 8; ++j)
                    acc[i][j] += av[i]*bv[j];
        }
        if (tid < 128) {
            #pragma unroll 8
            for (int ll = 0; ll < 32; ++ll) ks += (double)Ps[ll][tid];
        }
        __syncthreads();
    }
    float* outp = part_kv + ((size_t)(bh*16 + chunk))*RR_*DD;
    #pragma unroll
    for (int i = 0; i < 8; ++i) {
        int r = ty*8 + i;
        *(float4*)&outp[r*DD + tx*8]   = make_float4(acc[i][0],acc[i][1],acc[i][2],acc[i][3]);
        *(float4*)&outp[r*DD + tx*8+4] = make_float4(acc[i][4],acc[i][5],acc[i][6],acc[i][7]);
    }
    if (tid < 128) part_ks[(bh*16 + chunk)*RR_ + tid] = ks;
}

// ---------------------------------------------------------------------------
// Kernel 5: reduce partial KV over 16 chunks.
// ---------------------------------------------------------------------------
__global__ __launch_bounds__(256) void kvreduce_k(
    const float* __restrict__ part_kv, float* __restrict__ KV)
{
    const int gid = blockIdx.x*256 + threadIdx.x;
    if (gid >= 16*RR_*DD) return;
    const int bh = gid >> 14;
    const int rd = gid & 16383;
    float s = 0.f;
    #pragma unroll
    for (int c = 0; c < 16; ++c)
        s += part_kv[(((size_t)(bh*16 + c)) << 14) + rd];
    KV[gid] = s;
}

// ---------------------------------------------------------------------------
// Kernel 6: o = (phi_q @ KV) / (phi_q . Ksum + 1e-6). Den path in fp64.
// ---------------------------------------------------------------------------
__global__ __launch_bounds__(256) void numden_k(
    const float* __restrict__ phi_q, const float* __restrict__ KV,
    const double* __restrict__ part_ks, float* __restrict__ o_out)
{
    __shared__ float Pq[64][33];
    __shared__ float KVs[32][132];
    __shared__ double Ks_s[128];
    __shared__ double den_s[64];
    const int tid = threadIdx.x;
    const int lt = blockIdx.x;
    const int bh = blockIdx.y;
    const int b = bh >> 3, h = bh & 7;
    const int l0 = lt * 64;
    if (tid < 128) {
        double s = 0.0;
        #pragma unroll
        for (int c = 0; c < 16; ++c) s += part_ks[(bh*16 + c)*RR_ + tid];
        Ks_s[tid] = s;
    }
    const int ty = tid >> 4;
    const int tx = tid & 15;
    float acc[4][8] = {};
    double den = 0.0;

    for (int r0 = 0; r0 < RR_; r0 += 32) {
        __syncthreads();
        for (int e = tid; e < 64*32; e += 256) {
            int row = e >> 5, rr = e & 31;
            Pq[row][rr] = phi_q[((size_t)(b*LL + l0 + row)*HH + h)*RR_ + r0 + rr];
        }
        for (int e = tid; e < 32*128; e += 256) {
            int rr = e >> 7, d = e & 127;
            KVs[rr][d] = KV[((size_t)bh*RR_ + r0 + rr)*DD + d];
        }
        __syncthreads();
        for (int rr = 0; rr < 32; ++rr) {
            float a[4];
            #pragma unroll
            for (int i = 0; i < 4; ++i) a[i] = Pq[ty*4+i][rr];
            float4 b0 = *(const float4*)&KVs[rr][tx*8];
            float4 b1 = *(const float4*)&KVs[rr][tx*8+4];
            float bv[8] = {b0.x,b0.y,b0.z,b0.w,b1.x,b1.y,b1.z,b1.w};
            #pragma unroll
            for (int i = 0; i < 4; ++i)
                #pragma unroll
                for (int j = 0; j < 8; ++j)
                    acc[i][j] += a[i]*bv[j];
        }
        if (tid < 64) {
            #pragma unroll
            for (int rr = 0; rr < 32; ++rr)
                den += (double)Pq[tid][rr]*Ks_s[r0 + rr];
        }
    }
    __syncthreads();
    if (tid < 64) den_s[tid] = den;
    __syncthreads();
    #pragma unroll
    for (int i = 0; i < 4; ++i) {
        const int l = l0 + ty*4 + i;
        const float inv = (float)(1.0 / (den_s[ty*4+i] + 1e-6));
        size_t base = ((size_t)(b*LL + l))*OC + h*DD + tx*8;
        *(float4*)&o_out[base]   = make_float4(acc[i][0]*inv, acc[i][1]*inv,
                                               acc[i][2]*inv, acc[i][3]*inv);
        *(float4*)&o_out[base+4] = make_float4(acc[i][4]*inv, acc[i][5]*inv,
                                               acc[i][6]*inv, acc[i][7]*inv);
    }
}

// ---------------------------------------------------------------------------
// Kernel 7a: output projection, split-K x4.
// ---------------------------------------------------------------------------
__global__ __launch_bounds__(256) void proj_part_k(
    const float* __restrict__ o_s, const float* __restrict__ pw,
    float* __restrict__ part)
{
    __shared__ float As[32][33];
    __shared__ float Bs[32][132];
    const int tid = threadIdx.x;
    const int row0 = blockIdx.x * 32;
    const int kbase = blockIdx.y * 256;
    const int ty = tid >> 5;
    const int tx = tid & 31;
    float acc[4][4] = {};

    for (int k0 = kbase; k0 < kbase + 256; k0 += 32) {
        __syncthreads();
        for (int e = tid; e < 32*32; e += 256) {
            int r = e >> 5, kk = e & 31;
            As[r][kk] = o_s[(size_t)(row0 + r)*OC + k0 + kk];
        }
        for (int e = tid; e < 32*128; e += 256) {
            int j = e >> 5, kk = e & 31;
            Bs[kk][j] = pw[(size_t)j*OC + k0 + kk];
        }
        __syncthreads();
        for (int kk = 0; kk < 32; ++kk) {
            float a[4];
            #pragma unroll
            for (int i = 0; i < 4; ++i) a[i] = As[ty*4+i][kk];
            float4 bq = *(const float4*)&Bs[kk][tx*4];
            float bv[4] = {bq.x,bq.y,bq.z,bq.w};
            #pragma unroll
            for (int i = 0; i < 4; ++i)
                #pragma unroll
                for (int j = 0; j < 4; ++j)
                    acc[i][j] += a[i]*bv[j];
        }
    }
    float* outp = part + (size_t)blockIdx.y*BL*DD;
    #pragma unroll
    for (int i = 0; i < 4; ++i)
        *(float4*)&outp[(size_t)(row0 + ty*4 + i)*DD + tx*4] =
            make_float4(acc[i][0],acc[i][1],acc[i][2],acc[i][3]);
}

// ---------------------------------------------------------------------------
// Kernel 7b: reduce the 4 K-split partials + bias.
// ---------------------------------------------------------------------------
__global__ __launch_bounds__(256) void proj_reduce_k(
    const float* __restrict__ part, const float* __restrict__ pb,
    float* __restrict__ out)
{
    const int gid = blockIdx.x*256 + threadIdx.x;
    if (gid >= BL*DD/4) return;
    const float4* p4 = (const float4*)part;
    float4 s = p4[gid];
    #pragma unroll
    for (int c = 1; c < 4; ++c) {
        float4 t = p4[gid + (size_t)c*(BL*DD/4)];
        s.x += t.x; s.y += t.y; s.z += t.z; s.w += t.w;
    }
    const int col = (gid << 2) & (DD-1);
    s.x += pb[col]; s.y += pb[col+1]; s.z += pb[col+2]; s.w += pb[col+3];
    ((float4*)out)[gid] = s;
}

// ---------------------------------------------------------------------------
extern "C" void kernel_launch(void* const* d_in, const int* in_sizes, int n_in,
                              void* d_out, int out_size, void* d_ws, size_t ws_size,
                              hipStream_t stream) {
    const float* x       = (const float*)d_in[0];
    const float* q_w     = (const float*)d_in[1];
    const float* q_b     = (const float*)d_in[2];
    const float* k_w     = (const float*)d_in[3];
    const float* k_b     = (const float*)d_in[4];
    const float* v_w     = (const float*)d_in[5];
    const float* g1_q    = (const float*)d_in[6];
    const float* g2_q    = (const float*)d_in[7];
    const float* g1_k    = (const float*)d_in[8];
    const float* g2_k    = (const float*)d_in[9];
    const float* gamma_q = (const float*)d_in[10];
    const float* beta_q  = (const float*)d_in[11];
    const float* gamma_k = (const float*)d_in[12];
    const float* beta_k  = (const float*)d_in[13];
    const float* proj_w  = (const float*)d_in[14];
    const float* proj_b  = (const float*)d_in[15];

    float* f = (float*)d_ws;
    float* q_s     = f;                        // 4,194,304 floats
    float* k_s     = f + 4194304;              // 4,194,304
    float* v_s     = f + 8388608;              // 4,194,304
    float* part_kv = f + 12582912;             // 4,194,304 (wenc / proj partials share)
    double* part_ks = (double*)(f + 16777216); // 32,768 doubles
    float* KVb     = f + 16842752;             // 262,144 floats -> ends 17,104,896
    __bf16* genc   = (__bf16*)(f + 17104896);  // 196,608 bf16 (98,304 float slots)
    __bf16* venc   = (__bf16*)(f + 17203200);  // 262,144 bf16 (131,072 float slots)
    float* o_s     = k_s;                      // reuse (phi_k dead after kv_part_k)
    float* proj_part = part_kv;                // reuse
    __bf16* wenc   = (__bf16*)part_kv;         // 2.36M bf16, dead before kv_part_k
    __bf16* genc_q = genc;                     // mats 0,1
    __bf16* genc_k = genc + (size_t)2*3*128*128; // mats 2,3

    dim3 blk(256);
    enc_all_k<<<1792, blk, 0, stream>>>(q_w, k_w, v_w, g1_q, g2_q, g1_k, g2_k,
                                        wenc, genc, venc);
    conv_mfma_k<<<dim3(128,32), blk, 0, stream>>>(x, wenc, q_b, k_b,
                                                  gamma_q, beta_q, gamma_k, beta_k,
                                                  q_s, k_s);
    vproj_mfma_k<<<dim3(128,8), blk, 0, stream>>>(x, venc, v_s);
    sketch_mfma_k<<<1024, blk, 0, stream>>>(q_s, genc_q);
    sketch_mfma_k<<<1024, blk, 0, stream>>>(k_s, genc_k);
    kv_part_k<<<dim3(16,16), blk, 0, stream>>>(k_s, v_s, part_kv, part_ks);
    kvreduce_k<<<1024, blk, 0, stream>>>(part_kv, KVb);
    numden_k <<<dim3(32,16), blk, 0, stream>>>(q_s, KVb, part_ks, o_s);
    proj_part_k<<<dim3(128,4), blk, 0, stream>>>(o_s, proj_w, proj_part);
    proj_reduce_k<<<512, blk, 0, stream>>>(proj_part, proj_b, (float*)d_out);
}

// Round 9
// 367.356 us; speedup vs baseline: 1.8198x; 1.0759x over previous
//
#include <hip/hip_runtime.h>
#include <math.h>

// Problem constants
#define BB 2
#define DD 128
#define LL 2048
#define HH 8
#define OC 1024     // H*D
#define RR_ 128
#define BL (BB*LL)          // 4096
#define NROW (BL*HH)        // 32768
#define XROWS 2052          // xenc rows per (plane,b): l+2 for l in [-2,2047], padded

// Numerics ledger (absmax bf16-quantized; threshold 180.48):
//   r3  full fp64 conv+sketch             -> 128 PASS
//   r2  seq fp32 (eps~7e-7)               -> 192 FAIL
//   r5  chunk-32 fp32 + tanhf (~5e-7)     -> 192 FAIL
//   r6  conv chunk-4 + sketch chunk-8     -> 128 PASS (eps ~1.9e-7)
//   r7  conv = split-bf16 MFMA 3-plane/6-pass -> 64 PASS
//   r8  sketch 3-plane/6-pass + vproj 2-plane MFMA -> 64 PASS, 395us
// r9: same arithmetic, restructured conv: x encoded once (enc_x_k), conv
//     stages all K once (2 barriers), 4 l-tiles/wave. Bit-identical numerics.

typedef __bf16  bf16x8  __attribute__((ext_vector_type(8)));
typedef float   float4v __attribute__((ext_vector_type(4)));

// ---------------------------------------------------------------------------
// Kernel 0a: encode all weights to bf16 planes.
//  wenc[plane(3)][t(3)][o(2048: q|k)][c(128)]
//  genc[mat(4)][plane(3)][r(128)][d(128)] (transposed)
//  venc[plane(2)][o(1024)][c(128)]
// ---------------------------------------------------------------------------
__global__ __launch_bounds__(256) void enc_all_k(
    const float* __restrict__ q_w, const float* __restrict__ k_w,
    const float* __restrict__ v_w,
    const float* __restrict__ g1_q, const float* __restrict__ g2_q,
    const float* __restrict__ g1_k, const float* __restrict__ g2_k,
    __bf16* __restrict__ wenc, __bf16* __restrict__ genc,
    __bf16* __restrict__ venc)
{
    const int gid = blockIdx.x*256 + threadIdx.x;
    if (gid < 262144) {
        const int o = gid >> 7, c = gid & 127;
        #pragma unroll
        for (int t = 0; t < 3; ++t) {
            float v = (o < 1024) ? q_w[(o*128 + c)*3 + t]
                                 : k_w[((o-1024)*128 + c)*3 + t];
            __bf16 h1 = (__bf16)v;  float r1 = v - (float)h1;
            __bf16 h2 = (__bf16)r1; float r2 = r1 - (float)h2;
            __bf16 h3 = (__bf16)r2;
            wenc[((size_t)(0*3 + t)*2048 + o)*128 + c] = h1;
            wenc[((size_t)(1*3 + t)*2048 + o)*128 + c] = h2;
            wenc[((size_t)(2*3 + t)*2048 + o)*128 + c] = h3;
        }
    } else if (gid < 262144 + 65536) {
        const int g = gid - 262144;
        const int mat = g >> 14, rem = g & 16383;
        const int r = rem >> 7, d = rem & 127;
        const float* src = (mat == 0) ? g1_q : (mat == 1) ? g2_q
                         : (mat == 2) ? g1_k : g2_k;
        float v = src[d*RR_ + r];
        __bf16 h1 = (__bf16)v;  float r1 = v - (float)h1;
        __bf16 h2 = (__bf16)r1; float r2 = r1 - (float)h2;
        __bf16 h3 = (__bf16)r2;
        genc[((size_t)(mat*3 + 0)*128 + r)*128 + d] = h1;
        genc[((size_t)(mat*3 + 1)*128 + r)*128 + d] = h2;
        genc[((size_t)(mat*3 + 2)*128 + r)*128 + d] = h3;
    } else if (gid < 262144 + 65536 + 131072) {
        const int g = gid - 262144 - 65536;
        const int o = g >> 7, c = g & 127;
        float v = v_w[o*128 + c];
        __bf16 h1 = (__bf16)v;  float r1 = v - (float)h1;
        __bf16 h2 = (__bf16)r1;
        venc[((size_t)0*1024 + o)*128 + c] = h1;
        venc[((size_t)1*1024 + o)*128 + c] = h2;
    }
}

// ---------------------------------------------------------------------------
// Kernel 0b: encode x once to 3 bf16 planes, transposed to [plane][b][l+2][c].
// Rows 0,1 of each (plane,b) are the causal zero pad.
// ---------------------------------------------------------------------------
__global__ __launch_bounds__(256) void enc_x_k(
    const float* __restrict__ x, __bf16* __restrict__ xenc)
{
    __shared__ float t[32][33];
    const int tid = threadIdx.x;
    const int lt = blockIdx.x, ct = blockIdx.y, b = blockIdx.z;
    const int l0 = lt*32, c0 = ct*32;
    for (int e = tid; e < 32*32; e += 256) {
        int c = e >> 5, l = e & 31;
        t[c][l] = x[((size_t)(b*DD + c0 + c))*LL + l0 + l];
    }
    __syncthreads();
    for (int e = tid; e < 32*32; e += 256) {
        int l = e >> 5, c = e & 31;
        float v = t[c][l];
        __bf16 h1 = (__bf16)v;  float r1 = v - (float)h1;
        __bf16 h2 = (__bf16)r1; float r2 = r1 - (float)h2;
        __bf16 h3 = (__bf16)r2;
        const size_t row = (size_t)(l0 + l + 2);
        xenc[((size_t)(0*2 + b)*XROWS + row)*128 + c0 + c] = h1;
        xenc[((size_t)(1*2 + b)*XROWS + row)*128 + c0 + c] = h2;
        xenc[((size_t)(2*2 + b)*XROWS + row)*128 + c0 + c] = h3;
    }
    if (lt == 0 && ct == 0) {
        for (int e = tid; e < 2*128; e += 256) {
            int row = e >> 7, c = e & 127;
            xenc[((size_t)(0*2 + b)*XROWS + row)*128 + c] = (__bf16)0.f;
            xenc[((size_t)(1*2 + b)*XROWS + row)*128 + c] = (__bf16)0.f;
            xenc[((size_t)(2*2 + b)*XROWS + row)*128 + c] = (__bf16)0.f;
        }
    }
}

// ---------------------------------------------------------------------------
// Kernel 1: fused q+k causal conv1d K=3 as split-bf16 MFMA GEMM, v2.
// Block: 64 l x 64 o, 4 waves; wave w: o-sub w*16, 4 l-tiles of 16.
// Stage all 3 planes x 66 rows x 128 c once (52.7 KB LDS, 2 barriers).
// ---------------------------------------------------------------------------
__global__ __launch_bounds__(256) void conv_mfma_k(
    const __bf16* __restrict__ xenc, const __bf16* __restrict__ wenc,
    const float* __restrict__ q_b, const float* __restrict__ k_b,
    const float* __restrict__ gamma_q, const float* __restrict__ beta_q,
    const float* __restrict__ gamma_k, const float* __restrict__ beta_k,
    float* __restrict__ q_s, float* __restrict__ k_s)
{
    __shared__ __bf16 As[3][66][136];
    const int tid  = threadIdx.x;
    const int wave = tid >> 6;
    const int lane = tid & 63;
    const int m    = lane & 15;
    const int quad = lane >> 4;
    const int bx = blockIdx.x;         // 64: b*32 + l-block
    const int b  = bx >> 5;
    const int lb0 = (bx & 31) << 6;    // 64 l rows per block
    const int o0 = blockIdx.y << 6;
    const int osub = o0 + wave*16;

    // stage: xenc rows lb0 .. lb0+65  (= l from lb0-2 .. lb0+63)
    for (int e = tid; e < 3*66*16; e += 256) {
        const int p = e / (66*16), rem = e % (66*16);
        const int row = rem >> 4, cg = rem & 15;
        *(bf16x8*)&As[p][row][cg*8] =
            *(const bf16x8*)&xenc[((size_t)(p*2 + b)*XROWS + lb0 + row)*128 + cg*8];
    }
    __syncthreads();

    float4v accm[4][4];   // [l-tile][c-chunk] main accumulators (chain 3 each)
    float4v corr[4];      // correction accumulators
    #pragma unroll
    for (int lt = 0; lt < 4; ++lt) {
        corr[lt] = (float4v){0.f,0.f,0.f,0.f};
        #pragma unroll
        for (int c = 0; c < 4; ++c) accm[lt][c] = (float4v){0.f,0.f,0.f,0.f};
    }

    #pragma unroll
    for (int cidx = 0; cidx < 4; ++cidx) {
        const int c0 = cidx << 5;
        #pragma unroll
        for (int t = 0; t < 3; ++t) {
            bf16x8 B1, B2, B3;
            {
                size_t base = ((size_t)t*2048 + osub + m)*128 + c0 + quad*8;
                B1 = *(const bf16x8*)&wenc[base];
                B2 = *(const bf16x8*)&wenc[base + (size_t)3*2048*128];
                B3 = *(const bf16x8*)&wenc[base + (size_t)6*2048*128];
            }
            #pragma unroll
            for (int lt = 0; lt < 4; ++lt) {
                const int row = lt*16 + m + t;
                bf16x8 A1 = *(const bf16x8*)&As[0][row][c0 + quad*8];
                bf16x8 A2 = *(const bf16x8*)&As[1][row][c0 + quad*8];
                bf16x8 A3 = *(const bf16x8*)&As[2][row][c0 + quad*8];
                accm[lt][cidx] = __builtin_amdgcn_mfma_f32_16x16x32_bf16(A1, B1, accm[lt][cidx], 0, 0, 0);
                corr[lt] = __builtin_amdgcn_mfma_f32_16x16x32_bf16(A1, B2, corr[lt], 0, 0, 0);
                corr[lt] = __builtin_amdgcn_mfma_f32_16x16x32_bf16(A2, B1, corr[lt], 0, 0, 0);
                corr[lt] = __builtin_amdgcn_mfma_f32_16x16x32_bf16(A1, B3, corr[lt], 0, 0, 0);
                corr[lt] = __builtin_amdgcn_mfma_f32_16x16x32_bf16(A3, B1, corr[lt], 0, 0, 0);
                corr[lt] = __builtin_amdgcn_mfma_f32_16x16x32_bf16(A2, B2, corr[lt], 0, 0, 0);
            }
        }
    }

    const int is_k = (o0 >= 1024);
    const double g  = (double)(is_k ? gamma_k[0] : gamma_q[0]);
    const double be = (double)(is_k ? beta_k[0]  : beta_q[0]);
    const int o_global = osub + m;
    const int o_local  = o_global - (is_k ? 1024 : 0);
    const double bias  = (double)(is_k ? k_b[o_local] : q_b[o_local]);
    float* dest = is_k ? k_s : q_s;
    #pragma unroll
    for (int lt = 0; lt < 4; ++lt) {
        #pragma unroll
        for (int reg = 0; reg < 4; ++reg) {
            double s = (double)corr[lt][reg];
            #pragma unroll
            for (int c = 0; c < 4; ++c) s += (double)accm[lt][c][reg];
            const int l = lb0 + lt*16 + quad*4 + reg;
            dest[((size_t)(b*LL + l))*OC + o_local] = (float)(g*(s + bias) + be);
        }
    }
}

// ---------------------------------------------------------------------------
// Kernel 2: V projection as 2-plane split-bf16 MFMA, staging from xenc.
// ---------------------------------------------------------------------------
__global__ __launch_bounds__(256) void vproj_mfma_k(
    const __bf16* __restrict__ xenc, const __bf16* __restrict__ venc,
    float* __restrict__ v_out)
{
    __shared__ __bf16 As[2][32][136];
    const int tid  = threadIdx.x;
    const int wave = tid >> 6;
    const int lane = tid & 63;
    const int m    = lane & 15;
    const int quad = lane >> 4;
    const int bx = blockIdx.x;
    const int b  = bx >> 6;
    const int l0 = (bx & 63) << 5;
    const int o0 = blockIdx.y << 7;

    // stage from xenc planes 0,1 (rows l0+2 .. l0+33)
    for (int e = tid; e < 2*32*16; e += 256) {
        const int p = e >> 9, rem = e & 511;
        const int row = rem >> 4, cg = rem & 15;
        *(bf16x8*)&As[p][row][cg*8] =
            *(const bf16x8*)&xenc[((size_t)(p*2 + b)*XROWS + l0 + row + 2)*128 + cg*8];
    }
    __syncthreads();

    float4v accm[2][2], corr[2][2];
    #pragma unroll
    for (int mt = 0; mt < 2; ++mt)
        #pragma unroll
        for (int nt = 0; nt < 2; ++nt) {
            accm[mt][nt] = (float4v){0.f,0.f,0.f,0.f};
            corr[mt][nt] = (float4v){0.f,0.f,0.f,0.f};
        }

    #pragma unroll
    for (int ck = 0; ck < 4; ++ck) {
        const int k0 = ck << 5;
        bf16x8 A1[2], A2[2];
        #pragma unroll
        for (int mt = 0; mt < 2; ++mt) {
            A1[mt] = *(const bf16x8*)&As[0][mt*16 + m][k0 + quad*8];
            A2[mt] = *(const bf16x8*)&As[1][mt*16 + m][k0 + quad*8];
        }
        #pragma unroll
        for (int nt = 0; nt < 2; ++nt) {
            const int o = o0 + wave*32 + nt*16 + m;
            size_t base = ((size_t)o)*128 + k0 + quad*8;
            bf16x8 B1 = *(const bf16x8*)&venc[base];
            bf16x8 B2 = *(const bf16x8*)&venc[base + (size_t)1024*128];
            #pragma unroll
            for (int mt = 0; mt < 2; ++mt) {
                accm[mt][nt] = __builtin_amdgcn_mfma_f32_16x16x32_bf16(A1[mt], B1, accm[mt][nt], 0, 0, 0);
                corr[mt][nt] = __builtin_amdgcn_mfma_f32_16x16x32_bf16(A1[mt], B2, corr[mt][nt], 0, 0, 0);
                corr[mt][nt] = __builtin_amdgcn_mfma_f32_16x16x32_bf16(A2[mt], B1, corr[mt][nt], 0, 0, 0);
                corr[mt][nt] = __builtin_amdgcn_mfma_f32_16x16x32_bf16(A2[mt], B2, corr[mt][nt], 0, 0, 0);
            }
        }
    }

    #pragma unroll
    for (int mt = 0; mt < 2; ++mt)
        #pragma unroll
        for (int nt = 0; nt < 2; ++nt)
            #pragma unroll
            for (int reg = 0; reg < 4; ++reg) {
                const int l = l0 + mt*16 + quad*4 + reg;
                const int o = o0 + wave*32 + nt*16 + m;
                v_out[((size_t)(b*LL + l))*OC + o] = accm[mt][nt][reg] + corr[mt][nt][reg];
            }
}

// ---------------------------------------------------------------------------
// Kernel 3: sketch as 3-plane/6-pass split-bf16 MFMA, in-place (r8-proven).
// ---------------------------------------------------------------------------
__global__ __launch_bounds__(256) void sketch_mfma_k(
    float* __restrict__ buf, const __bf16* __restrict__ genc)
{
    __shared__ __bf16 As[3][32][136];
    const int tid  = threadIdx.x;
    const int wave = tid >> 6;
    const int lane = tid & 63;
    const int m    = lane & 15;
    const int quad = lane >> 4;
    const size_t i0 = (size_t)blockIdx.x * 32;

    for (int e = tid; e < 32*128; e += 256) {
        int row = e >> 7, d = e & 127;
        float v = buf[(i0 + row)*RR_ + d];
        __bf16 h1 = (__bf16)v;  float r1 = v - (float)h1;
        __bf16 h2 = (__bf16)r1; float r2 = r1 - (float)h2;
        __bf16 h3 = (__bf16)r2;
        As[0][row][d] = h1; As[1][row][d] = h2; As[2][row][d] = h3;
    }
    __syncthreads();

    float4v accm[2][2][2], corr[2][2][2];
    #pragma unroll
    for (int mt = 0; mt < 2; ++mt)
        #pragma unroll
        for (int nt = 0; nt < 2; ++nt)
            #pragma unroll
            for (int mat = 0; mat < 2; ++mat) {
                accm[mt][nt][mat] = (float4v){0.f,0.f,0.f,0.f};
                corr[mt][nt][mat] = (float4v){0.f,0.f,0.f,0.f};
            }

    #pragma unroll
    for (int ck = 0; ck < 4; ++ck) {
        const int k0 = ck << 5;
        bf16x8 A1[2], A2[2], A3[2];
        #pragma unroll
        for (int mt = 0; mt < 2; ++mt) {
            A1[mt] = *(const bf16x8*)&As[0][mt*16 + m][k0 + quad*8];
            A2[mt] = *(const bf16x8*)&As[1][mt*16 + m][k0 + quad*8];
            A3[mt] = *(const bf16x8*)&As[2][mt*16 + m][k0 + quad*8];
        }
        #pragma unroll
        for (int nt = 0; nt < 2; ++nt) {
            const int r = wave*32 + nt*16 + m;
            #pragma unroll
            for (int mat = 0; mat < 2; ++mat) {
                size_t base = ((size_t)(mat*3)*128 + r)*128 + k0 + quad*8;
                bf16x8 B1 = *(const bf16x8*)&genc[base];
                bf16x8 B2 = *(const bf16x8*)&genc[base + (size_t)128*128];
                bf16x8 B3 = *(const bf16x8*)&genc[base + (size_t)2*128*128];
                #pragma unroll
                for (int mt = 0; mt < 2; ++mt) {
                    accm[mt][nt][mat] = __builtin_amdgcn_mfma_f32_16x16x32_bf16(A1[mt], B1, accm[mt][nt][mat], 0, 0, 0);
                    corr[mt][nt][mat] = __builtin_amdgcn_mfma_f32_16x16x32_bf16(A1[mt], B2, corr[mt][nt][mat], 0, 0, 0);
                    corr[mt][nt][mat] = __builtin_amdgcn_mfma_f32_16x16x32_bf16(A2[mt], B1, corr[mt][nt][mat], 0, 0, 0);
                    corr[mt][nt][mat] = __builtin_amdgcn_mfma_f32_16x16x32_bf16(A1[mt], B3, corr[mt][nt][mat], 0, 0, 0);
                    corr[mt][nt][mat] = __builtin_amdgcn_mfma_f32_16x16x32_bf16(A3[mt], B1, corr[mt][nt][mat], 0, 0, 0);
                    corr[mt][nt][mat] = __builtin_amdgcn_mfma_f32_16x16x32_bf16(A2[mt], B2, corr[mt][nt][mat], 0, 0, 0);
                }
            }
        }
    }
    __syncthreads();

    const double SR  = 11.313708498984760390;
    const double ISR = 0.088388347648318440550;
    #pragma unroll
    for (int mt = 0; mt < 2; ++mt)
        #pragma unroll
        for (int nt = 0; nt < 2; ++nt)
            #pragma unroll
            for (int reg = 0; reg < 4; ++reg) {
                double u1 = (double)accm[mt][nt][0][reg] + (double)corr[mt][nt][0][reg];
                double u2 = (double)accm[mt][nt][1][reg] + (double)corr[mt][nt][1][reg];
                double phi = SR * tanh(u1*u2*ISR);
                const size_t row = i0 + mt*16 + quad*4 + reg;
                const int col = wave*32 + nt*16 + m;
                buf[row*RR_ + col] = (float)phi;
            }
}

// ---------------------------------------------------------------------------
// Kernel 4: partial KV (fp32) + Ksum (fp64) per (b,h,l-chunk of 128).
// ---------------------------------------------------------------------------
__global__ __launch_bounds__(256) void kv_part_k(
    const float* __restrict__ phi_k, const float* __restrict__ v,
    float* __restrict__ part_kv, double* __restrict__ part_ks)
{
    __shared__ float Ps[32][132];
    __shared__ float Vs[32][132];
    const int tid = threadIdx.x;
    const int chunk = blockIdx.x;
    const int bh = blockIdx.y;
    const int b = bh >> 3, h = bh & 7;
    const int lbase = chunk * 128;
    const int ty = tid >> 4;
    const int tx = tid & 15;
    float acc[8][8] = {};
    double ks = 0.0;

    for (int ls = 0; ls < 128; ls += 32) {
        for (int e = tid; e < 32*128; e += 256) {
            int ll = e >> 7, r = e & 127;
            size_t base = ((size_t)(b*LL + lbase + ls + ll)*HH + h)*RR_;
            Ps[ll][r] = phi_k[base + r];
            Vs[ll][r] = v[base + r];
        }
        __syncthreads();
        for (int ll = 0; ll < 32; ++ll) {
            float4 a0 = *(const float4*)&Ps[ll][ty*8];
            float4 a1 = *(const float4*)&Ps[ll][ty*8+4];
            float4 b0 = *(const float4*)&Vs[ll][tx*8];
            float4 b1 = *(const float4*)&Vs[ll][tx*8+4];
            float av[8] = {a0.x,a0.y,a0.z,a0.w,a1.x,a1.y,a1.z,a1.w};
            float bv[8] = {b0.x,b0.y,b0.z,b0.w,b1.x,b1.y,b1.z,b1.w};
            #pragma unroll
            for (int i = 0; i < 8; ++i)
                #pragma unroll
                for (int j = 0; j < 8; ++j)
                    acc[i][j] += av[i]*bv[j];
        }
        if (tid < 128) {
            #pragma unroll 8
            for (int ll = 0; ll < 32; ++ll) ks += (double)Ps[ll][tid];
        }
        __syncthreads();
    }
    float* outp = part_kv + ((size_t)(bh*16 + chunk))*RR_*DD;
    #pragma unroll
    for (int i = 0; i < 8; ++i) {
        int r = ty*8 + i;
        *(float4*)&outp[r*DD + tx*8]   = make_float4(acc[i][0],acc[i][1],acc[i][2],acc[i][3]);
        *(float4*)&outp[r*DD + tx*8+4] = make_float4(acc[i][4],acc[i][5],acc[i][6],acc[i][7]);
    }
    if (tid < 128) part_ks[(bh*16 + chunk)*RR_ + tid] = ks;
}

// ---------------------------------------------------------------------------
// Kernel 5: reduce partial KV over 16 chunks.
// ---------------------------------------------------------------------------
__global__ __launch_bounds__(256) void kvreduce_k(
    const float* __restrict__ part_kv, float* __restrict__ KV)
{
    const int gid = blockIdx.x*256 + threadIdx.x;
    if (gid >= 16*RR_*DD) return;
    const int bh = gid >> 14;
    const int rd = gid & 16383;
    float s = 0.f;
    #pragma unroll
    for (int c = 0; c < 16; ++c)
        s += part_kv[(((size_t)(bh*16 + c)) << 14) + rd];
    KV[gid] = s;
}

// ---------------------------------------------------------------------------
// Kernel 6: o = (phi_q @ KV) / (phi_q . Ksum + 1e-6). Den path in fp64.
// ---------------------------------------------------------------------------
__global__ __launch_bounds__(256) void numden_k(
    const float* __restrict__ phi_q, const float* __restrict__ KV,
    const double* __restrict__ part_ks, float* __restrict__ o_out)
{
    __shared__ float Pq[64][33];
    __shared__ float KVs[32][132];
    __shared__ double Ks_s[128];
    __shared__ double den_s[64];
    const int tid = threadIdx.x;
    const int lt = blockIdx.x;
    const int bh = blockIdx.y;
    const int b = bh >> 3, h = bh & 7;
    const int l0 = lt * 64;
    if (tid < 128) {
        double s = 0.0;
        #pragma unroll
        for (int c = 0; c < 16; ++c) s += part_ks[(bh*16 + c)*RR_ + tid];
        Ks_s[tid] = s;
    }
    const int ty = tid >> 4;
    const int tx = tid & 15;
    float acc[4][8] = {};
    double den = 0.0;

    for (int r0 = 0; r0 < RR_; r0 += 32) {
        __syncthreads();
        for (int e = tid; e < 64*32; e += 256) {
            int row = e >> 5, rr = e & 31;
            Pq[row][rr] = phi_q[((size_t)(b*LL + l0 + row)*HH + h)*RR_ + r0 + rr];
        }
        for (int e = tid; e < 32*128; e += 256) {
            int rr = e >> 7, d = e & 127;
            KVs[rr][d] = KV[((size_t)bh*RR_ + r0 + rr)*DD + d];
        }
        __syncthreads();
        for (int rr = 0; rr < 32; ++rr) {
            float a[4];
            #pragma unroll
            for (int i = 0; i < 4; ++i) a[i] = Pq[ty*4+i][rr];
            float4 b0 = *(const float4*)&KVs[rr][tx*8];
            float4 b1 = *(const float4*)&KVs[rr][tx*8+4];
            float bv[8] = {b0.x,b0.y,b0.z,b0.w,b1.x,b1.y,b1.z,b1.w};
            #pragma unroll
            for (int i = 0; i < 4; ++i)
                #pragma unroll
                for (int j = 0; j < 8; ++j)
                    acc[i][j] += a[i]*bv[j];
        }
        if (tid < 64) {
            #pragma unroll
            for (int rr = 0; rr < 32; ++rr)
                den += (double)Pq[tid][rr]*Ks_s[r0 + rr];
        }
    }
    __syncthreads();
    if (tid < 64) den_s[tid] = den;
    __syncthreads();
    #pragma unroll
    for (int i = 0; i < 4; ++i) {
        const int l = l0 + ty*4 + i;
        const float inv = (float)(1.0 / (den_s[ty*4+i] + 1e-6));
        size_t base = ((size_t)(b*LL + l))*OC + h*DD + tx*8;
        *(float4*)&o_out[base]   = make_float4(acc[i][0]*inv, acc[i][1]*inv,
                                               acc[i][2]*inv, acc[i][3]*inv);
        *(float4*)&o_out[base+4] = make_float4(acc[i][4]*inv, acc[i][5]*inv,
                                               acc[i][6]*inv, acc[i][7]*inv);
    }
}

// ---------------------------------------------------------------------------
// Kernel 7a: output projection, split-K x4.
// ---------------------------------------------------------------------------
__global__ __launch_bounds__(256) void proj_part_k(
    const float* __restrict__ o_s, const float* __restrict__ pw,
    float* __restrict__ part)
{
    __shared__ float As[32][33];
    __shared__ float Bs[32][132];
    const int tid = threadIdx.x;
    const int row0 = blockIdx.x * 32;
    const int kbase = blockIdx.y * 256;
    const int ty = tid >> 5;
    const int tx = tid & 31;
    float acc[4][4] = {};

    for (int k0 = kbase; k0 < kbase + 256; k0 += 32) {
        __syncthreads();
        for (int e = tid; e < 32*32; e += 256) {
            int r = e >> 5, kk = e & 31;
            As[r][kk] = o_s[(size_t)(row0 + r)*OC + k0 + kk];
        }
        for (int e = tid; e < 32*128; e += 256) {
            int j = e >> 5, kk = e & 31;
            Bs[kk][j] = pw[(size_t)j*OC + k0 + kk];
        }
        __syncthreads();
        for (int kk = 0; kk < 32; ++kk) {
            float a[4];
            #pragma unroll
            for (int i = 0; i < 4; ++i) a[i] = As[ty*4+i][kk];
            float4 bq = *(const float4*)&Bs[kk][tx*4];
            float bv[4] = {bq.x,bq.y,bq.z,bq.w};
            #pragma unroll
            for (int i = 0; i < 4; ++i)
                #pragma unroll
                for (int j = 0; j < 4; ++j)
                    acc[i][j] += a[i]*bv[j];
        }
    }
    float* outp = part + (size_t)blockIdx.y*BL*DD;
    #pragma unroll
    for (int i = 0; i < 4; ++i)
        *(float4*)&outp[(size_t)(row0 + ty*4 + i)*DD + tx*4] =
            make_float4(acc[i][0],acc[i][1],acc[i][2],acc[i][3]);
}

// ---------------------------------------------------------------------------
// Kernel 7b: reduce the 4 K-split partials + bias.
// ---------------------------------------------------------------------------
__global__ __launch_bounds__(256) void proj_reduce_k(
    const float* __restrict__ part, const float* __restrict__ pb,
    float* __restrict__ out)
{
    const int gid = blockIdx.x*256 + threadIdx.x;
    if (gid >= BL*DD/4) return;
    const float4* p4 = (const float4*)part;
    float4 s = p4[gid];
    #pragma unroll
    for (int c = 1; c < 4; ++c) {
        float4 t = p4[gid + (size_t)c*(BL*DD/4)];
        s.x += t.x; s.y += t.y; s.z += t.z; s.w += t.w;
    }
    const int col = (gid << 2) & (DD-1);
    s.x += pb[col]; s.y += pb[col+1]; s.z += pb[col+2]; s.w += pb[col+3];
    ((float4*)out)[gid] = s;
}

// ---------------------------------------------------------------------------
extern "C" void kernel_launch(void* const* d_in, const int* in_sizes, int n_in,
                              void* d_out, int out_size, void* d_ws, size_t ws_size,
                              hipStream_t stream) {
    const float* x       = (const float*)d_in[0];
    const float* q_w     = (const float*)d_in[1];
    const float* q_b     = (const float*)d_in[2];
    const float* k_w     = (const float*)d_in[3];
    const float* k_b     = (const float*)d_in[4];
    const float* v_w     = (const float*)d_in[5];
    const float* g1_q    = (const float*)d_in[6];
    const float* g2_q    = (const float*)d_in[7];
    const float* g1_k    = (const float*)d_in[8];
    const float* g2_k    = (const float*)d_in[9];
    const float* gamma_q = (const float*)d_in[10];
    const float* beta_q  = (const float*)d_in[11];
    const float* gamma_k = (const float*)d_in[12];
    const float* beta_k  = (const float*)d_in[13];
    const float* proj_w  = (const float*)d_in[14];
    const float* proj_b  = (const float*)d_in[15];

    float* f = (float*)d_ws;
    float* q_s     = f;                        // 4,194,304 floats
    float* k_s     = f + 4194304;              // 4,194,304
    float* v_s     = f + 8388608;              // 4,194,304
    float* part_kv = f + 12582912;             // 4,194,304 floats (scratch region)
    double* part_ks = (double*)(f + 16777216); // 32,768 doubles
    float* KVb     = f + 16842752;             // 262,144 -> ends 17,104,896
    __bf16* genc   = (__bf16*)(f + 17104896);  // 196,608 bf16 (98,304 slots)
    __bf16* venc   = (__bf16*)(f + 17203200);  // 262,144 bf16 (131,072 slots)
    float* o_s     = k_s;                      // reuse (phi_k dead after kv_part_k)
    float* proj_part = part_kv;                // reuse (after kvreduce)
    // wenc (2.36M bf16 = 1,179,648 slots) + xenc (1.58M bf16 = 787,968 slots)
    // overlaid on part_kv region; both dead before kv_part_k writes it.
    __bf16* wenc   = (__bf16*)(f + 12582912);
    __bf16* xenc   = (__bf16*)(f + 13762560);
    __bf16* genc_q = genc;
    __bf16* genc_k = genc + (size_t)2*3*128*128;

    dim3 blk(256);
    enc_all_k<<<1792, blk, 0, stream>>>(q_w, k_w, v_w, g1_q, g2_q, g1_k, g2_k,
                                        wenc, genc, venc);
    enc_x_k  <<<dim3(64,4,2), blk, 0, stream>>>(x, xenc);
    conv_mfma_k<<<dim3(64,32), blk, 0, stream>>>(xenc, wenc, q_b, k_b,
                                                 gamma_q, beta_q, gamma_k, beta_k,
                                                 q_s, k_s);
    vproj_mfma_k<<<dim3(128,8), blk, 0, stream>>>(xenc, venc, v_s);
    sketch_mfma_k<<<1024, blk, 0, stream>>>(q_s, genc_q);
    sketch_mfma_k<<<1024, blk, 0, stream>>>(k_s, genc_k);
    kv_part_k<<<dim3(16,16), blk, 0, stream>>>(k_s, v_s, part_kv, part_ks);
    kvreduce_k<<<1024, blk, 0, stream>>>(part_kv, KVb);
    numden_k <<<dim3(32,16), blk, 0, stream>>>(q_s, KVb, part_ks, o_s);
    proj_part_k<<<dim3(128,4), blk, 0, stream>>>(o_s, proj_w, proj_part);
    proj_reduce_k<<<512, blk, 0, stream>>>(proj_part, proj_b, (float*)d_out);
}

// Round 10
// 301.178 us; speedup vs baseline: 2.2197x; 1.2197x over previous
//
#include <hip/hip_runtime.h>
#include <math.h>

// Problem constants
#define BB 2
#define DD 128
#define LL 2048
#define HH 8
#define OC 1024     // H*D
#define RR_ 128
#define BL (BB*LL)          // 4096
#define NROW (BL*HH)        // 32768
#define XROWS 2052

// Numerics ledger (absmax bf16-quantized; threshold 180.48):
//   r3 full fp64 -> 128 PASS | r2 seq fp32 -> 192 FAIL | r5 chunk32+tanhf -> 192 FAIL
//   r6 chunk4/chunk8+fp64 tanh -> 128 PASS | r7 conv 3-plane MFMA -> 64 PASS
//   r8 sketch 3-plane + vproj 2-plane MFMA -> 64 PASS | r9 conv restructured -> 64 PASS, 367us
// r10: numerator tail (KV, num, proj) -> 2-plane/4-pass split-bf16 MFMA
//      (rel ~1e-5, budget ~1e-3). Denominator paths (Ksum, den) kept fp64
//      from fp32 phi, identical arithmetic. conv/sketch untouched.

typedef __bf16  bf16x8  __attribute__((ext_vector_type(8)));
typedef float   float4v __attribute__((ext_vector_type(4)));

__device__ __forceinline__ void enc2(const float* src, bf16x8& p1, bf16x8& p2) {
    #pragma unroll
    for (int j = 0; j < 8; ++j) {
        float v = src[j];
        __bf16 h1 = (__bf16)v;
        p1[j] = h1;
        p2[j] = (__bf16)(v - (float)h1);
    }
}

// ---------------------------------------------------------------------------
// Kernel 0a: encode weights to bf16 planes (conv 3-plane, sketch 3-plane,
// v 2-plane, proj 2-plane).
// ---------------------------------------------------------------------------
__global__ __launch_bounds__(256) void enc_all_k(
    const float* __restrict__ q_w, const float* __restrict__ k_w,
    const float* __restrict__ v_w, const float* __restrict__ pw,
    const float* __restrict__ g1_q, const float* __restrict__ g2_q,
    const float* __restrict__ g1_k, const float* __restrict__ g2_k,
    __bf16* __restrict__ wenc, __bf16* __restrict__ genc,
    __bf16* __restrict__ venc, __bf16* __restrict__ penc)
{
    const int gid = blockIdx.x*256 + threadIdx.x;
    if (gid < 262144) {
        const int o = gid >> 7, c = gid & 127;
        #pragma unroll
        for (int t = 0; t < 3; ++t) {
            float v = (o < 1024) ? q_w[(o*128 + c)*3 + t]
                                 : k_w[((o-1024)*128 + c)*3 + t];
            __bf16 h1 = (__bf16)v;  float r1 = v - (float)h1;
            __bf16 h2 = (__bf16)r1; float r2 = r1 - (float)h2;
            __bf16 h3 = (__bf16)r2;
            wenc[((size_t)(0*3 + t)*2048 + o)*128 + c] = h1;
            wenc[((size_t)(1*3 + t)*2048 + o)*128 + c] = h2;
            wenc[((size_t)(2*3 + t)*2048 + o)*128 + c] = h3;
        }
    } else if (gid < 262144 + 65536) {
        const int g = gid - 262144;
        const int mat = g >> 14, rem = g & 16383;
        const int r = rem >> 7, d = rem & 127;
        const float* src = (mat == 0) ? g1_q : (mat == 1) ? g2_q
                         : (mat == 2) ? g1_k : g2_k;
        float v = src[d*RR_ + r];
        __bf16 h1 = (__bf16)v;  float r1 = v - (float)h1;
        __bf16 h2 = (__bf16)r1; float r2 = r1 - (float)h2;
        __bf16 h3 = (__bf16)r2;
        genc[((size_t)(mat*3 + 0)*128 + r)*128 + d] = h1;
        genc[((size_t)(mat*3 + 1)*128 + r)*128 + d] = h2;
        genc[((size_t)(mat*3 + 2)*128 + r)*128 + d] = h3;
    } else if (gid < 262144 + 65536 + 131072) {
        const int g = gid - 262144 - 65536;
        const int o = g >> 7, c = g & 127;
        float v = v_w[o*128 + c];
        __bf16 h1 = (__bf16)v;  float r1 = v - (float)h1;
        __bf16 h2 = (__bf16)r1;
        venc[((size_t)0*1024 + o)*128 + c] = h1;
        venc[((size_t)1*1024 + o)*128 + c] = h2;
    } else if (gid < 262144 + 65536 + 131072 + 131072) {
        const int g = gid - 262144 - 65536 - 131072;
        const int j = g >> 10, k = g & 1023;
        float v = pw[(size_t)j*OC + k];
        __bf16 h1 = (__bf16)v;  float r1 = v - (float)h1;
        __bf16 h2 = (__bf16)r1;
        penc[((size_t)(0*128 + j))*OC + k] = h1;
        penc[((size_t)(1*128 + j))*OC + k] = h2;
    }
}

// ---------------------------------------------------------------------------
// Kernel 0b: encode x once to 3 bf16 planes, [plane][b][l+2][c].
// ---------------------------------------------------------------------------
__global__ __launch_bounds__(256) void enc_x_k(
    const float* __restrict__ x, __bf16* __restrict__ xenc)
{
    __shared__ float t[32][33];
    const int tid = threadIdx.x;
    const int lt = blockIdx.x, ct = blockIdx.y, b = blockIdx.z;
    const int l0 = lt*32, c0 = ct*32;
    for (int e = tid; e < 32*32; e += 256) {
        int c = e >> 5, l = e & 31;
        t[c][l] = x[((size_t)(b*DD + c0 + c))*LL + l0 + l];
    }
    __syncthreads();
    for (int e = tid; e < 32*32; e += 256) {
        int l = e >> 5, c = e & 31;
        float v = t[c][l];
        __bf16 h1 = (__bf16)v;  float r1 = v - (float)h1;
        __bf16 h2 = (__bf16)r1; float r2 = r1 - (float)h2;
        __bf16 h3 = (__bf16)r2;
        const size_t row = (size_t)(l0 + l + 2);
        xenc[((size_t)(0*2 + b)*XROWS + row)*128 + c0 + c] = h1;
        xenc[((size_t)(1*2 + b)*XROWS + row)*128 + c0 + c] = h2;
        xenc[((size_t)(2*2 + b)*XROWS + row)*128 + c0 + c] = h3;
    }
    if (lt == 0 && ct == 0) {
        for (int e = tid; e < 2*128; e += 256) {
            int row = e >> 7, c = e & 127;
            xenc[((size_t)(0*2 + b)*XROWS + row)*128 + c] = (__bf16)0.f;
            xenc[((size_t)(1*2 + b)*XROWS + row)*128 + c] = (__bf16)0.f;
            xenc[((size_t)(2*2 + b)*XROWS + row)*128 + c] = (__bf16)0.f;
        }
    }
}

// ---------------------------------------------------------------------------
// Kernel 1: fused q+k conv as split-bf16 MFMA GEMM (r9-proven).
// ---------------------------------------------------------------------------
__global__ __launch_bounds__(256) void conv_mfma_k(
    const __bf16* __restrict__ xenc, const __bf16* __restrict__ wenc,
    const float* __restrict__ q_b, const float* __restrict__ k_b,
    const float* __restrict__ gamma_q, const float* __restrict__ beta_q,
    const float* __restrict__ gamma_k, const float* __restrict__ beta_k,
    float* __restrict__ q_s, float* __restrict__ k_s)
{
    __shared__ __bf16 As[3][66][136];
    const int tid  = threadIdx.x;
    const int wave = tid >> 6;
    const int lane = tid & 63;
    const int m    = lane & 15;
    const int quad = lane >> 4;
    const int bx = blockIdx.x;
    const int b  = bx >> 5;
    const int lb0 = (bx & 31) << 6;
    const int o0 = blockIdx.y << 6;
    const int osub = o0 + wave*16;

    for (int e = tid; e < 3*66*16; e += 256) {
        const int p = e / (66*16), rem = e % (66*16);
        const int row = rem >> 4, cg = rem & 15;
        *(bf16x8*)&As[p][row][cg*8] =
            *(const bf16x8*)&xenc[((size_t)(p*2 + b)*XROWS + lb0 + row)*128 + cg*8];
    }
    __syncthreads();

    float4v accm[4][4];
    float4v corr[4];
    #pragma unroll
    for (int lt = 0; lt < 4; ++lt) {
        corr[lt] = (float4v){0.f,0.f,0.f,0.f};
        #pragma unroll
        for (int c = 0; c < 4; ++c) accm[lt][c] = (float4v){0.f,0.f,0.f,0.f};
    }

    #pragma unroll
    for (int cidx = 0; cidx < 4; ++cidx) {
        const int c0 = cidx << 5;
        #pragma unroll
        for (int t = 0; t < 3; ++t) {
            bf16x8 B1, B2, B3;
            {
                size_t base = ((size_t)t*2048 + osub + m)*128 + c0 + quad*8;
                B1 = *(const bf16x8*)&wenc[base];
                B2 = *(const bf16x8*)&wenc[base + (size_t)3*2048*128];
                B3 = *(const bf16x8*)&wenc[base + (size_t)6*2048*128];
            }
            #pragma unroll
            for (int lt = 0; lt < 4; ++lt) {
                const int row = lt*16 + m + t;
                bf16x8 A1 = *(const bf16x8*)&As[0][row][c0 + quad*8];
                bf16x8 A2 = *(const bf16x8*)&As[1][row][c0 + quad*8];
                bf16x8 A3 = *(const bf16x8*)&As[2][row][c0 + quad*8];
                accm[lt][cidx] = __builtin_amdgcn_mfma_f32_16x16x32_bf16(A1, B1, accm[lt][cidx], 0, 0, 0);
                corr[lt] = __builtin_amdgcn_mfma_f32_16x16x32_bf16(A1, B2, corr[lt], 0, 0, 0);
                corr[lt] = __builtin_amdgcn_mfma_f32_16x16x32_bf16(A2, B1, corr[lt], 0, 0, 0);
                corr[lt] = __builtin_amdgcn_mfma_f32_16x16x32_bf16(A1, B3, corr[lt], 0, 0, 0);
                corr[lt] = __builtin_amdgcn_mfma_f32_16x16x32_bf16(A3, B1, corr[lt], 0, 0, 0);
                corr[lt] = __builtin_amdgcn_mfma_f32_16x16x32_bf16(A2, B2, corr[lt], 0, 0, 0);
            }
        }
    }

    const int is_k = (o0 >= 1024);
    const double g  = (double)(is_k ? gamma_k[0] : gamma_q[0]);
    const double be = (double)(is_k ? beta_k[0]  : beta_q[0]);
    const int o_global = osub + m;
    const int o_local  = o_global - (is_k ? 1024 : 0);
    const double bias  = (double)(is_k ? k_b[o_local] : q_b[o_local]);
    float* dest = is_k ? k_s : q_s;
    #pragma unroll
    for (int lt = 0; lt < 4; ++lt) {
        #pragma unroll
        for (int reg = 0; reg < 4; ++reg) {
            double s = (double)corr[lt][reg];
            #pragma unroll
            for (int c = 0; c < 4; ++c) s += (double)accm[lt][c][reg];
            const int l = lb0 + lt*16 + quad*4 + reg;
            dest[((size_t)(b*LL + l))*OC + o_local] = (float)(g*(s + bias) + be);
        }
    }
}

// ---------------------------------------------------------------------------
// Kernel 2: V projection, 2-plane MFMA from xenc (r9-proven).
// ---------------------------------------------------------------------------
__global__ __launch_bounds__(256) void vproj_mfma_k(
    const __bf16* __restrict__ xenc, const __bf16* __restrict__ venc,
    float* __restrict__ v_out)
{
    __shared__ __bf16 As[2][32][136];
    const int tid  = threadIdx.x;
    const int wave = tid >> 6;
    const int lane = tid & 63;
    const int m    = lane & 15;
    const int quad = lane >> 4;
    const int bx = blockIdx.x;
    const int b  = bx >> 6;
    const int l0 = (bx & 63) << 5;
    const int o0 = blockIdx.y << 7;

    for (int e = tid; e < 2*32*16; e += 256) {
        const int p = e >> 9, rem = e & 511;
        const int row = rem >> 4, cg = rem & 15;
        *(bf16x8*)&As[p][row][cg*8] =
            *(const bf16x8*)&xenc[((size_t)(p*2 + b)*XROWS + l0 + row + 2)*128 + cg*8];
    }
    __syncthreads();

    float4v accm[2][2], corr[2][2];
    #pragma unroll
    for (int mt = 0; mt < 2; ++mt)
        #pragma unroll
        for (int nt = 0; nt < 2; ++nt) {
            accm[mt][nt] = (float4v){0.f,0.f,0.f,0.f};
            corr[mt][nt] = (float4v){0.f,0.f,0.f,0.f};
        }

    #pragma unroll
    for (int ck = 0; ck < 4; ++ck) {
        const int k0 = ck << 5;
        bf16x8 A1[2], A2[2];
        #pragma unroll
        for (int mt = 0; mt < 2; ++mt) {
            A1[mt] = *(const bf16x8*)&As[0][mt*16 + m][k0 + quad*8];
            A2[mt] = *(const bf16x8*)&As[1][mt*16 + m][k0 + quad*8];
        }
        #pragma unroll
        for (int nt = 0; nt < 2; ++nt) {
            const int o = o0 + wave*32 + nt*16 + m;
            size_t base = ((size_t)o)*128 + k0 + quad*8;
            bf16x8 B1 = *(const bf16x8*)&venc[base];
            bf16x8 B2 = *(const bf16x8*)&venc[base + (size_t)1024*128];
            #pragma unroll
            for (int mt = 0; mt < 2; ++mt) {
                accm[mt][nt] = __builtin_amdgcn_mfma_f32_16x16x32_bf16(A1[mt], B1, accm[mt][nt], 0, 0, 0);
                corr[mt][nt] = __builtin_amdgcn_mfma_f32_16x16x32_bf16(A1[mt], B2, corr[mt][nt], 0, 0, 0);
                corr[mt][nt] = __builtin_amdgcn_mfma_f32_16x16x32_bf16(A2[mt], B1, corr[mt][nt], 0, 0, 0);
                corr[mt][nt] = __builtin_amdgcn_mfma_f32_16x16x32_bf16(A2[mt], B2, corr[mt][nt], 0, 0, 0);
            }
        }
    }

    #pragma unroll
    for (int mt = 0; mt < 2; ++mt)
        #pragma unroll
        for (int nt = 0; nt < 2; ++nt)
            #pragma unroll
            for (int reg = 0; reg < 4; ++reg) {
                const int l = l0 + mt*16 + quad*4 + reg;
                const int o = o0 + wave*32 + nt*16 + m;
                v_out[((size_t)(b*LL + l))*OC + o] = accm[mt][nt][reg] + corr[mt][nt][reg];
            }
}

// ---------------------------------------------------------------------------
// Kernel 3: sketch, 3-plane/6-pass MFMA in-place (r8-proven).
// ---------------------------------------------------------------------------
__global__ __launch_bounds__(256) void sketch_mfma_k(
    float* __restrict__ buf, const __bf16* __restrict__ genc)
{
    __shared__ __bf16 As[3][32][136];
    const int tid  = threadIdx.x;
    const int wave = tid >> 6;
    const int lane = tid & 63;
    const int m    = lane & 15;
    const int quad = lane >> 4;
    const size_t i0 = (size_t)blockIdx.x * 32;

    for (int e = tid; e < 32*128; e += 256) {
        int row = e >> 7, d = e & 127;
        float v = buf[(i0 + row)*RR_ + d];
        __bf16 h1 = (__bf16)v;  float r1 = v - (float)h1;
        __bf16 h2 = (__bf16)r1; float r2 = r1 - (float)h2;
        __bf16 h3 = (__bf16)r2;
        As[0][row][d] = h1; As[1][row][d] = h2; As[2][row][d] = h3;
    }
    __syncthreads();

    float4v accm[2][2][2], corr[2][2][2];
    #pragma unroll
    for (int mt = 0; mt < 2; ++mt)
        #pragma unroll
        for (int nt = 0; nt < 2; ++nt)
            #pragma unroll
            for (int mat = 0; mat < 2; ++mat) {
                accm[mt][nt][mat] = (float4v){0.f,0.f,0.f,0.f};
                corr[mt][nt][mat] = (float4v){0.f,0.f,0.f,0.f};
            }

    #pragma unroll
    for (int ck = 0; ck < 4; ++ck) {
        const int k0 = ck << 5;
        bf16x8 A1[2], A2[2], A3[2];
        #pragma unroll
        for (int mt = 0; mt < 2; ++mt) {
            A1[mt] = *(const bf16x8*)&As[0][mt*16 + m][k0 + quad*8];
            A2[mt] = *(const bf16x8*)&As[1][mt*16 + m][k0 + quad*8];
            A3[mt] = *(const bf16x8*)&As[2][mt*16 + m][k0 + quad*8];
        }
        #pragma unroll
        for (int nt = 0; nt < 2; ++nt) {
            const int r = wave*32 + nt*16 + m;
            #pragma unroll
            for (int mat = 0; mat < 2; ++mat) {
                size_t base = ((size_t)(mat*3)*128 + r)*128 + k0 + quad*8;
                bf16x8 B1 = *(const bf16x8*)&genc[base];
                bf16x8 B2 = *(const bf16x8*)&genc[base + (size_t)128*128];
                bf16x8 B3 = *(const bf16x8*)&genc[base + (size_t)2*128*128];
                #pragma unroll
                for (int mt = 0; mt < 2; ++mt) {
                    accm[mt][nt][mat] = __builtin_amdgcn_mfma_f32_16x16x32_bf16(A1[mt], B1, accm[mt][nt][mat], 0, 0, 0);
                    corr[mt][nt][mat] = __builtin_amdgcn_mfma_f32_16x16x32_bf16(A1[mt], B2, corr[mt][nt][mat], 0, 0, 0);
                    corr[mt][nt][mat] = __builtin_amdgcn_mfma_f32_16x16x32_bf16(A2[mt], B1, corr[mt][nt][mat], 0, 0, 0);
                    corr[mt][nt][mat] = __builtin_amdgcn_mfma_f32_16x16x32_bf16(A1[mt], B3, corr[mt][nt][mat], 0, 0, 0);
                    corr[mt][nt][mat] = __builtin_amdgcn_mfma_f32_16x16x32_bf16(A3[mt], B1, corr[mt][nt][mat], 0, 0, 0);
                    corr[mt][nt][mat] = __builtin_amdgcn_mfma_f32_16x16x32_bf16(A2[mt], B2, corr[mt][nt][mat], 0, 0, 0);
                }
            }
        }
    }
    __syncthreads();

    const double SR  = 11.313708498984760390;
    const double ISR = 0.088388347648318440550;
    #pragma unroll
    for (int mt = 0; mt < 2; ++mt)
        #pragma unroll
        for (int nt = 0; nt < 2; ++nt)
            #pragma unroll
            for (int reg = 0; reg < 4; ++reg) {
                double u1 = (double)accm[mt][nt][0][reg] + (double)corr[mt][nt][0][reg];
                double u2 = (double)accm[mt][nt][1][reg] + (double)corr[mt][nt][1][reg];
                double phi = SR * tanh(u1*u2*ISR);
                const size_t row = i0 + mt*16 + quad*4 + reg;
                const int col = wave*32 + nt*16 + m;
                buf[row*RR_ + col] = (float)phi;
            }
}

// ---------------------------------------------------------------------------
// Kernel 4: KV^T partials via 2-plane MFMA + fp64 Ksum partials.
// Per (split, bh): KVT[d][r] += sum_{l in split} v[l,d]*phi_k[l,r].
// m=d (A=v), n=r (B=phi_k), k=l. Stage fp32 transposed [128][36], encode at
// frag load. grid (16,16), block 512 (8 waves: d-half x r-quarter).
// ---------------------------------------------------------------------------
__global__ __launch_bounds__(512) void kv_mfma_k(
    const float* __restrict__ phi_k, const float* __restrict__ v,
    float* __restrict__ part_kv, double* __restrict__ part_ks)
{
    __shared__ float Pt[128*36];     // phi_k^T [r][l]
    __shared__ float Vt[128*36];     // v^T     [d][l]
    __shared__ double ksred[512];
    const int tid  = threadIdx.x;
    const int wave = tid >> 6;
    const int lane = tid & 63;
    const int m    = lane & 15;
    const int quad = lane >> 4;
    const int split = blockIdx.x;    // 16
    const int bh    = blockIdx.y;    // 16
    const int b = bh >> 3, h = bh & 7;
    const int lbase = split * 128;
    const int dh = wave & 1;         // d half (4 mt of 16)
    const int rq = wave >> 1;        // r quarter (2 nt of 16)

    float4v accm[4][2], corr[4][2];
    #pragma unroll
    for (int mt = 0; mt < 4; ++mt)
        #pragma unroll
        for (int nt = 0; nt < 2; ++nt) {
            accm[mt][nt] = (float4v){0.f,0.f,0.f,0.f};
            corr[mt][nt] = (float4v){0.f,0.f,0.f,0.f};
        }
    double ks = 0.0;

    for (int ch = 0; ch < 4; ++ch) {
        __syncthreads();
        for (int e = tid; e < 32*128; e += 512) {
            const int l = e >> 7, r = e & 127;
            size_t base = ((size_t)(b*LL + lbase + ch*32 + l)*HH + h)*RR_;
            float pv = phi_k[base + r];
            float vv = v[base + r];
            Pt[r*36 + l] = pv;
            Vt[r*36 + l] = vv;
            ks += (double)pv;        // fixed r per thread; fp64 Ksum path
        }
        __syncthreads();
        bf16x8 A1[4], A2[4], B1[2], B2[2];
        #pragma unroll
        for (int mt = 0; mt < 4; ++mt)
            enc2(&Vt[(dh*64 + mt*16 + m)*36 + quad*8], A1[mt], A2[mt]);
        #pragma unroll
        for (int nt = 0; nt < 2; ++nt)
            enc2(&Pt[(rq*32 + nt*16 + m)*36 + quad*8], B1[nt], B2[nt]);
        #pragma unroll
        for (int mt = 0; mt < 4; ++mt)
            #pragma unroll
            for (int nt = 0; nt < 2; ++nt) {
                accm[mt][nt] = __builtin_amdgcn_mfma_f32_16x16x32_bf16(A1[mt], B1[nt], accm[mt][nt], 0, 0, 0);
                corr[mt][nt] = __builtin_amdgcn_mfma_f32_16x16x32_bf16(A1[mt], B2[nt], corr[mt][nt], 0, 0, 0);
                corr[mt][nt] = __builtin_amdgcn_mfma_f32_16x16x32_bf16(A2[mt], B1[nt], corr[mt][nt], 0, 0, 0);
                corr[mt][nt] = __builtin_amdgcn_mfma_f32_16x16x32_bf16(A2[mt], B2[nt], corr[mt][nt], 0, 0, 0);
            }
    }

    ksred[tid] = ks;
    __syncthreads();
    if (tid < 128) {
        double s = ksred[tid] + ksred[tid+128] + ksred[tid+256] + ksred[tid+384];
        part_ks[(bh*16 + split)*RR_ + tid] = s;
    }

    float* outp = part_kv + ((size_t)(bh*16 + split))*RR_*DD;  // [d][r]
    #pragma unroll
    for (int mt = 0; mt < 4; ++mt)
        #pragma unroll
        for (int nt = 0; nt < 2; ++nt)
            #pragma unroll
            for (int reg = 0; reg < 4; ++reg) {
                const int d = dh*64 + mt*16 + quad*4 + reg;
                const int r = rq*32 + nt*16 + m;
                outp[d*128 + r] = accm[mt][nt][reg] + corr[mt][nt][reg];
            }
}

// ---------------------------------------------------------------------------
// Kernel 5: reduce KVT partials over 16 splits -> bf16 2-plane KVTenc.
// ---------------------------------------------------------------------------
__global__ __launch_bounds__(256) void kvreduce_k(
    const float* __restrict__ part_kv, __bf16* __restrict__ kvt_enc)
{
    const int gid = blockIdx.x*256 + threadIdx.x;
    if (gid >= 16*RR_*DD) return;
    const int bh = gid >> 14;
    const int rd = gid & 16383;
    float s = 0.f;
    #pragma unroll
    for (int c = 0; c < 16; ++c)
        s += part_kv[(((size_t)(bh*16 + c)) << 14) + rd];
    __bf16 h1 = (__bf16)s;
    __bf16 h2 = (__bf16)(s - (float)h1);
    kvt_enc[(size_t)bh*16384 + rd] = h1;
    kvt_enc[(size_t)(16 + bh)*16384 + rd] = h2;
}

// ---------------------------------------------------------------------------
// Kernel 6: numerator via 2-plane MFMA (A=phi_q natural, B=KVTenc) +
// fp64 den from fp32 phi_q in LDS (unchanged arithmetic).
// grid (32 l-tiles of 64, 16 bh), block 256.
// ---------------------------------------------------------------------------
__global__ __launch_bounds__(256) void numden_mfma_k(
    const float* __restrict__ phi_q, const __bf16* __restrict__ kvt_enc,
    const double* __restrict__ part_ks, float* __restrict__ o_out)
{
    __shared__ float Pq[64*132];
    __shared__ double Ks_s[128];
    __shared__ double den_s[64];
    const int tid  = threadIdx.x;
    const int wave = tid >> 6;
    const int lane = tid & 63;
    const int m    = lane & 15;
    const int quad = lane >> 4;
    const int lt = blockIdx.x;
    const int bh = blockIdx.y;
    const int b = bh >> 3, h = bh & 7;
    const int l0 = lt * 64;

    if (tid < 128) {
        double s = 0.0;
        #pragma unroll
        for (int c = 0; c < 16; ++c) s += part_ks[(bh*16 + c)*RR_ + tid];
        Ks_s[tid] = s;
    }
    for (int e = tid; e < 64*128; e += 256) {
        const int l = e >> 7, r = e & 127;
        Pq[l*132 + r] = phi_q[((size_t)(b*LL + l0 + l)*HH + h)*RR_ + r];
    }
    __syncthreads();

    double den = 0.0;
    if (tid < 64) {
        #pragma unroll
        for (int r = 0; r < 128; ++r)
            den += (double)Pq[tid*132 + r] * Ks_s[r];
    }

    float4v accm[4][2], corr[4][2];
    #pragma unroll
    for (int mt = 0; mt < 4; ++mt)
        #pragma unroll
        for (int nt = 0; nt < 2; ++nt) {
            accm[mt][nt] = (float4v){0.f,0.f,0.f,0.f};
            corr[mt][nt] = (float4v){0.f,0.f,0.f,0.f};
        }

    #pragma unroll
    for (int ck = 0; ck < 4; ++ck) {
        const int k0 = ck << 5;
        bf16x8 A1[4], A2[4];
        #pragma unroll
        for (int mt = 0; mt < 4; ++mt)
            enc2(&Pq[(mt*16 + m)*132 + k0 + quad*8], A1[mt], A2[mt]);
        #pragma unroll
        for (int nt = 0; nt < 2; ++nt) {
            const int d = wave*32 + nt*16 + m;
            size_t base = ((size_t)bh*128 + d)*128 + k0 + quad*8;
            bf16x8 B1 = *(const bf16x8*)&kvt_enc[base];
            bf16x8 B2 = *(const bf16x8*)&kvt_enc[base + (size_t)16*16384];
            #pragma unroll
            for (int mt = 0; mt < 4; ++mt) {
                accm[mt][nt] = __builtin_amdgcn_mfma_f32_16x16x32_bf16(A1[mt], B1, accm[mt][nt], 0, 0, 0);
                corr[mt][nt] = __builtin_amdgcn_mfma_f32_16x16x32_bf16(A1[mt], B2, corr[mt][nt], 0, 0, 0);
                corr[mt][nt] = __builtin_amdgcn_mfma_f32_16x16x32_bf16(A2[mt], B1, corr[mt][nt], 0, 0, 0);
                corr[mt][nt] = __builtin_amdgcn_mfma_f32_16x16x32_bf16(A2[mt], B2, corr[mt][nt], 0, 0, 0);
            }
        }
    }

    __syncthreads();
    if (tid < 64) den_s[tid] = den;
    __syncthreads();

    #pragma unroll
    for (int mt = 0; mt < 4; ++mt)
        #pragma unroll
        for (int nt = 0; nt < 2; ++nt)
            #pragma unroll
            for (int reg = 0; reg < 4; ++reg) {
                const int ll = mt*16 + quad*4 + reg;
                const int d  = wave*32 + nt*16 + m;
                const float inv = (float)(1.0 / (den_s[ll] + 1e-6));
                o_out[((size_t)(b*LL + l0 + ll))*OC + h*DD + d] =
                    (accm[mt][nt][reg] + corr[mt][nt][reg]) * inv;
            }
}

// ---------------------------------------------------------------------------
// Kernel 7a: output projection partials via 2-plane MFMA.
// grid (128 row-blocks of 32, 4 ksplits), block 256.
// ---------------------------------------------------------------------------
__global__ __launch_bounds__(256) void proj_part_mfma_k(
    const float* __restrict__ o_s, const __bf16* __restrict__ penc,
    float* __restrict__ part)
{
    __shared__ float As[32*260];
    const int tid  = threadIdx.x;
    const int wave = tid >> 6;
    const int lane = tid & 63;
    const int m    = lane & 15;
    const int quad = lane >> 4;
    const int row0  = blockIdx.x * 32;
    const int kbase = blockIdx.y * 256;

    for (int e = tid; e < 32*256; e += 256) {
        const int row = e >> 8, k = e & 255;
        As[row*260 + k] = o_s[(size_t)(row0 + row)*OC + kbase + k];
    }
    __syncthreads();

    float4v accm[2][2], corr[2][2];
    #pragma unroll
    for (int mt = 0; mt < 2; ++mt)
        #pragma unroll
        for (int nt = 0; nt < 2; ++nt) {
            accm[mt][nt] = (float4v){0.f,0.f,0.f,0.f};
            corr[mt][nt] = (float4v){0.f,0.f,0.f,0.f};
        }

    #pragma unroll
    for (int ck = 0; ck < 8; ++ck) {
        const int k0 = ck << 5;
        bf16x8 A1[2], A2[2];
        #pragma unroll
        for (int mt = 0; mt < 2; ++mt)
            enc2(&As[(mt*16 + m)*260 + k0 + quad*8], A1[mt], A2[mt]);
        #pragma unroll
        for (int nt = 0; nt < 2; ++nt) {
            const int j = wave*32 + nt*16 + m;
            size_t base = ((size_t)j)*OC + kbase + k0 + quad*8;
            bf16x8 B1 = *(const bf16x8*)&penc[base];
            bf16x8 B2 = *(const bf16x8*)&penc[base + (size_t)128*OC];
            #pragma unroll
            for (int mt = 0; mt < 2; ++mt) {
                accm[mt][nt] = __builtin_amdgcn_mfma_f32_16x16x32_bf16(A1[mt], B1, accm[mt][nt], 0, 0, 0);
                corr[mt][nt] = __builtin_amdgcn_mfma_f32_16x16x32_bf16(A1[mt], B2, corr[mt][nt], 0, 0, 0);
                corr[mt][nt] = __builtin_amdgcn_mfma_f32_16x16x32_bf16(A2[mt], B1, corr[mt][nt], 0, 0, 0);
                corr[mt][nt] = __builtin_amdgcn_mfma_f32_16x16x32_bf16(A2[mt], B2, corr[mt][nt], 0, 0, 0);
            }
        }
    }

    float* outp = part + (size_t)blockIdx.y*BL*DD;
    #pragma unroll
    for (int mt = 0; mt < 2; ++mt)
        #pragma unroll
        for (int nt = 0; nt < 2; ++nt)
            #pragma unroll
            for (int reg = 0; reg < 4; ++reg) {
                const int row = row0 + mt*16 + quad*4 + reg;
                const int j   = wave*32 + nt*16 + m;
                outp[(size_t)row*DD + j] = accm[mt][nt][reg] + corr[mt][nt][reg];
            }
}

// ---------------------------------------------------------------------------
// Kernel 7b: reduce the 4 K-split partials + bias.
// ---------------------------------------------------------------------------
__global__ __launch_bounds__(256) void proj_reduce_k(
    const float* __restrict__ part, const float* __restrict__ pb,
    float* __restrict__ out)
{
    const int gid = blockIdx.x*256 + threadIdx.x;
    if (gid >= BL*DD/4) return;
    const float4* p4 = (const float4*)part;
    float4 s = p4[gid];
    #pragma unroll
    for (int c = 1; c < 4; ++c) {
        float4 t = p4[gid + (size_t)c*(BL*DD/4)];
        s.x += t.x; s.y += t.y; s.z += t.z; s.w += t.w;
    }
    const int col = (gid << 2) & (DD-1);
    s.x += pb[col]; s.y += pb[col+1]; s.z += pb[col+2]; s.w += pb[col+3];
    ((float4*)out)[gid] = s;
}

// ---------------------------------------------------------------------------
extern "C" void kernel_launch(void* const* d_in, const int* in_sizes, int n_in,
                              void* d_out, int out_size, void* d_ws, size_t ws_size,
                              hipStream_t stream) {
    const float* x       = (const float*)d_in[0];
    const float* q_w     = (const float*)d_in[1];
    const float* q_b     = (const float*)d_in[2];
    const float* k_w     = (const float*)d_in[3];
    const float* k_b     = (const float*)d_in[4];
    const float* v_w     = (const float*)d_in[5];
    const float* g1_q    = (const float*)d_in[6];
    const float* g2_q    = (const float*)d_in[7];
    const float* g1_k    = (const float*)d_in[8];
    const float* g2_k    = (const float*)d_in[9];
    const float* gamma_q = (const float*)d_in[10];
    const float* beta_q  = (const float*)d_in[11];
    const float* gamma_k = (const float*)d_in[12];
    const float* beta_k  = (const float*)d_in[13];
    const float* proj_w  = (const float*)d_in[14];
    const float* proj_b  = (const float*)d_in[15];

    float* f = (float*)d_ws;
    float* q_s     = f;                        // 4,194,304 floats
    float* k_s     = f + 4194304;              // 4,194,304
    float* v_s     = f + 8388608;              // 4,194,304
    float* part_kv = f + 12582912;             // 4,194,304 (scratch: wenc/xenc/kv parts/proj parts)
    double* part_ks = (double*)(f + 16777216); // 32,768 doubles
    __bf16* kvt_enc = (__bf16*)(f + 16842752); // 524,288 bf16 (262,144 slots, old KVb region)
    __bf16* genc   = (__bf16*)(f + 17104896);  // 196,608 bf16
    __bf16* venc   = (__bf16*)(f + 17203200);  // 262,144 bf16
    __bf16* penc   = (__bf16*)(f + 17334272);  // 262,144 bf16 (131,072 slots)
    float* o_s     = k_s;                      // reuse (phi_k dead after kv_mfma)
    float* proj_part = part_kv;                // reuse (kv parts dead after kvreduce)
    __bf16* wenc   = (__bf16*)(f + 12582912);
    __bf16* xenc   = (__bf16*)(f + 13762560);
    __bf16* genc_q = genc;
    __bf16* genc_k = genc + (size_t)2*3*128*128;

    dim3 blk(256);
    enc_all_k<<<2304, blk, 0, stream>>>(q_w, k_w, v_w, proj_w,
                                        g1_q, g2_q, g1_k, g2_k,
                                        wenc, genc, venc, penc);
    enc_x_k  <<<dim3(64,4,2), blk, 0, stream>>>(x, xenc);
    conv_mfma_k<<<dim3(64,32), blk, 0, stream>>>(xenc, wenc, q_b, k_b,
                                                 gamma_q, beta_q, gamma_k, beta_k,
                                                 q_s, k_s);
    vproj_mfma_k<<<dim3(128,8), blk, 0, stream>>>(xenc, venc, v_s);
    sketch_mfma_k<<<1024, blk, 0, stream>>>(q_s, genc_q);
    sketch_mfma_k<<<1024, blk, 0, stream>>>(k_s, genc_k);
    kv_mfma_k<<<dim3(16,16), dim3(512), 0, stream>>>(k_s, v_s, part_kv, part_ks);
    kvreduce_k<<<1024, blk, 0, stream>>>(part_kv, kvt_enc);
    numden_mfma_k<<<dim3(32,16), blk, 0, stream>>>(q_s, kvt_enc, part_ks, o_s);
    proj_part_mfma_k<<<dim3(128,4), blk, 0, stream>>>(o_s, penc, proj_part);
    proj_reduce_k<<<512, blk, 0, stream>>>(proj_part, proj_b, (float*)d_out);
}

// Round 11
// 287.645 us; speedup vs baseline: 2.3242x; 1.0470x over previous
//
#include <hip/hip_runtime.h>
#include <math.h>

// Problem constants
#define BB 2
#define DD 128
#define LL 2048
#define HH 8
#define OC 1024     // H*D
#define RR_ 128
#define BL (BB*LL)          // 4096
#define NROW (BL*HH)        // 32768
#define XROWS 2052

// Numerics ledger (absmax bf16-quantized; threshold 180.48):
//   r3 full fp64 -> 128 PASS | r2 seq fp32 -> 192 FAIL | r5 chunk32+tanhf -> 192 FAIL
//   r6 chunk4/chunk8+fp64 tanh -> 128 PASS | r7 conv 3-plane MFMA -> 64 PASS
//   r8 sketch/vproj MFMA -> 64 | r9 conv restructured -> 64, 367us
//   r10 KV/num/proj 2-plane MFMA -> 64, 301us
// r11: structure only — v folded into conv (same staging), corr chain split
//      (depth 60->30, fp64 combine), sketch q+k fused, enc fused. 8 launches.

typedef __bf16  bf16x8  __attribute__((ext_vector_type(8)));
typedef float   float4v __attribute__((ext_vector_type(4)));

__device__ __forceinline__ void enc2(const float* src, bf16x8& p1, bf16x8& p2) {
    #pragma unroll
    for (int j = 0; j < 8; ++j) {
        float v = src[j];
        __bf16 h1 = (__bf16)v;
        p1[j] = h1;
        p2[j] = (__bf16)(v - (float)h1);
    }
}

// ---------------------------------------------------------------------------
// Kernel 0: fused encode. Blocks 0..2303: weights (conv 3-plane, sketch
// 3-plane transposed, v 2-plane, proj 2-plane). Blocks 2304..2815: x 3-plane
// transposed [plane][b][l+2][c].
// ---------------------------------------------------------------------------
__global__ __launch_bounds__(256) void enc_fused_k(
    const float* __restrict__ q_w, const float* __restrict__ k_w,
    const float* __restrict__ v_w, const float* __restrict__ pw,
    const float* __restrict__ g1_q, const float* __restrict__ g2_q,
    const float* __restrict__ g1_k, const float* __restrict__ g2_k,
    const float* __restrict__ x,
    __bf16* __restrict__ wenc, __bf16* __restrict__ genc,
    __bf16* __restrict__ venc, __bf16* __restrict__ penc,
    __bf16* __restrict__ xenc)
{
    __shared__ float t[32][33];
    const int bid = blockIdx.x;
    const int tid = threadIdx.x;
    if (bid < 2304) {
        const int gid = bid*256 + tid;
        if (gid < 262144) {
            const int o = gid >> 7, c = gid & 127;
            #pragma unroll
            for (int tt = 0; tt < 3; ++tt) {
                float v = (o < 1024) ? q_w[(o*128 + c)*3 + tt]
                                     : k_w[((o-1024)*128 + c)*3 + tt];
                __bf16 h1 = (__bf16)v;  float r1 = v - (float)h1;
                __bf16 h2 = (__bf16)r1; float r2 = r1 - (float)h2;
                __bf16 h3 = (__bf16)r2;
                wenc[((size_t)(0*3 + tt)*2048 + o)*128 + c] = h1;
                wenc[((size_t)(1*3 + tt)*2048 + o)*128 + c] = h2;
                wenc[((size_t)(2*3 + tt)*2048 + o)*128 + c] = h3;
            }
        } else if (gid < 262144 + 65536) {
            const int g = gid - 262144;
            const int mat = g >> 14, rem = g & 16383;
            const int r = rem >> 7, d = rem & 127;
            const float* src = (mat == 0) ? g1_q : (mat == 1) ? g2_q
                             : (mat == 2) ? g1_k : g2_k;
            float v = src[d*RR_ + r];
            __bf16 h1 = (__bf16)v;  float r1 = v - (float)h1;
            __bf16 h2 = (__bf16)r1; float r2 = r1 - (float)h2;
            __bf16 h3 = (__bf16)r2;
            genc[((size_t)(mat*3 + 0)*128 + r)*128 + d] = h1;
            genc[((size_t)(mat*3 + 1)*128 + r)*128 + d] = h2;
            genc[((size_t)(mat*3 + 2)*128 + r)*128 + d] = h3;
        } else if (gid < 262144 + 65536 + 131072) {
            const int g = gid - 262144 - 65536;
            const int o = g >> 7, c = g & 127;
            float v = v_w[o*128 + c];
            __bf16 h1 = (__bf16)v;  float r1 = v - (float)h1;
            __bf16 h2 = (__bf16)r1;
            venc[((size_t)0*1024 + o)*128 + c] = h1;
            venc[((size_t)1*1024 + o)*128 + c] = h2;
        } else if (gid < 262144 + 65536 + 131072 + 131072) {
            const int g = gid - 262144 - 65536 - 131072;
            const int j = g >> 10, k = g & 1023;
            float v = pw[(size_t)j*OC + k];
            __bf16 h1 = (__bf16)v;  float r1 = v - (float)h1;
            __bf16 h2 = (__bf16)r1;
            penc[((size_t)(0*128 + j))*OC + k] = h1;
            penc[((size_t)(1*128 + j))*OC + k] = h2;
        }
    } else {
        const int g = bid - 2304;            // 512 blocks: lt(64) x ct(4) x b(2)
        const int lt = g & 63, ct = (g >> 6) & 3, b = g >> 8;
        const int l0 = lt*32, c0 = ct*32;
        for (int e = tid; e < 32*32; e += 256) {
            int c = e >> 5, l = e & 31;
            t[c][l] = x[((size_t)(b*DD + c0 + c))*LL + l0 + l];
        }
        __syncthreads();
        for (int e = tid; e < 32*32; e += 256) {
            int l = e >> 5, c = e & 31;
            float v = t[c][l];
            __bf16 h1 = (__bf16)v;  float r1 = v - (float)h1;
            __bf16 h2 = (__bf16)r1; float r2 = r1 - (float)h2;
            __bf16 h3 = (__bf16)r2;
            const size_t row = (size_t)(l0 + l + 2);
            xenc[((size_t)(0*2 + b)*XROWS + row)*128 + c0 + c] = h1;
            xenc[((size_t)(1*2 + b)*XROWS + row)*128 + c0 + c] = h2;
            xenc[((size_t)(2*2 + b)*XROWS + row)*128 + c0 + c] = h3;
        }
        if (lt == 0 && ct == 0) {
            for (int e = tid; e < 2*128; e += 256) {
                int row = e >> 7, c = e & 127;
                xenc[((size_t)(0*2 + b)*XROWS + row)*128 + c] = (__bf16)0.f;
                xenc[((size_t)(1*2 + b)*XROWS + row)*128 + c] = (__bf16)0.f;
                xenc[((size_t)(2*2 + b)*XROWS + row)*128 + c] = (__bf16)0.f;
            }
        }
    }
}

// ---------------------------------------------------------------------------
// Kernel 1: fused q+k conv (3-plane/6-pass) AND v-projection (2-plane/4-pass)
// sharing one LDS staging. grid (64, 48): y<32 -> q|k conv o-tile, y>=32 ->
// v o-tile (t=2 only). corr chain split in two (depth 30), fp64 combine.
// ---------------------------------------------------------------------------
__global__ __launch_bounds__(256) void conv_mfma_k(
    const __bf16* __restrict__ xenc, const __bf16* __restrict__ wenc,
    const __bf16* __restrict__ venc,
    const float* __restrict__ q_b, const float* __restrict__ k_b,
    const float* __restrict__ gamma_q, const float* __restrict__ beta_q,
    const float* __restrict__ gamma_k, const float* __restrict__ beta_k,
    float* __restrict__ q_s, float* __restrict__ k_s, float* __restrict__ v_s)
{
    __shared__ __bf16 As[3][66][136];
    const int tid  = threadIdx.x;
    const int wave = tid >> 6;
    const int lane = tid & 63;
    const int m    = lane & 15;
    const int quad = lane >> 4;
    const int bx = blockIdx.x;
    const int b  = bx >> 5;
    const int lb0 = (bx & 31) << 6;
    const int yt = blockIdx.y;

    for (int e = tid; e < 3*66*16; e += 256) {
        const int p = e / (66*16), rem = e % (66*16);
        const int row = rem >> 4, cg = rem & 15;
        *(bf16x8*)&As[p][row][cg*8] =
            *(const bf16x8*)&xenc[((size_t)(p*2 + b)*XROWS + lb0 + row)*128 + cg*8];
    }
    __syncthreads();

    if (yt < 32) {
        // ---- q|k conv path ----
        const int o0 = yt << 6;
        const int osub = o0 + wave*16;
        float4v accm[4][4];
        float4v corr[4][2];
        #pragma unroll
        for (int lt = 0; lt < 4; ++lt) {
            corr[lt][0] = (float4v){0.f,0.f,0.f,0.f};
            corr[lt][1] = (float4v){0.f,0.f,0.f,0.f};
            #pragma unroll
            for (int c = 0; c < 4; ++c) accm[lt][c] = (float4v){0.f,0.f,0.f,0.f};
        }
        #pragma unroll
        for (int cidx = 0; cidx < 4; ++cidx) {
            const int c0 = cidx << 5;
            #pragma unroll
            for (int t = 0; t < 3; ++t) {
                bf16x8 B1, B2, B3;
                {
                    size_t base = ((size_t)t*2048 + osub + m)*128 + c0 + quad*8;
                    B1 = *(const bf16x8*)&wenc[base];
                    B2 = *(const bf16x8*)&wenc[base + (size_t)3*2048*128];
                    B3 = *(const bf16x8*)&wenc[base + (size_t)6*2048*128];
                }
                #pragma unroll
                for (int lt = 0; lt < 4; ++lt) {
                    const int row = lt*16 + m + t;
                    bf16x8 A1 = *(const bf16x8*)&As[0][row][c0 + quad*8];
                    bf16x8 A2 = *(const bf16x8*)&As[1][row][c0 + quad*8];
                    bf16x8 A3 = *(const bf16x8*)&As[2][row][c0 + quad*8];
                    accm[lt][cidx] = __builtin_amdgcn_mfma_f32_16x16x32_bf16(A1, B1, accm[lt][cidx], 0, 0, 0);
                    corr[lt][0] = __builtin_amdgcn_mfma_f32_16x16x32_bf16(A1, B2, corr[lt][0], 0, 0, 0);
                    corr[lt][1] = __builtin_amdgcn_mfma_f32_16x16x32_bf16(A2, B1, corr[lt][1], 0, 0, 0);
                    corr[lt][0] = __builtin_amdgcn_mfma_f32_16x16x32_bf16(A1, B3, corr[lt][0], 0, 0, 0);
                    corr[lt][1] = __builtin_amdgcn_mfma_f32_16x16x32_bf16(A3, B1, corr[lt][1], 0, 0, 0);
                    corr[lt][0] = __builtin_amdgcn_mfma_f32_16x16x32_bf16(A2, B2, corr[lt][0], 0, 0, 0);
                }
            }
        }
        const int is_k = (o0 >= 1024);
        const double g  = (double)(is_k ? gamma_k[0] : gamma_q[0]);
        const double be = (double)(is_k ? beta_k[0]  : beta_q[0]);
        const int o_global = osub + m;
        const int o_local  = o_global - (is_k ? 1024 : 0);
        const double bias  = (double)(is_k ? k_b[o_local] : q_b[o_local]);
        float* dest = is_k ? k_s : q_s;
        #pragma unroll
        for (int lt = 0; lt < 4; ++lt) {
            #pragma unroll
            for (int reg = 0; reg < 4; ++reg) {
                double s = (double)corr[lt][0][reg] + (double)corr[lt][1][reg];
                #pragma unroll
                for (int c = 0; c < 4; ++c) s += (double)accm[lt][c][reg];
                const int l = lb0 + lt*16 + quad*4 + reg;
                dest[((size_t)(b*LL + l))*OC + o_local] = (float)(g*(s + bias) + be);
            }
        }
    } else {
        // ---- v path (K=1 tap => t=2 rows; 2-plane/4-pass; numerator budget) ----
        const int o0 = (yt - 32) << 6;
        const int osub = o0 + wave*16;
        float4v accm[4][4];
        float4v corr[4];
        #pragma unroll
        for (int lt = 0; lt < 4; ++lt) {
            corr[lt] = (float4v){0.f,0.f,0.f,0.f};
            #pragma unroll
            for (int c = 0; c < 4; ++c) accm[lt][c] = (float4v){0.f,0.f,0.f,0.f};
        }
        #pragma unroll
        for (int cidx = 0; cidx < 4; ++cidx) {
            const int c0 = cidx << 5;
            bf16x8 B1, B2;
            {
                size_t base = ((size_t)(osub + m))*128 + c0 + quad*8;
                B1 = *(const bf16x8*)&venc[base];
                B2 = *(const bf16x8*)&venc[base + (size_t)1024*128];
            }
            #pragma unroll
            for (int lt = 0; lt < 4; ++lt) {
                const int row = lt*16 + m + 2;
                bf16x8 A1 = *(const bf16x8*)&As[0][row][c0 + quad*8];
                bf16x8 A2 = *(const bf16x8*)&As[1][row][c0 + quad*8];
                accm[lt][cidx] = __builtin_amdgcn_mfma_f32_16x16x32_bf16(A1, B1, accm[lt][cidx], 0, 0, 0);
                corr[lt] = __builtin_amdgcn_mfma_f32_16x16x32_bf16(A1, B2, corr[lt], 0, 0, 0);
                corr[lt] = __builtin_amdgcn_mfma_f32_16x16x32_bf16(A2, B1, corr[lt], 0, 0, 0);
                corr[lt] = __builtin_amdgcn_mfma_f32_16x16x32_bf16(A2, B2, corr[lt], 0, 0, 0);
            }
        }
        const int o_local = osub + m;
        #pragma unroll
        for (int lt = 0; lt < 4; ++lt) {
            #pragma unroll
            for (int reg = 0; reg < 4; ++reg) {
                float s = corr[lt][reg];
                #pragma unroll
                for (int c = 0; c < 4; ++c) s += accm[lt][c][reg];
                const int l = lb0 + lt*16 + quad*4 + reg;
                v_s[((size_t)(b*LL + l))*OC + o_local] = s;
            }
        }
    }
}

// ---------------------------------------------------------------------------
// Kernel 2: sketch q+k fused, 3-plane/6-pass MFMA in-place (r8-proven body).
// grid 2048: x<1024 -> q, else k.
// ---------------------------------------------------------------------------
__global__ __launch_bounds__(256) void sketch_mfma_k(
    float* __restrict__ q_s, float* __restrict__ k_s,
    const __bf16* __restrict__ genc_all)
{
    __shared__ __bf16 As[3][32][136];
    const int tid  = threadIdx.x;
    const int wave = tid >> 6;
    const int lane = tid & 63;
    const int m    = lane & 15;
    const int quad = lane >> 4;
    const int half = blockIdx.x >> 10;
    float* buf = half ? k_s : q_s;
    const __bf16* genc = genc_all + (size_t)half*2*3*128*128;
    const size_t i0 = (size_t)(blockIdx.x & 1023) * 32;

    for (int e = tid; e < 32*128; e += 256) {
        int row = e >> 7, d = e & 127;
        float v = buf[(i0 + row)*RR_ + d];
        __bf16 h1 = (__bf16)v;  float r1 = v - (float)h1;
        __bf16 h2 = (__bf16)r1; float r2 = r1 - (float)h2;
        __bf16 h3 = (__bf16)r2;
        As[0][row][d] = h1; As[1][row][d] = h2; As[2][row][d] = h3;
    }
    __syncthreads();

    float4v accm[2][2][2], corr[2][2][2];
    #pragma unroll
    for (int mt = 0; mt < 2; ++mt)
        #pragma unroll
        for (int nt = 0; nt < 2; ++nt)
            #pragma unroll
            for (int mat = 0; mat < 2; ++mat) {
                accm[mt][nt][mat] = (float4v){0.f,0.f,0.f,0.f};
                corr[mt][nt][mat] = (float4v){0.f,0.f,0.f,0.f};
            }

    #pragma unroll
    for (int ck = 0; ck < 4; ++ck) {
        const int k0 = ck << 5;
        bf16x8 A1[2], A2[2], A3[2];
        #pragma unroll
        for (int mt = 0; mt < 2; ++mt) {
            A1[mt] = *(const bf16x8*)&As[0][mt*16 + m][k0 + quad*8];
            A2[mt] = *(const bf16x8*)&As[1][mt*16 + m][k0 + quad*8];
            A3[mt] = *(const bf16x8*)&As[2][mt*16 + m][k0 + quad*8];
        }
        #pragma unroll
        for (int nt = 0; nt < 2; ++nt) {
            const int r = wave*32 + nt*16 + m;
            #pragma unroll
            for (int mat = 0; mat < 2; ++mat) {
                size_t base = ((size_t)(mat*3)*128 + r)*128 + k0 + quad*8;
                bf16x8 B1 = *(const bf16x8*)&genc[base];
                bf16x8 B2 = *(const bf16x8*)&genc[base + (size_t)128*128];
                bf16x8 B3 = *(const bf16x8*)&genc[base + (size_t)2*128*128];
                #pragma unroll
                for (int mt = 0; mt < 2; ++mt) {
                    accm[mt][nt][mat] = __builtin_amdgcn_mfma_f32_16x16x32_bf16(A1[mt], B1, accm[mt][nt][mat], 0, 0, 0);
                    corr[mt][nt][mat] = __builtin_amdgcn_mfma_f32_16x16x32_bf16(A1[mt], B2, corr[mt][nt][mat], 0, 0, 0);
                    corr[mt][nt][mat] = __builtin_amdgcn_mfma_f32_16x16x32_bf16(A2[mt], B1, corr[mt][nt][mat], 0, 0, 0);
                    corr[mt][nt][mat] = __builtin_amdgcn_mfma_f32_16x16x32_bf16(A1[mt], B3, corr[mt][nt][mat], 0, 0, 0);
                    corr[mt][nt][mat] = __builtin_amdgcn_mfma_f32_16x16x32_bf16(A3[mt], B1, corr[mt][nt][mat], 0, 0, 0);
                    corr[mt][nt][mat] = __builtin_amdgcn_mfma_f32_16x16x32_bf16(A2[mt], B2, corr[mt][nt][mat], 0, 0, 0);
                }
            }
        }
    }
    __syncthreads();

    const double SR  = 11.313708498984760390;
    const double ISR = 0.088388347648318440550;
    #pragma unroll
    for (int mt = 0; mt < 2; ++mt)
        #pragma unroll
        for (int nt = 0; nt < 2; ++nt)
            #pragma unroll
            for (int reg = 0; reg < 4; ++reg) {
                double u1 = (double)accm[mt][nt][0][reg] + (double)corr[mt][nt][0][reg];
                double u2 = (double)accm[mt][nt][1][reg] + (double)corr[mt][nt][1][reg];
                double phi = SR * tanh(u1*u2*ISR);
                const size_t row = i0 + mt*16 + quad*4 + reg;
                const int col = wave*32 + nt*16 + m;
                buf[row*RR_ + col] = (float)phi;
            }
}

// ---------------------------------------------------------------------------
// Kernel 3: KV^T partials via 2-plane MFMA + fp64 Ksum partials (r10-proven).
// ---------------------------------------------------------------------------
__global__ __launch_bounds__(512) void kv_mfma_k(
    const float* __restrict__ phi_k, const float* __restrict__ v,
    float* __restrict__ part_kv, double* __restrict__ part_ks)
{
    __shared__ float Pt[128*36];
    __shared__ float Vt[128*36];
    __shared__ double ksred[512];
    const int tid  = threadIdx.x;
    const int wave = tid >> 6;
    const int lane = tid & 63;
    const int m    = lane & 15;
    const int quad = lane >> 4;
    const int split = blockIdx.x;
    const int bh    = blockIdx.y;
    const int b = bh >> 3, h = bh & 7;
    const int lbase = split * 128;
    const int dh = wave & 1;
    const int rq = wave >> 1;

    float4v accm[4][2], corr[4][2];
    #pragma unroll
    for (int mt = 0; mt < 4; ++mt)
        #pragma unroll
        for (int nt = 0; nt < 2; ++nt) {
            accm[mt][nt] = (float4v){0.f,0.f,0.f,0.f};
            corr[mt][nt] = (float4v){0.f,0.f,0.f,0.f};
        }
    double ks = 0.0;

    for (int ch = 0; ch < 4; ++ch) {
        __syncthreads();
        for (int e = tid; e < 32*128; e += 512) {
            const int l = e >> 7, r = e & 127;
            size_t base = ((size_t)(b*LL + lbase + ch*32 + l)*HH + h)*RR_;
            float pv = phi_k[base + r];
            float vv = v[base + r];
            Pt[r*36 + l] = pv;
            Vt[r*36 + l] = vv;
            ks += (double)pv;
        }
        __syncthreads();
        bf16x8 A1[4], A2[4], B1[2], B2[2];
        #pragma unroll
        for (int mt = 0; mt < 4; ++mt)
            enc2(&Vt[(dh*64 + mt*16 + m)*36 + quad*8], A1[mt], A2[mt]);
        #pragma unroll
        for (int nt = 0; nt < 2; ++nt)
            enc2(&Pt[(rq*32 + nt*16 + m)*36 + quad*8], B1[nt], B2[nt]);
        #pragma unroll
        for (int mt = 0; mt < 4; ++mt)
            #pragma unroll
            for (int nt = 0; nt < 2; ++nt) {
                accm[mt][nt] = __builtin_amdgcn_mfma_f32_16x16x32_bf16(A1[mt], B1[nt], accm[mt][nt], 0, 0, 0);
                corr[mt][nt] = __builtin_amdgcn_mfma_f32_16x16x32_bf16(A1[mt], B2[nt], corr[mt][nt], 0, 0, 0);
                corr[mt][nt] = __builtin_amdgcn_mfma_f32_16x16x32_bf16(A2[mt], B1[nt], corr[mt][nt], 0, 0, 0);
                corr[mt][nt] = __builtin_amdgcn_mfma_f32_16x16x32_bf16(A2[mt], B2[nt], corr[mt][nt], 0, 0, 0);
            }
    }

    ksred[tid] = ks;
    __syncthreads();
    if (tid < 128) {
        double s = ksred[tid] + ksred[tid+128] + ksred[tid+256] + ksred[tid+384];
        part_ks[(bh*16 + split)*RR_ + tid] = s;
    }

    float* outp = part_kv + ((size_t)(bh*16 + split))*RR_*DD;
    #pragma unroll
    for (int mt = 0; mt < 4; ++mt)
        #pragma unroll
        for (int nt = 0; nt < 2; ++nt)
            #pragma unroll
            for (int reg = 0; reg < 4; ++reg) {
                const int d = dh*64 + mt*16 + quad*4 + reg;
                const int r = rq*32 + nt*16 + m;
                outp[d*128 + r] = accm[mt][nt][reg] + corr[mt][nt][reg];
            }
}

// ---------------------------------------------------------------------------
// Kernel 4: reduce KVT partials -> bf16 2-plane KVTenc.
// ---------------------------------------------------------------------------
__global__ __launch_bounds__(256) void kvreduce_k(
    const float* __restrict__ part_kv, __bf16* __restrict__ kvt_enc)
{
    const int gid = blockIdx.x*256 + threadIdx.x;
    if (gid >= 16*RR_*DD) return;
    const int bh = gid >> 14;
    const int rd = gid & 16383;
    float s = 0.f;
    #pragma unroll
    for (int c = 0; c < 16; ++c)
        s += part_kv[(((size_t)(bh*16 + c)) << 14) + rd];
    __bf16 h1 = (__bf16)s;
    __bf16 h2 = (__bf16)(s - (float)h1);
    kvt_enc[(size_t)bh*16384 + rd] = h1;
    kvt_enc[(size_t)(16 + bh)*16384 + rd] = h2;
}

// ---------------------------------------------------------------------------
// Kernel 5: numerator MFMA + fp64 den (r10-proven).
// ---------------------------------------------------------------------------
__global__ __launch_bounds__(256) void numden_mfma_k(
    const float* __restrict__ phi_q, const __bf16* __restrict__ kvt_enc,
    const double* __restrict__ part_ks, float* __restrict__ o_out)
{
    __shared__ float Pq[64*132];
    __shared__ double Ks_s[128];
    __shared__ double den_s[64];
    const int tid  = threadIdx.x;
    const int wave = tid >> 6;
    const int lane = tid & 63;
    const int m    = lane & 15;
    const int quad = lane >> 4;
    const int lt = blockIdx.x;
    const int bh = blockIdx.y;
    const int b = bh >> 3, h = bh & 7;
    const int l0 = lt * 64;

    if (tid < 128) {
        double s = 0.0;
        #pragma unroll
        for (int c = 0; c < 16; ++c) s += part_ks[(bh*16 + c)*RR_ + tid];
        Ks_s[tid] = s;
    }
    for (int e = tid; e < 64*128; e += 256) {
        const int l = e >> 7, r = e & 127;
        Pq[l*132 + r] = phi_q[((size_t)(b*LL + l0 + l)*HH + h)*RR_ + r];
    }
    __syncthreads();

    double den = 0.0;
    if (tid < 64) {
        #pragma unroll
        for (int r = 0; r < 128; ++r)
            den += (double)Pq[tid*132 + r] * Ks_s[r];
    }

    float4v accm[4][2], corr[4][2];
    #pragma unroll
    for (int mt = 0; mt < 4; ++mt)
        #pragma unroll
        for (int nt = 0; nt < 2; ++nt) {
            accm[mt][nt] = (float4v){0.f,0.f,0.f,0.f};
            corr[mt][nt] = (float4v){0.f,0.f,0.f,0.f};
        }

    #pragma unroll
    for (int ck = 0; ck < 4; ++ck) {
        const int k0 = ck << 5;
        bf16x8 A1[4], A2[4];
        #pragma unroll
        for (int mt = 0; mt < 4; ++mt)
            enc2(&Pq[(mt*16 + m)*132 + k0 + quad*8], A1[mt], A2[mt]);
        #pragma unroll
        for (int nt = 0; nt < 2; ++nt) {
            const int d = wave*32 + nt*16 + m;
            size_t base = ((size_t)bh*128 + d)*128 + k0 + quad*8;
            bf16x8 B1 = *(const bf16x8*)&kvt_enc[base];
            bf16x8 B2 = *(const bf16x8*)&kvt_enc[base + (size_t)16*16384];
            #pragma unroll
            for (int mt = 0; mt < 4; ++mt) {
                accm[mt][nt] = __builtin_amdgcn_mfma_f32_16x16x32_bf16(A1[mt], B1, accm[mt][nt], 0, 0, 0);
                corr[mt][nt] = __builtin_amdgcn_mfma_f32_16x16x32_bf16(A1[mt], B2, corr[mt][nt], 0, 0, 0);
                corr[mt][nt] = __builtin_amdgcn_mfma_f32_16x16x32_bf16(A2[mt], B1, corr[mt][nt], 0, 0, 0);
                corr[mt][nt] = __builtin_amdgcn_mfma_f32_16x16x32_bf16(A2[mt], B2, corr[mt][nt], 0, 0, 0);
            }
        }
    }

    __syncthreads();
    if (tid < 64) den_s[tid] = den;
    __syncthreads();

    #pragma unroll
    for (int mt = 0; mt < 4; ++mt)
        #pragma unroll
        for (int nt = 0; nt < 2; ++nt)
            #pragma unroll
            for (int reg = 0; reg < 4; ++reg) {
                const int ll = mt*16 + quad*4 + reg;
                const int d  = wave*32 + nt*16 + m;
                const float inv = (float)(1.0 / (den_s[ll] + 1e-6));
                o_out[((size_t)(b*LL + l0 + ll))*OC + h*DD + d] =
                    (accm[mt][nt][reg] + corr[mt][nt][reg]) * inv;
            }
}

// ---------------------------------------------------------------------------
// Kernel 6: output projection partials via 2-plane MFMA (r10-proven).
// ---------------------------------------------------------------------------
__global__ __launch_bounds__(256) void proj_part_mfma_k(
    const float* __restrict__ o_s, const __bf16* __restrict__ penc,
    float* __restrict__ part)
{
    __shared__ float As[32*260];
    const int tid  = threadIdx.x;
    const int wave = tid >> 6;
    const int lane = tid & 63;
    const int m    = lane & 15;
    const int quad = lane >> 4;
    const int row0  = blockIdx.x * 32;
    const int kbase = blockIdx.y * 256;

    for (int e = tid; e < 32*256; e += 256) {
        const int row = e >> 8, k = e & 255;
        As[row*260 + k] = o_s[(size_t)(row0 + row)*OC + kbase + k];
    }
    __syncthreads();

    float4v accm[2][2], corr[2][2];
    #pragma unroll
    for (int mt = 0; mt < 2; ++mt)
        #pragma unroll
        for (int nt = 0; nt < 2; ++nt) {
            accm[mt][nt] = (float4v){0.f,0.f,0.f,0.f};
            corr[mt][nt] = (float4v){0.f,0.f,0.f,0.f};
        }

    #pragma unroll
    for (int ck = 0; ck < 8; ++ck) {
        const int k0 = ck << 5;
        bf16x8 A1[2], A2[2];
        #pragma unroll
        for (int mt = 0; mt < 2; ++mt)
            enc2(&As[(mt*16 + m)*260 + k0 + quad*8], A1[mt], A2[mt]);
        #pragma unroll
        for (int nt = 0; nt < 2; ++nt) {
            const int j = wave*32 + nt*16 + m;
            size_t base = ((size_t)j)*OC + kbase + k0 + quad*8;
            bf16x8 B1 = *(const bf16x8*)&penc[base];
            bf16x8 B2 = *(const bf16x8*)&penc[base + (size_t)128*OC];
            #pragma unroll
            for (int mt = 0; mt < 2; ++mt) {
                accm[mt][nt] = __builtin_amdgcn_mfma_f32_16x16x32_bf16(A1[mt], B1, accm[mt][nt], 0, 0, 0);
                corr[mt][nt] = __builtin_amdgcn_mfma_f32_16x16x32_bf16(A1[mt], B2, corr[mt][nt], 0, 0, 0);
                corr[mt][nt] = __builtin_amdgcn_mfma_f32_16x16x32_bf16(A2[mt], B1, corr[mt][nt], 0, 0, 0);
                corr[mt][nt] = __builtin_amdgcn_mfma_f32_16x16x32_bf16(A2[mt], B2, corr[mt][nt], 0, 0, 0);
            }
        }
    }

    float* outp = part + (size_t)blockIdx.y*BL*DD;
    #pragma unroll
    for (int mt = 0; mt < 2; ++mt)
        #pragma unroll
        for (int nt = 0; nt < 2; ++nt)
            #pragma unroll
            for (int reg = 0; reg < 4; ++reg) {
                const int row = row0 + mt*16 + quad*4 + reg;
                const int j   = wave*32 + nt*16 + m;
                outp[(size_t)row*DD + j] = accm[mt][nt][reg] + corr[mt][nt][reg];
            }
}

// ---------------------------------------------------------------------------
// Kernel 7: reduce the 4 K-split partials + bias.
// ---------------------------------------------------------------------------
__global__ __launch_bounds__(256) void proj_reduce_k(
    const float* __restrict__ part, const float* __restrict__ pb,
    float* __restrict__ out)
{
    const int gid = blockIdx.x*256 + threadIdx.x;
    if (gid >= BL*DD/4) return;
    const float4* p4 = (const float4*)part;
    float4 s = p4[gid];
    #pragma unroll
    for (int c = 1; c < 4; ++c) {
        float4 t = p4[gid + (size_t)c*(BL*DD/4)];
        s.x += t.x; s.y += t.y; s.z += t.z; s.w += t.w;
    }
    const int col = (gid << 2) & (DD-1);
    s.x += pb[col]; s.y += pb[col+1]; s.z += pb[col+2]; s.w += pb[col+3];
    ((float4*)out)[gid] = s;
}

// ---------------------------------------------------------------------------
extern "C" void kernel_launch(void* const* d_in, const int* in_sizes, int n_in,
                              void* d_out, int out_size, void* d_ws, size_t ws_size,
                              hipStream_t stream) {
    const float* x       = (const float*)d_in[0];
    const float* q_w     = (const float*)d_in[1];
    const float* q_b     = (const float*)d_in[2];
    const float* k_w     = (const float*)d_in[3];
    const float* k_b     = (const float*)d_in[4];
    const float* v_w     = (const float*)d_in[5];
    const float* g1_q    = (const float*)d_in[6];
    const float* g2_q    = (const float*)d_in[7];
    const float* g1_k    = (const float*)d_in[8];
    const float* g2_k    = (const float*)d_in[9];
    const float* gamma_q = (const float*)d_in[10];
    const float* beta_q  = (const float*)d_in[11];
    const float* gamma_k = (const float*)d_in[12];
    const float* beta_k  = (const float*)d_in[13];
    const float* proj_w  = (const float*)d_in[14];
    const float* proj_b  = (const float*)d_in[15];

    float* f = (float*)d_ws;
    float* q_s     = f;                        // 4,194,304 floats
    float* k_s     = f + 4194304;              // 4,194,304
    float* v_s     = f + 8388608;              // 4,194,304
    float* part_kv = f + 12582912;             // 4,194,304 (scratch: wenc/xenc/kv parts/proj parts)
    double* part_ks = (double*)(f + 16777216); // 32,768 doubles
    __bf16* kvt_enc = (__bf16*)(f + 16842752); // 524,288 bf16
    __bf16* genc   = (__bf16*)(f + 17104896);  // 196,608 bf16
    __bf16* venc   = (__bf16*)(f + 17203200);  // 262,144 bf16
    __bf16* penc   = (__bf16*)(f + 17334272);  // 262,144 bf16
    float* o_s     = k_s;                      // reuse (phi_k dead after kv_mfma)
    float* proj_part = part_kv;                // reuse (kv parts dead after kvreduce)
    __bf16* wenc   = (__bf16*)(f + 12582912);
    __bf16* xenc   = (__bf16*)(f + 13762560);

    dim3 blk(256);
    enc_fused_k<<<2816, blk, 0, stream>>>(q_w, k_w, v_w, proj_w,
                                          g1_q, g2_q, g1_k, g2_k, x,
                                          wenc, genc, venc, penc, xenc);
    conv_mfma_k<<<dim3(64,48), blk, 0, stream>>>(xenc, wenc, venc, q_b, k_b,
                                                 gamma_q, beta_q, gamma_k, beta_k,
                                                 q_s, k_s, v_s);
    sketch_mfma_k<<<2048, blk, 0, stream>>>(q_s, k_s, genc);
    kv_mfma_k<<<dim3(16,16), dim3(512), 0, stream>>>(k_s, v_s, part_kv, part_ks);
    kvreduce_k<<<1024, blk, 0, stream>>>(part_kv, kvt_enc);
    numden_mfma_k<<<dim3(32,16), blk, 0, stream>>>(q_s, kvt_enc, part_ks, o_s);
    proj_part_mfma_k<<<dim3(128,4), blk, 0, stream>>>(o_s, penc, proj_part);
    proj_reduce_k<<<512, blk, 0, stream>>>(proj_part, proj_b, (float*)d_out);
}

// Round 14
// 267.944 us; speedup vs baseline: 2.4950x; 1.0735x over previous
//
#include <hip/hip_runtime.h>
#include <math.h>

// Problem constants
#define BB 2
#define DD 128
#define LL 2048
#define HH 8
#define OC 1024     // H*D
#define RR_ 128
#define BL (BB*LL)          // 4096
#define NROW (BL*HH)        // 32768
#define XROWS 2052

// Numerics ledger (absmax bf16-quantized; threshold 180.48):
//   r3 full fp64 -> 128 PASS | r2 seq fp32 (eps~7e-7) -> 192 FAIL
//   r5 chunk32+tanhf (~5e-7) -> 192 FAIL | r6 chunk4/8+fp64 tanh -> 128 PASS
//   r7-r11 MFMA ladder -> 64 PASS, 288us
//   r12 fast tanh -> 640 FAIL, r13 fp64-core fast tanh -> 768 FAIL.
//   ROOT CAUSE (r13 post-mortem): the constant C=2*ISR*log2e was mistyped
//   (0.25505654 vs correct 0.25503486) in BOTH r12 and r13 — 8.5e-5 rel
//   error on the tanh argument; core precision was irrelevant.
// r14: same r13 core, C computed as compile-time product of two short
//      constants (sqrt2/8 * log2e) — no long-literal transcription risk.

typedef __bf16  bf16x8  __attribute__((ext_vector_type(8)));
typedef float   float4v __attribute__((ext_vector_type(4)));

__device__ __forceinline__ void enc2(const float* src, bf16x8& p1, bf16x8& p2) {
    #pragma unroll
    for (int j = 0; j < 8; ++j) {
        float v = src[j];
        __bf16 h1 = (__bf16)v;
        p1[j] = h1;
        p2[j] = (__bf16)(v - (float)h1);
    }
}

// phi = SR*tanh(u1*u2/SR) = SR*(1 - 2/(2^y + 1)), y = u1*u2*(2/sqrt(128))*log2e.
// fp64 pipeline; exp2 core: n = rint(y), f = y-n in [-0.5,0.5];
// 2^f = 1 + c1*f + f^2*(c2 + f*Q32(f)), Q32 = c3..c9 Horner in fp32;
// 2^n by exponent bits; reciprocal = v_rcp_f32 seed + 2 fp64 Newton steps.
__device__ __forceinline__ float fast_phi(double u1, double u2) {
    const double TWO_ISR = 0.17677669529663688110;  // 2/sqrt(128) = sqrt(2)/8
    const double LOG2E   = 1.44269504088896340736;  // log2(e)
    const double SR      = 11.313708498984760390;   // sqrt(128)
    double y = (u1*u2) * (TWO_ISR * LOG2E);
    y = fmin(fmax(y, -1020.4), 1020.4);         // keeps f in [-0.5,0.5], E finite
    double n = rint(y);
    double f = y - n;
    // fp32 tail Q(f) = c3 + c4 f + ... + c9 f^6   (ck = ln2^k / k!)
    float ff = (float)f;
    float q;
    q = fmaf(1.01780860092396960e-7f, ff, 1.32154867901443094e-6f);
    q = fmaf(q, ff, 1.52527338040598403e-5f);
    q = fmaf(q, ff, 1.54035303933816099e-4f);
    q = fmaf(q, ff, 1.33335581464284434e-3f);
    q = fmaf(q, ff, 9.61812910762847716e-3f);
    q = fmaf(q, ff, 5.55041086648215800e-2f);
    // fp64 head: E0 = 1 + c1*f + f^2*(c2 + f*q)
    double t2   = fma(f, (double)q, 0.24022650695910071233);
    double head = fma(f, 0.69314718055994530942, 1.0);
    double E0   = fma(f*f, t2, head);
    int ni = (int)n;
    double En = __hiloint2double((ni + 1023) << 20, 0);   // 2^n
    double E  = E0 * En;
    double den = E + 1.0;                        // finite always (y clamped)
    double r = (double)__builtin_amdgcn_rcpf((float)den); // seed (0 if den>3.4e38)
    r = r * fma(-den, r, 2.0);                   // Newton 1
    r = r * fma(-den, r, 2.0);                   // Newton 2 -> fp64-accurate
    double t = fma(-2.0, r, 1.0);
    return (float)(SR * t);
}

// ---------------------------------------------------------------------------
// Kernel 0: fused encode (weights + x). (r11-proven)
// ---------------------------------------------------------------------------
__global__ __launch_bounds__(256) void enc_fused_k(
    const float* __restrict__ q_w, const float* __restrict__ k_w,
    const float* __restrict__ v_w, const float* __restrict__ pw,
    const float* __restrict__ g1_q, const float* __restrict__ g2_q,
    const float* __restrict__ g1_k, const float* __restrict__ g2_k,
    const float* __restrict__ x,
    __bf16* __restrict__ wenc, __bf16* __restrict__ genc,
    __bf16* __restrict__ venc, __bf16* __restrict__ penc,
    __bf16* __restrict__ xenc)
{
    __shared__ float t[32][33];
    const int bid = blockIdx.x;
    const int tid = threadIdx.x;
    if (bid < 2304) {
        const int gid = bid*256 + tid;
        if (gid < 262144) {
            const int o = gid >> 7, c = gid & 127;
            #pragma unroll
            for (int tt = 0; tt < 3; ++tt) {
                float v = (o < 1024) ? q_w[(o*128 + c)*3 + tt]
                                     : k_w[((o-1024)*128 + c)*3 + tt];
                __bf16 h1 = (__bf16)v;  float r1 = v - (float)h1;
                __bf16 h2 = (__bf16)r1; float r2 = r1 - (float)h2;
                __bf16 h3 = (__bf16)r2;
                wenc[((size_t)(0*3 + tt)*2048 + o)*128 + c] = h1;
                wenc[((size_t)(1*3 + tt)*2048 + o)*128 + c] = h2;
                wenc[((size_t)(2*3 + tt)*2048 + o)*128 + c] = h3;
            }
        } else if (gid < 262144 + 65536) {
            const int g = gid - 262144;
            const int mat = g >> 14, rem = g & 16383;
            const int r = rem >> 7, d = rem & 127;
            const float* src = (mat == 0) ? g1_q : (mat == 1) ? g2_q
                             : (mat == 2) ? g1_k : g2_k;
            float v = src[d*RR_ + r];
            __bf16 h1 = (__bf16)v;  float r1 = v - (float)h1;
            __bf16 h2 = (__bf16)r1; float r2 = r1 - (float)h2;
            __bf16 h3 = (__bf16)r2;
            genc[((size_t)(mat*3 + 0)*128 + r)*128 + d] = h1;
            genc[((size_t)(mat*3 + 1)*128 + r)*128 + d] = h2;
            genc[((size_t)(mat*3 + 2)*128 + r)*128 + d] = h3;
        } else if (gid < 262144 + 65536 + 131072) {
            const int g = gid - 262144 - 65536;
            const int o = g >> 7, c = g & 127;
            float v = v_w[o*128 + c];
            __bf16 h1 = (__bf16)v;  float r1 = v - (float)h1;
            __bf16 h2 = (__bf16)r1;
            venc[((size_t)0*1024 + o)*128 + c] = h1;
            venc[((size_t)1*1024 + o)*128 + c] = h2;
        } else if (gid < 262144 + 65536 + 131072 + 131072) {
            const int g = gid - 262144 - 65536 - 131072;
            const int j = g >> 10, k = g & 1023;
            float v = pw[(size_t)j*OC + k];
            __bf16 h1 = (__bf16)v;  float r1 = v - (float)h1;
            __bf16 h2 = (__bf16)r1;
            penc[((size_t)(0*128 + j))*OC + k] = h1;
            penc[((size_t)(1*128 + j))*OC + k] = h2;
        }
    } else {
        const int g = bid - 2304;
        const int lt = g & 63, ct = (g >> 6) & 3, b = g >> 8;
        const int l0 = lt*32, c0 = ct*32;
        for (int e = tid; e < 32*32; e += 256) {
            int c = e >> 5, l = e & 31;
            t[c][l] = x[((size_t)(b*DD + c0 + c))*LL + l0 + l];
        }
        __syncthreads();
        for (int e = tid; e < 32*32; e += 256) {
            int l = e >> 5, c = e & 31;
            float v = t[c][l];
            __bf16 h1 = (__bf16)v;  float r1 = v - (float)h1;
            __bf16 h2 = (__bf16)r1; float r2 = r1 - (float)h2;
            __bf16 h3 = (__bf16)r2;
            const size_t row = (size_t)(l0 + l + 2);
            xenc[((size_t)(0*2 + b)*XROWS + row)*128 + c0 + c] = h1;
            xenc[((size_t)(1*2 + b)*XROWS + row)*128 + c0 + c] = h2;
            xenc[((size_t)(2*2 + b)*XROWS + row)*128 + c0 + c] = h3;
        }
        if (lt == 0 && ct == 0) {
            for (int e = tid; e < 2*128; e += 256) {
                int row = e >> 7, c = e & 127;
                xenc[((size_t)(0*2 + b)*XROWS + row)*128 + c] = (__bf16)0.f;
                xenc[((size_t)(1*2 + b)*XROWS + row)*128 + c] = (__bf16)0.f;
                xenc[((size_t)(2*2 + b)*XROWS + row)*128 + c] = (__bf16)0.f;
            }
        }
    }
}

// ---------------------------------------------------------------------------
// Kernel 1: fused q+k conv (3-plane/6-pass) AND v (2-plane/4-pass). (r11)
// ---------------------------------------------------------------------------
__global__ __launch_bounds__(256) void conv_mfma_k(
    const __bf16* __restrict__ xenc, const __bf16* __restrict__ wenc,
    const __bf16* __restrict__ venc,
    const float* __restrict__ q_b, const float* __restrict__ k_b,
    const float* __restrict__ gamma_q, const float* __restrict__ beta_q,
    const float* __restrict__ gamma_k, const float* __restrict__ beta_k,
    float* __restrict__ q_s, float* __restrict__ k_s, float* __restrict__ v_s)
{
    __shared__ __bf16 As[3][66][136];
    const int tid  = threadIdx.x;
    const int wave = tid >> 6;
    const int lane = tid & 63;
    const int m    = lane & 15;
    const int quad = lane >> 4;
    const int bx = blockIdx.x;
    const int b  = bx >> 5;
    const int lb0 = (bx & 31) << 6;
    const int yt = blockIdx.y;

    for (int e = tid; e < 3*66*16; e += 256) {
        const int p = e / (66*16), rem = e % (66*16);
        const int row = rem >> 4, cg = rem & 15;
        *(bf16x8*)&As[p][row][cg*8] =
            *(const bf16x8*)&xenc[((size_t)(p*2 + b)*XROWS + lb0 + row)*128 + cg*8];
    }
    __syncthreads();

    if (yt < 32) {
        const int o0 = yt << 6;
        const int osub = o0 + wave*16;
        float4v accm[4][4];
        float4v corr[4][2];
        #pragma unroll
        for (int lt = 0; lt < 4; ++lt) {
            corr[lt][0] = (float4v){0.f,0.f,0.f,0.f};
            corr[lt][1] = (float4v){0.f,0.f,0.f,0.f};
            #pragma unroll
            for (int c = 0; c < 4; ++c) accm[lt][c] = (float4v){0.f,0.f,0.f,0.f};
        }
        #pragma unroll
        for (int cidx = 0; cidx < 4; ++cidx) {
            const int c0 = cidx << 5;
            #pragma unroll
            for (int t = 0; t < 3; ++t) {
                bf16x8 B1, B2, B3;
                {
                    size_t base = ((size_t)t*2048 + osub + m)*128 + c0 + quad*8;
                    B1 = *(const bf16x8*)&wenc[base];
                    B2 = *(const bf16x8*)&wenc[base + (size_t)3*2048*128];
                    B3 = *(const bf16x8*)&wenc[base + (size_t)6*2048*128];
                }
                #pragma unroll
                for (int lt = 0; lt < 4; ++lt) {
                    const int row = lt*16 + m + t;
                    bf16x8 A1 = *(const bf16x8*)&As[0][row][c0 + quad*8];
                    bf16x8 A2 = *(const bf16x8*)&As[1][row][c0 + quad*8];
                    bf16x8 A3 = *(const bf16x8*)&As[2][row][c0 + quad*8];
                    accm[lt][cidx] = __builtin_amdgcn_mfma_f32_16x16x32_bf16(A1, B1, accm[lt][cidx], 0, 0, 0);
                    corr[lt][0] = __builtin_amdgcn_mfma_f32_16x16x32_bf16(A1, B2, corr[lt][0], 0, 0, 0);
                    corr[lt][1] = __builtin_amdgcn_mfma_f32_16x16x32_bf16(A2, B1, corr[lt][1], 0, 0, 0);
                    corr[lt][0] = __builtin_amdgcn_mfma_f32_16x16x32_bf16(A1, B3, corr[lt][0], 0, 0, 0);
                    corr[lt][1] = __builtin_amdgcn_mfma_f32_16x16x32_bf16(A3, B1, corr[lt][1], 0, 0, 0);
                    corr[lt][0] = __builtin_amdgcn_mfma_f32_16x16x32_bf16(A2, B2, corr[lt][0], 0, 0, 0);
                }
            }
        }
        const int is_k = (o0 >= 1024);
        const double g  = (double)(is_k ? gamma_k[0] : gamma_q[0]);
        const double be = (double)(is_k ? beta_k[0]  : beta_q[0]);
        const int o_global = osub + m;
        const int o_local  = o_global - (is_k ? 1024 : 0);
        const double bias  = (double)(is_k ? k_b[o_local] : q_b[o_local]);
        float* dest = is_k ? k_s : q_s;
        #pragma unroll
        for (int lt = 0; lt < 4; ++lt) {
            #pragma unroll
            for (int reg = 0; reg < 4; ++reg) {
                double s = (double)corr[lt][0][reg] + (double)corr[lt][1][reg];
                #pragma unroll
                for (int c = 0; c < 4; ++c) s += (double)accm[lt][c][reg];
                const int l = lb0 + lt*16 + quad*4 + reg;
                dest[((size_t)(b*LL + l))*OC + o_local] = (float)(g*(s + bias) + be);
            }
        }
    } else {
        const int o0 = (yt - 32) << 6;
        const int osub = o0 + wave*16;
        float4v accm[4][4];
        float4v corr[4];
        #pragma unroll
        for (int lt = 0; lt < 4; ++lt) {
            corr[lt] = (float4v){0.f,0.f,0.f,0.f};
            #pragma unroll
            for (int c = 0; c < 4; ++c) accm[lt][c] = (float4v){0.f,0.f,0.f,0.f};
        }
        #pragma unroll
        for (int cidx = 0; cidx < 4; ++cidx) {
            const int c0 = cidx << 5;
            bf16x8 B1, B2;
            {
                size_t base = ((size_t)(osub + m))*128 + c0 + quad*8;
                B1 = *(const bf16x8*)&venc[base];
                B2 = *(const bf16x8*)&venc[base + (size_t)1024*128];
            }
            #pragma unroll
            for (int lt = 0; lt < 4; ++lt) {
                const int row = lt*16 + m + 2;
                bf16x8 A1 = *(const bf16x8*)&As[0][row][c0 + quad*8];
                bf16x8 A2 = *(const bf16x8*)&As[1][row][c0 + quad*8];
                accm[lt][cidx] = __builtin_amdgcn_mfma_f32_16x16x32_bf16(A1, B1, accm[lt][cidx], 0, 0, 0);
                corr[lt] = __builtin_amdgcn_mfma_f32_16x16x32_bf16(A1, B2, corr[lt], 0, 0, 0);
                corr[lt] = __builtin_amdgcn_mfma_f32_16x16x32_bf16(A2, B1, corr[lt], 0, 0, 0);
                corr[lt] = __builtin_amdgcn_mfma_f32_16x16x32_bf16(A2, B2, corr[lt], 0, 0, 0);
            }
        }
        const int o_local = osub + m;
        #pragma unroll
        for (int lt = 0; lt < 4; ++lt) {
            #pragma unroll
            for (int reg = 0; reg < 4; ++reg) {
                float s = corr[lt][reg];
                #pragma unroll
                for (int c = 0; c < 4; ++c) s += accm[lt][c][reg];
                const int l = lb0 + lt*16 + quad*4 + reg;
                v_s[((size_t)(b*LL + l))*OC + o_local] = s;
            }
        }
    }
}

// ---------------------------------------------------------------------------
// Kernel 2: sketch q+k fused, 3-plane/6-pass MFMA in-place; fast_phi epilogue.
// ---------------------------------------------------------------------------
__global__ __launch_bounds__(256) void sketch_mfma_k(
    float* __restrict__ q_s, float* __restrict__ k_s,
    const __bf16* __restrict__ genc_all)
{
    __shared__ __bf16 As[3][32][136];
    const int tid  = threadIdx.x;
    const int wave = tid >> 6;
    const int lane = tid & 63;
    const int m    = lane & 15;
    const int quad = lane >> 4;
    const int half = blockIdx.x >> 10;
    float* buf = half ? k_s : q_s;
    const __bf16* genc = genc_all + (size_t)half*2*3*128*128;
    const size_t i0 = (size_t)(blockIdx.x & 1023) * 32;

    for (int e = tid; e < 32*128; e += 256) {
        int row = e >> 7, d = e & 127;
        float v = buf[(i0 + row)*RR_ + d];
        __bf16 h1 = (__bf16)v;  float r1 = v - (float)h1;
        __bf16 h2 = (__bf16)r1; float r2 = r1 - (float)h2;
        __bf16 h3 = (__bf16)r2;
        As[0][row][d] = h1; As[1][row][d] = h2; As[2][row][d] = h3;
    }
    __syncthreads();

    float4v accm[2][2][2], corr[2][2][2];
    #pragma unroll
    for (int mt = 0; mt < 2; ++mt)
        #pragma unroll
        for (int nt = 0; nt < 2; ++nt)
            #pragma unroll
            for (int mat = 0; mat < 2; ++mat) {
                accm[mt][nt][mat] = (float4v){0.f,0.f,0.f,0.f};
                corr[mt][nt][mat] = (float4v){0.f,0.f,0.f,0.f};
            }

    #pragma unroll
    for (int ck = 0; ck < 4; ++ck) {
        const int k0 = ck << 5;
        bf16x8 A1[2], A2[2], A3[2];
        #pragma unroll
        for (int mt = 0; mt < 2; ++mt) {
            A1[mt] = *(const bf16x8*)&As[0][mt*16 + m][k0 + quad*8];
            A2[mt] = *(const bf16x8*)&As[1][mt*16 + m][k0 + quad*8];
            A3[mt] = *(const bf16x8*)&As[2][mt*16 + m][k0 + quad*8];
        }
        #pragma unroll
        for (int nt = 0; nt < 2; ++nt) {
            const int r = wave*32 + nt*16 + m;
            #pragma unroll
            for (int mat = 0; mat < 2; ++mat) {
                size_t base = ((size_t)(mat*3)*128 + r)*128 + k0 + quad*8;
                bf16x8 B1 = *(const bf16x8*)&genc[base];
                bf16x8 B2 = *(const bf16x8*)&genc[base + (size_t)128*128];
                bf16x8 B3 = *(const bf16x8*)&genc[base + (size_t)2*128*128];
                #pragma unroll
                for (int mt = 0; mt < 2; ++mt) {
                    accm[mt][nt][mat] = __builtin_amdgcn_mfma_f32_16x16x32_bf16(A1[mt], B1, accm[mt][nt][mat], 0, 0, 0);
                    corr[mt][nt][mat] = __builtin_amdgcn_mfma_f32_16x16x32_bf16(A1[mt], B2, corr[mt][nt][mat], 0, 0, 0);
                    corr[mt][nt][mat] = __builtin_amdgcn_mfma_f32_16x16x32_bf16(A2[mt], B1, corr[mt][nt][mat], 0, 0, 0);
                    corr[mt][nt][mat] = __builtin_amdgcn_mfma_f32_16x16x32_bf16(A1[mt], B3, corr[mt][nt][mat], 0, 0, 0);
                    corr[mt][nt][mat] = __builtin_amdgcn_mfma_f32_16x16x32_bf16(A3[mt], B1, corr[mt][nt][mat], 0, 0, 0);
                    corr[mt][nt][mat] = __builtin_amdgcn_mfma_f32_16x16x32_bf16(A2[mt], B2, corr[mt][nt][mat], 0, 0, 0);
                }
            }
        }
    }
    __syncthreads();

    #pragma unroll
    for (int mt = 0; mt < 2; ++mt)
        #pragma unroll
        for (int nt = 0; nt < 2; ++nt)
            #pragma unroll
            for (int reg = 0; reg < 4; ++reg) {
                double u1 = (double)accm[mt][nt][0][reg] + (double)corr[mt][nt][0][reg];
                double u2 = (double)accm[mt][nt][1][reg] + (double)corr[mt][nt][1][reg];
                const size_t row = i0 + mt*16 + quad*4 + reg;
                const int col = wave*32 + nt*16 + m;
                buf[row*RR_ + col] = fast_phi(u1, u2);
            }
}

// ---------------------------------------------------------------------------
// Kernel 3: KV^T partials via 2-plane MFMA + fp64 Ksum partials (r10-proven).
// ---------------------------------------------------------------------------
__global__ __launch_bounds__(512) void kv_mfma_k(
    const float* __restrict__ phi_k, const float* __restrict__ v,
    float* __restrict__ part_kv, double* __restrict__ part_ks)
{
    __shared__ float Pt[128*36];
    __shared__ float Vt[128*36];
    __shared__ double ksred[512];
    const int tid  = threadIdx.x;
    const int wave = tid >> 6;
    const int lane = tid & 63;
    const int m    = lane & 15;
    const int quad = lane >> 4;
    const int split = blockIdx.x;
    const int bh    = blockIdx.y;
    const int b = bh >> 3, h = bh & 7;
    const int lbase = split * 128;
    const int dh = wave & 1;
    const int rq = wave >> 1;

    float4v accm[4][2], corr[4][2];
    #pragma unroll
    for (int mt = 0; mt < 4; ++mt)
        #pragma unroll
        for (int nt = 0; nt < 2; ++nt) {
            accm[mt][nt] = (float4v){0.f,0.f,0.f,0.f};
            corr[mt][nt] = (float4v){0.f,0.f,0.f,0.f};
        }
    double ks = 0.0;

    for (int ch = 0; ch < 4; ++ch) {
        __syncthreads();
        for (int e = tid; e < 32*128; e += 512) {
            const int l = e >> 7, r = e & 127;
            size_t base = ((size_t)(b*LL + lbase + ch*32 + l)*HH + h)*RR_;
            float pv = phi_k[base + r];
            float vv = v[base + r];
            Pt[r*36 + l] = pv;
            Vt[r*36 + l] = vv;
            ks += (double)pv;
        }
        __syncthreads();
        bf16x8 A1[4], A2[4], B1[2], B2[2];
        #pragma unroll
        for (int mt = 0; mt < 4; ++mt)
            enc2(&Vt[(dh*64 + mt*16 + m)*36 + quad*8], A1[mt], A2[mt]);
        #pragma unroll
        for (int nt = 0; nt < 2; ++nt)
            enc2(&Pt[(rq*32 + nt*16 + m)*36 + quad*8], B1[nt], B2[nt]);
        #pragma unroll
        for (int mt = 0; mt < 4; ++mt)
            #pragma unroll
            for (int nt = 0; nt < 2; ++nt) {
                accm[mt][nt] = __builtin_amdgcn_mfma_f32_16x16x32_bf16(A1[mt], B1[nt], accm[mt][nt], 0, 0, 0);
                corr[mt][nt] = __builtin_amdgcn_mfma_f32_16x16x32_bf16(A1[mt], B2[nt], corr[mt][nt], 0, 0, 0);
                corr[mt][nt] = __builtin_amdgcn_mfma_f32_16x16x32_bf16(A2[mt], B1[nt], corr[mt][nt], 0, 0, 0);
                corr[mt][nt] = __builtin_amdgcn_mfma_f32_16x16x32_bf16(A2[mt], B2[nt], corr[mt][nt], 0, 0, 0);
            }
    }

    ksred[tid] = ks;
    __syncthreads();
    if (tid < 128) {
        double s = ksred[tid] + ksred[tid+128] + ksred[tid+256] + ksred[tid+384];
        part_ks[(bh*16 + split)*RR_ + tid] = s;
    }

    float* outp = part_kv + ((size_t)(bh*16 + split))*RR_*DD;
    #pragma unroll
    for (int mt = 0; mt < 4; ++mt)
        #pragma unroll
        for (int nt = 0; nt < 2; ++nt)
            #pragma unroll
            for (int reg = 0; reg < 4; ++reg) {
                const int d = dh*64 + mt*16 + quad*4 + reg;
                const int r = rq*32 + nt*16 + m;
                outp[d*128 + r] = accm[mt][nt][reg] + corr[mt][nt][reg];
            }
}

// ---------------------------------------------------------------------------
// Kernel 4: reduce KVT partials -> bf16 2-plane KVTenc.
// ---------------------------------------------------------------------------
__global__ __launch_bounds__(256) void kvreduce_k(
    const float* __restrict__ part_kv, __bf16* __restrict__ kvt_enc)
{
    const int gid = blockIdx.x*256 + threadIdx.x;
    if (gid >= 16*RR_*DD) return;
    const int bh = gid >> 14;
    const int rd = gid & 16383;
    float s = 0.f;
    #pragma unroll
    for (int c = 0; c < 16; ++c)
        s += part_kv[(((size_t)(bh*16 + c)) << 14) + rd];
    __bf16 h1 = (__bf16)s;
    __bf16 h2 = (__bf16)(s - (float)h1);
    kvt_enc[(size_t)bh*16384 + rd] = h1;
    kvt_enc[(size_t)(16 + bh)*16384 + rd] = h2;
}

// ---------------------------------------------------------------------------
// Kernel 5: numerator MFMA + fp64 den (r10-proven).
// ---------------------------------------------------------------------------
__global__ __launch_bounds__(256) void numden_mfma_k(
    const float* __restrict__ phi_q, const __bf16* __restrict__ kvt_enc,
    const double* __restrict__ part_ks, float* __restrict__ o_out)
{
    __shared__ float Pq[64*132];
    __shared__ double Ks_s[128];
    __shared__ double den_s[64];
    const int tid  = threadIdx.x;
    const int wave = tid >> 6;
    const int lane = tid & 63;
    const int m    = lane & 15;
    const int quad = lane >> 4;
    const int lt = blockIdx.x;
    const int bh = blockIdx.y;
    const int b = bh >> 3, h = bh & 7;
    const int l0 = lt * 64;

    if (tid < 128) {
        double s = 0.0;
        #pragma unroll
        for (int c = 0; c < 16; ++c) s += part_ks[(bh*16 + c)*RR_ + tid];
        Ks_s[tid] = s;
    }
    for (int e = tid; e < 64*128; e += 256) {
        const int l = e >> 7, r = e & 127;
        Pq[l*132 + r] = phi_q[((size_t)(b*LL + l0 + l)*HH + h)*RR_ + r];
    }
    __syncthreads();

    double den = 0.0;
    if (tid < 64) {
        #pragma unroll
        for (int r = 0; r < 128; ++r)
            den += (double)Pq[tid*132 + r] * Ks_s[r];
    }

    float4v accm[4][2], corr[4][2];
    #pragma unroll
    for (int mt = 0; mt < 4; ++mt)
        #pragma unroll
        for (int nt = 0; nt < 2; ++nt) {
            accm[mt][nt] = (float4v){0.f,0.f,0.f,0.f};
            corr[mt][nt] = (float4v){0.f,0.f,0.f,0.f};
        }

    #pragma unroll
    for (int ck = 0; ck < 4; ++ck) {
        const int k0 = ck << 5;
        bf16x8 A1[4], A2[4];
        #pragma unroll
        for (int mt = 0; mt < 4; ++mt)
            enc2(&Pq[(mt*16 + m)*132 + k0 + quad*8], A1[mt], A2[mt]);
        #pragma unroll
        for (int nt = 0; nt < 2; ++nt) {
            const int d = wave*32 + nt*16 + m;
            size_t base = ((size_t)bh*128 + d)*128 + k0 + quad*8;
            bf16x8 B1 = *(const bf16x8*)&kvt_enc[base];
            bf16x8 B2 = *(const bf16x8*)&kvt_enc[base + (size_t)16*16384];
            #pragma unroll
            for (int mt = 0; mt < 4; ++mt) {
                accm[mt][nt] = __builtin_amdgcn_mfma_f32_16x16x32_bf16(A1[mt], B1, accm[mt][nt], 0, 0, 0);
                corr[mt][nt] = __builtin_amdgcn_mfma_f32_16x16x32_bf16(A1[mt], B2, corr[mt][nt], 0, 0, 0);
                corr[mt][nt] = __builtin_amdgcn_mfma_f32_16x16x32_bf16(A2[mt], B1, corr[mt][nt], 0, 0, 0);
                corr[mt][nt] = __builtin_amdgcn_mfma_f32_16x16x32_bf16(A2[mt], B2, corr[mt][nt], 0, 0, 0);
            }
        }
    }

    __syncthreads();
    if (tid < 64) den_s[tid] = den;
    __syncthreads();

    #pragma unroll
    for (int mt = 0; mt < 4; ++mt)
        #pragma unroll
        for (int nt = 0; nt < 2; ++nt)
            #pragma unroll
            for (int reg = 0; reg < 4; ++reg) {
                const int ll = mt*16 + quad*4 + reg;
                const int d  = wave*32 + nt*16 + m;
                const float inv = (float)(1.0 / (den_s[ll] + 1e-6));
                o_out[((size_t)(b*LL + l0 + ll))*OC + h*DD + d] =
                    (accm[mt][nt][reg] + corr[mt][nt][reg]) * inv;
            }
}

// ---------------------------------------------------------------------------
// Kernel 6: output projection partials via 2-plane MFMA (r10-proven).
// ---------------------------------------------------------------------------
__global__ __launch_bounds__(256) void proj_part_mfma_k(
    const float* __restrict__ o_s, const __bf16* __restrict__ penc,
    float* __restrict__ part)
{
    __shared__ float As[32*260];
    const int tid  = threadIdx.x;
    const int wave = tid >> 6;
    const int lane = tid & 63;
    const int m    = lane & 15;
    const int quad = lane >> 4;
    const int row0  = blockIdx.x * 32;
    const int kbase = blockIdx.y * 256;

    for (int e = tid; e < 32*256; e += 256) {
        const int row = e >> 8, k = e & 255;
        As[row*260 + k] = o_s[(size_t)(row0 + row)*OC + kbase + k];
    }
    __syncthreads();

    float4v accm[2][2], corr[2][2];
    #pragma unroll
    for (int mt = 0; mt < 2; ++mt)
        #pragma unroll
        for (int nt = 0; nt < 2; ++nt) {
            accm[mt][nt] = (float4v){0.f,0.f,0.f,0.f};
            corr[mt][nt] = (float4v){0.f,0.f,0.f,0.f};
        }

    #pragma unroll
    for (int ck = 0; ck < 8; ++ck) {
        const int k0 = ck << 5;
        bf16x8 A1[2], A2[2];
        #pragma unroll
        for (int mt = 0; mt < 2; ++mt)
            enc2(&As[(mt*16 + m)*260 + k0 + quad*8], A1[mt], A2[mt]);
        #pragma unroll
        for (int nt = 0; nt < 2; ++nt) {
            const int j = wave*32 + nt*16 + m;
            size_t base = ((size_t)j)*OC + kbase + k0 + quad*8;
            bf16x8 B1 = *(const bf16x8*)&penc[base];
            bf16x8 B2 = *(const bf16x8*)&penc[base + (size_t)128*OC];
            #pragma unroll
            for (int mt = 0; mt < 2; ++mt) {
                accm[mt][nt] = __builtin_amdgcn_mfma_f32_16x16x32_bf16(A1[mt], B1, accm[mt][nt], 0, 0, 0);
                corr[mt][nt] = __builtin_amdgcn_mfma_f32_16x16x32_bf16(A1[mt], B2, corr[mt][nt], 0, 0, 0);
                corr[mt][nt] = __builtin_amdgcn_mfma_f32_16x16x32_bf16(A2[mt], B1, corr[mt][nt], 0, 0, 0);
                corr[mt][nt] = __builtin_amdgcn_mfma_f32_16x16x32_bf16(A2[mt], B2, corr[mt][nt], 0, 0, 0);
            }
        }
    }

    float* outp = part + (size_t)blockIdx.y*BL*DD;
    #pragma unroll
    for (int mt = 0; mt < 2; ++mt)
        #pragma unroll
        for (int nt = 0; nt < 2; ++nt)
            #pragma unroll
            for (int reg = 0; reg < 4; ++reg) {
                const int row = row0 + mt*16 + quad*4 + reg;
                const int j   = wave*32 + nt*16 + m;
                outp[(size_t)row*DD + j] = accm[mt][nt][reg] + corr[mt][nt][reg];
            }
}

// ---------------------------------------------------------------------------
// Kernel 7: reduce the 4 K-split partials + bias.
// ---------------------------------------------------------------------------
__global__ __launch_bounds__(256) void proj_reduce_k(
    const float* __restrict__ part, const float* __restrict__ pb,
    float* __restrict__ out)
{
    const int gid = blockIdx.x*256 + threadIdx.x;
    if (gid >= BL*DD/4) return;
    const float4* p4 = (const float4*)part;
    float4 s = p4[gid];
    #pragma unroll
    for (int c = 1; c < 4; ++c) {
        float4 t = p4[gid + (size_t)c*(BL*DD/4)];
        s.x += t.x; s.y += t.y; s.z += t.z; s.w += t.w;
    }
    const int col = (gid << 2) & (DD-1);
    s.x += pb[col]; s.y += pb[col+1]; s.z += pb[col+2]; s.w += pb[col+3];
    ((float4*)out)[gid] = s;
}

// ---------------------------------------------------------------------------
extern "C" void kernel_launch(void* const* d_in, const int* in_sizes, int n_in,
                              void* d_out, int out_size, void* d_ws, size_t ws_size,
                              hipStream_t stream) {
    const float* x       = (const float*)d_in[0];
    const float* q_w     = (const float*)d_in[1];
    const float* q_b     = (const float*)d_in[2];
    const float* k_w     = (const float*)d_in[3];
    const float* k_b     = (const float*)d_in[4];
    const float* v_w     = (const float*)d_in[5];
    const float* g1_q    = (const float*)d_in[6];
    const float* g2_q    = (const float*)d_in[7];
    const float* g1_k    = (const float*)d_in[8];
    const float* g2_k    = (const float*)d_in[9];
    const float* gamma_q = (const float*)d_in[10];
    const float* beta_q  = (const float*)d_in[11];
    const float* gamma_k = (const float*)d_in[12];
    const float* beta_k  = (const float*)d_in[13];
    const float* proj_w  = (const float*)d_in[14];
    const float* proj_b  = (const float*)d_in[15];

    float* f = (float*)d_ws;
    float* q_s     = f;                        // 4,194,304 floats
    float* k_s     = f + 4194304;              // 4,194,304
    float* v_s     = f + 8388608;              // 4,194,304
    float* part_kv = f + 12582912;             // 4,194,304 (scratch: wenc/xenc/kv parts/proj parts)
    double* part_ks = (double*)(f + 16777216); // 32,768 doubles
    __bf16* kvt_enc = (__bf16*)(f + 16842752); // 524,288 bf16
    __bf16* genc   = (__bf16*)(f + 17104896);  // 196,608 bf16
    __bf16* venc   = (__bf16*)(f + 17203200);  // 262,144 bf16
    __bf16* penc   = (__bf16*)(f + 17334272);  // 262,144 bf16
    float* o_s     = k_s;                      // reuse (phi_k dead after kv_mfma)
    float* proj_part = part_kv;                // reuse (kv parts dead after kvreduce)
    __bf16* wenc   = (__bf16*)(f + 12582912);
    __bf16* xenc   = (__bf16*)(f + 13762560);

    dim3 blk(256);
    enc_fused_k<<<2816, blk, 0, stream>>>(q_w, k_w, v_w, proj_w,
                                          g1_q, g2_q, g1_k, g2_k, x,
                                          wenc, genc, venc, penc, xenc);
    conv_mfma_k<<<dim3(64,48), blk, 0, stream>>>(xenc, wenc, venc, q_b, k_b,
                                                 gamma_q, beta_q, gamma_k, beta_k,
                                                 q_s, k_s, v_s);
    sketch_mfma_k<<<2048, blk, 0, stream>>>(q_s, k_s, genc);
    kv_mfma_k<<<dim3(16,16), dim3(512), 0, stream>>>(k_s, v_s, part_kv, part_ks);
    kvreduce_k<<<1024, blk, 0, stream>>>(part_kv, kvt_enc);
    numden_mfma_k<<<dim3(32,16), blk, 0, stream>>>(q_s, kvt_enc, part_ks, o_s);
    proj_part_mfma_k<<<dim3(128,4), blk, 0, stream>>>(o_s, penc, proj_part);
    proj_reduce_k<<<512, blk, 0, stream>>>(proj_part, proj_b, (float*)d_out);
}